// Round 5
// baseline (1964.263 us; speedup 1.0000x reference)
//
#include <hip/hip_runtime.h>
#include <hip/hip_bf16.h>

typedef __hip_bfloat16 bf16;

#define Hh 160
#define Wd 160
#define HWp (Hh*Wd)       // 25600
#define Bn 2
#define Cc 64
#define NPIX (Bn*HWp)     // 51200
#define SCL 0.07905694150420949f   // 1/sqrt(160)
#define TWO_PI_160 0.039269908169872414f  // 2*pi/160

static __device__ __forceinline__ float b2f(bf16 x) { return __bfloat162float(x); }
static __device__ __forceinline__ bf16 f2b(float f) { return __float2bfloat16(f); }
static __device__ __forceinline__ float bfu(unsigned short u) {
  union { unsigned int i; float f; } z; z.i = ((unsigned int)u) << 16; return z.f;
}

// ---------------- LayerNorm over channel dim (per pixel), fp32 in -> bf16 out ----------------
__global__ void k_ln(const float* __restrict__ in, const float* __restrict__ w,
                     const float* __restrict__ bb, bf16* __restrict__ out) {
  int idx = blockIdx.x * 256 + threadIdx.x;   // grid covers exactly NPIX
  int b = idx / HWp, p = idx - b * HWp;
  const float* src = in + (size_t)b * Cc * HWp + p;
  float s = 0.f, s2 = 0.f;
  for (int c = 0; c < Cc; c++) { float v = src[(size_t)c * HWp]; s += v; s2 += v * v; }
  float mu = s * (1.f / 64.f);
  float var = s2 * (1.f / 64.f) - mu * mu;
  float rs = rsqrtf(fmaxf(var, 0.f) + 1e-6f);
  bf16* dst = out + (size_t)b * Cc * HWp + p;
  for (int c = 0; c < Cc; c++) {
    float v = src[(size_t)c * HWp];
    dst[(size_t)c * HWp] = f2b((v - mu) * rs * w[c] + bb[c]);
  }
}

// ---------------- mean over HW per (b,c) plane (bf16 in) ----------------
__global__ void k_meanhw(const bf16* __restrict__ in, float* __restrict__ out) {
  int bc = blockIdx.x;
  const bf16* src = in + (size_t)bc * HWp;
  int t = threadIdx.x;
  float s = 0.f;
  for (int i = t; i < HWp; i += 256) s += b2f(src[i]);
  __shared__ float sm[256];
  sm[t] = s; __syncthreads();
  for (int off = 128; off; off >>= 1) { if (t < off) sm[t] += sm[t + off]; __syncthreads(); }
  if (t == 0) out[bc] = sm[0] * (1.f / HWp);
}

// ---------------- small matvec: out[b,o] = (addone) + W[o,:]·xin[b,:] + bias[o] ----------------
__global__ void k_small_mv(const float* __restrict__ xin, const float* __restrict__ w,
                           const float* __restrict__ bias, float* __restrict__ out, int addone) {
  int t = threadIdx.x;              // 128 threads
  int b = t >> 6, o = t & 63;
  float acc = bias[o];
  for (int k = 0; k < 64; k++) acc += w[o * 64 + k] * xin[b * 64 + k];
  out[t] = addone ? (1.f + acc) : acc;
}

// ---------------- generic 1x1 conv, bf16 ws in/out, fp32 weights ----------------
__global__ void k_conv1x1(const bf16* __restrict__ in, const float* __restrict__ w,
                          const float* __restrict__ bias, bf16* __restrict__ out,
                          int Cin, int Cout) {
  int p = blockIdx.x * 64 + threadIdx.x;
  int o = blockIdx.y * 4 + threadIdx.y;
  int b = blockIdx.z;
  float acc = bias[o];
  const bf16* src = in + (size_t)b * Cin * HWp + p;
  const float* wr = w + (size_t)o * Cin;
  for (int k = 0; k < Cin; k++) acc += wr[k] * b2f(src[(size_t)k * HWp]);
  out[((size_t)b * Cout + o) * HWp + p] = f2b(acc);
}

// ---------------- c11b: grouped 5x5 conv, groups=16 (4ch/group), pad 2 ----------------
__global__ void k_c11b(const bf16* __restrict__ in, const float* __restrict__ w,
                       const float* __restrict__ bias, bf16* __restrict__ out) {
  int p = blockIdx.x * 64 + threadIdx.x;
  int o = blockIdx.y * 4 + threadIdx.y;
  int b = blockIdx.z;
  int h = p / Wd, x = p - h * Wd;
  int gb = (o >> 2) << 2;
  float acc = bias[o];
  for (int ci = 0; ci < 4; ci++) {
    const bf16* src = in + ((size_t)b * Cc + gb + ci) * HWp;
    for (int ki = 0; ki < 5; ki++) {
      int hh = h + ki - 2; if ((unsigned)hh >= Hh) continue;
      for (int kj = 0; kj < 5; kj++) {
        int ww = x + kj - 2; if ((unsigned)ww >= Wd) continue;
        acc += w[((o * 4 + ci) * 5 + ki) * 5 + kj] * b2f(src[hh * Wd + ww]);
      }
    }
  }
  out[((size_t)b * Cc + o) * HWp + p] = f2b(acc);
}

// ---------------- c2a: grouped 3x3, 64->32, groups=32 (2 in-ch/group), pad 1 ----------------
__global__ void k_c2a(const bf16* __restrict__ in, const float* __restrict__ w,
                      const float* __restrict__ bias, bf16* __restrict__ out) {
  int p = blockIdx.x * 64 + threadIdx.x;
  int o = blockIdx.y * 4 + threadIdx.y;   // 0..31
  int b = blockIdx.z;
  int h = p / Wd, x = p - h * Wd;
  float acc = bias[o];
  for (int ci = 0; ci < 2; ci++) {
    const bf16* src = in + ((size_t)b * Cc + o * 2 + ci) * HWp;
    for (int ki = 0; ki < 3; ki++) {
      int hh = h + ki - 1; if ((unsigned)hh >= Hh) continue;
      for (int kj = 0; kj < 3; kj++) {
        int ww = x + kj - 1; if ((unsigned)ww >= Wd) continue;
        acc += w[((o * 2 + ci) * 3 + ki) * 3 + kj] * b2f(src[hh * Wd + ww]);
      }
    }
  }
  out[((size_t)b * 32 + o) * HWp + p] = f2b(acc);
}

// ---------------- att = c2c(gate(g))*attgamma + c211(x) ----------------
__global__ void k_att(const bf16* __restrict__ g, const bf16* __restrict__ x,
                      const float* __restrict__ c2cw, const float* __restrict__ c2cb,
                      const float* __restrict__ c211w, const float* __restrict__ c211b,
                      const float* __restrict__ attg, bf16* __restrict__ att) {
  int p = blockIdx.x * 64 + threadIdx.x;
  int s = blockIdx.y * 4 + threadIdx.y;   // 0..31
  int b = blockIdx.z;
  float a1 = c2cb[s];
  const bf16* gs = g + (size_t)b * 32 * HWp + p;
  for (int k = 0; k < 16; k++)
    a1 += c2cw[s * 16 + k] * b2f(gs[(size_t)k * HWp]) * b2f(gs[(size_t)(16 + k) * HWp]);
  float acc = a1 * attg[s] + c211b[s];
  const bf16* xs = x + (size_t)b * Cc * HWp + p;
  for (int c = 0; c < Cc; c++) acc += c211w[s * 64 + c] * b2f(xs[(size_t)c * HWp]);
  att[((size_t)b * 32 + s) * HWp + p] = f2b(acc);
}

// ---------------- depthwise 3x3, pad 1 ----------------
__global__ void k_c21dw(const bf16* __restrict__ in, const float* __restrict__ w,
                        const float* __restrict__ bias, bf16* __restrict__ out) {
  int p = blockIdx.x * 64 + threadIdx.x;
  int c = blockIdx.y * 4 + threadIdx.y;
  int b = blockIdx.z;
  int h = p / Wd, x = p - h * Wd;
  float acc = bias[c];
  const bf16* src = in + ((size_t)b * Cc + c) * HWp;
  for (int ki = 0; ki < 3; ki++) {
    int hh = h + ki - 1; if ((unsigned)hh >= Hh) continue;
    for (int kj = 0; kj < 3; kj++) {
      int ww = x + kj - 1; if ((unsigned)ww >= Wd) continue;
      acc += w[c * 9 + ki * 3 + kj] * b2f(src[hh * Wd + ww]);
    }
  }
  out[((size_t)b * Cc + c) * HWp + p] = f2b(acc);
}

// ---------------- KBA fused: out = ((kba+bias)*ga1 + uf) * x1 * sca ----------------
// tile = 64 pixels of one row. thread: g=t&15 (group), pq=t>>4 (4 px each).
// Patch window hoisted to registers (s-invariant); weights staged fp32 in LDS
// as [si][g][d][o] so each tap's 4 o-weights are one ds_read_b128.
__global__ __launch_bounds__(256) void k_kba(
    const bf16* __restrict__ uf, const bf16* __restrict__ att,
    const bf16* __restrict__ x1, const float* __restrict__ scaV,
    const float* __restrict__ kbw, const float* __restrict__ kbb,
    const float* __restrict__ ga1, bf16* __restrict__ out) {
  __shared__ unsigned short patchL[64 * 3 * 66];        // 25344 B, bf16 [c][ki][col]
  __shared__ float attL[64][33];                        // 8448 B
  __shared__ __align__(16) float kwL[2 * 16 * 36 * 4];  // 18432 B  (2 sets/chunk)
  int b = blockIdx.z, h = blockIdx.y;
  int w0 = blockIdx.x * 64;
  int width = min(64, Wd - w0);
  int t = threadIdx.x;
  const unsigned short* uf_u = (const unsigned short*)uf;
  for (int i = t; i < 64 * 3 * 66; i += 256) {
    int c = i / 198, rem = i - c * 198;
    int r = rem / 66, col = rem - r * 66;
    int hh = h + r - 1, ww = w0 + col - 1;
    unsigned short v = 0;
    if ((unsigned)hh < Hh && (unsigned)ww < Wd)
      v = uf_u[((size_t)b * Cc + c) * HWp + hh * Wd + ww];
    patchL[i] = v;
  }
  for (int i = t; i < 64 * 32; i += 256) {
    int px = i & 63, s = i >> 6;
    float v = 0.f;
    if (px < width) v = b2f(att[((size_t)b * 32 + s) * HWp + h * Wd + w0 + px]);
    attL[px][s] = v;
  }
  __syncthreads();
  int g = t & 15, pq = t >> 4;
  // hoist the 4ci x 3ki x 6col patch window into registers (s-invariant)
  float pf[4][3][6];
  #pragma unroll
  for (int ci = 0; ci < 4; ci++)
    #pragma unroll
    for (int ki = 0; ki < 3; ki++) {
      const unsigned int* pr32 =
          (const unsigned int*)&patchL[(g * 4 + ci) * 198 + ki * 66 + 4 * pq];  // 4B aligned
      #pragma unroll
      for (int m2 = 0; m2 < 3; m2++) {
        unsigned int u = pr32[m2];
        pf[ci][ki][2 * m2 + 0] = bfu((unsigned short)(u & 0xffffu));
        pf[ci][ki][2 * m2 + 1] = bfu((unsigned short)(u >> 16));
      }
    }
  float acc[4][4];
  #pragma unroll
  for (int j = 0; j < 4; j++)
    #pragma unroll
    for (int o = 0; o < 4; o++) acc[j][o] = 0.f;

  for (int sc = 0; sc < 16; sc++) {        // 2 sets per chunk
    __syncthreads();
    for (int i = t; i < 2 * 2304; i += 256) {
      int o = i & 3, dd = (i >> 2) % 36, rest = (i >> 2) / 36;
      int gg = rest & 15, si = rest >> 4;
      kwL[i] = kbw[(sc * 2 + si) * 2304 + gg * 144 + o * 36 + dd];
    }
    __syncthreads();
    #pragma unroll
    for (int si = 0; si < 2; si++) {
      int s = sc * 2 + si;
      float a0 = attL[4 * pq + 0][s], a1 = attL[4 * pq + 1][s];
      float a2 = attL[4 * pq + 2][s], a3 = attL[4 * pq + 3][s];
      const float* wbase = &kwL[(si * 16 + g) * 144];
      #pragma unroll
      for (int ci = 0; ci < 4; ci++)
        #pragma unroll
        for (int ki = 0; ki < 3; ki++)
          #pragma unroll
          for (int kj = 0; kj < 3; kj++) {
            int d = ci * 9 + ki * 3 + kj;
            float4 wv = *(const float4*)&wbase[d * 4];
            float p0 = pf[ci][ki][kj + 0] * a0;
            float p1 = pf[ci][ki][kj + 1] * a1;
            float p2 = pf[ci][ki][kj + 2] * a2;
            float p3 = pf[ci][ki][kj + 3] * a3;
            acc[0][0] += p0 * wv.x; acc[0][1] += p0 * wv.y; acc[0][2] += p0 * wv.z; acc[0][3] += p0 * wv.w;
            acc[1][0] += p1 * wv.x; acc[1][1] += p1 * wv.y; acc[1][2] += p1 * wv.z; acc[1][3] += p1 * wv.w;
            acc[2][0] += p2 * wv.x; acc[2][1] += p2 * wv.y; acc[2][2] += p2 * wv.z; acc[2][3] += p2 * wv.w;
            acc[3][0] += p3 * wv.x; acc[3][1] += p3 * wv.y; acc[3][2] += p3 * wv.z; acc[3][3] += p3 * wv.w;
          }
    }
  }
  // bias = att @ kb_b
  float bias_[4][4];
  #pragma unroll
  for (int j = 0; j < 4; j++)
    #pragma unroll
    for (int o = 0; o < 4; o++) bias_[j][o] = 0.f;
  for (int s = 0; s < 32; s++) {
    float kv[4];
    #pragma unroll
    for (int o = 0; o < 4; o++) kv[o] = kbb[s * 64 + g * 4 + o];
    #pragma unroll
    for (int j = 0; j < 4; j++) {
      float av = attL[4 * pq + j][s];
      #pragma unroll
      for (int o = 0; o < 4; o++) bias_[j][o] += av * kv[o];
    }
  }
  #pragma unroll
  for (int j = 0; j < 4; j++) {
    int px = 4 * pq + j;
    if (px >= width) continue;
    int p = h * Wd + w0 + px;
    #pragma unroll
    for (int o = 0; o < 4; o++) {
      int c = g * 4 + o;
      float kout = acc[j][o] + bias_[j][o];
      float ufc = pf[o][1][j + 1];                      // center tap (ki=1,kj=1)
      float xk = kout * ga1[c] + ufc;
      float xv = xk * b2f(x1[((size_t)b * Cc + c) * HWp + p]) * scaV[b * 64 + c];
      out[((size_t)b * Cc + c) * HWp + p] = f2b(xv);
    }
  }
}

// ---------------- c3 1x1 conv + residual: y = inp + (conv)*beta (fp32 out) ----------------
__global__ void k_c3y(const bf16* __restrict__ xprod, const float* __restrict__ w,
                      const float* __restrict__ bias, const float* __restrict__ beta,
                      const float* __restrict__ inp, float* __restrict__ y) {
  int p = blockIdx.x * 64 + threadIdx.x;
  int o = blockIdx.y * 4 + threadIdx.y;
  int b = blockIdx.z;
  float acc = bias[o];
  const bf16* src = xprod + (size_t)b * Cc * HWp + p;
  const float* wr = w + o * 64;
  for (int k = 0; k < 64; k++) acc += wr[k] * b2f(src[(size_t)k * HWp]);
  size_t oi = ((size_t)b * Cc + o) * HWp + p;
  y[oi] = inp[oi] + acc * beta[o];
}

// ---------------- LayerNorm, fp32 in (y in d_out) -> bf16 ws out ----------------
__global__ void k_ln2(const float* __restrict__ in, const float* __restrict__ w,
                      const float* __restrict__ bb, bf16* __restrict__ out) {
  int idx = blockIdx.x * 256 + threadIdx.x;
  int b = idx / HWp, p = idx - b * HWp;
  const float* src = in + (size_t)b * Cc * HWp + p;
  float s = 0.f, s2 = 0.f;
  for (int c = 0; c < Cc; c++) { float v = src[(size_t)c * HWp]; s += v; s2 += v * v; }
  float mu = s * (1.f / 64.f);
  float var = s2 * (1.f / 64.f) - mu * mu;
  float rs = rsqrtf(fmaxf(var, 0.f) + 1e-6f);
  bf16* dst = out + (size_t)b * Cc * HWp + p;
  for (int c = 0; c < Cc; c++) {
    float v = src[(size_t)c * HWp];
    dst[(size_t)c * HWp] = f2b((v - mu) * rs * w[c] + bb[c]);
  }
}

// ---------------- one DFT pass with transpose: out[c][a] = scale * sum_b in[a][b] e^{i*sgn*2pi*b*c/N}
__global__ __launch_bounds__(256) void k_cpass(
    const bf16* __restrict__ inr, const bf16* __restrict__ ini,
    bf16* __restrict__ outr, bf16* __restrict__ outi,
    float sgn, float scale,
    const float* __restrict__ sclr, const float* __restrict__ scli) {
  int plane = blockIdx.z;
  int a0 = blockIdx.x * 64, c0 = blockIdx.y * 64;
  __shared__ __align__(16) float Lr[32][68], Li[32][68], Lc[32][68], Ls[32][68];
  int t = threadIdx.x;
  int ta = t & 15, tc = t >> 4;
  float ar[4][4], ai[4][4];
  #pragma unroll
  for (int j = 0; j < 4; j++) for (int k = 0; k < 4; k++) { ar[j][k] = 0.f; ai[j][k] = 0.f; }
  const bf16* pr = inr + (size_t)plane * HWp;
  const bf16* pi = ini ? ini + (size_t)plane * HWp : nullptr;
  float srm = sclr ? sclr[plane] : 1.f;
  float sim = scli ? scli[plane] : 1.f;
  for (int b0 = 0; b0 < 160; b0 += 32) {
    __syncthreads();
    for (int i = t; i < 32 * 64; i += 256) {
      int bb = i & 31, aa = i >> 5;
      int a = a0 + aa;
      float vr = 0.f, vi = 0.f;
      if (a < 160) {
        vr = b2f(pr[a * 160 + b0 + bb]) * srm;
        if (pi) vi = b2f(pi[a * 160 + b0 + bb]) * sim;
      }
      Lr[bb][aa] = vr; Li[bb][aa] = vi;
    }
    for (int i = t; i < 32 * 64; i += 256) {
      int cc = i & 63, bb = i >> 6;
      int c = c0 + cc;
      float vc = 0.f, vs = 0.f;
      if (c < 160) {
        int m = ((b0 + bb) * c) % 160;
        float sv, cv;
        __sincosf((float)m * TWO_PI_160, &sv, &cv);
        vc = cv; vs = sv * sgn;
      }
      Lc[bb][cc] = vc; Ls[bb][cc] = vs;
    }
    __syncthreads();
    for (int bb = 0; bb < 32; bb++) {
      float4 x4 = *(const float4*)&Lr[bb][ta * 4];
      float4 y4 = *(const float4*)&Li[bb][ta * 4];
      float4 c4 = *(const float4*)&Lc[bb][tc * 4];
      float4 s4 = *(const float4*)&Ls[bb][tc * 4];
      float xr[4] = {x4.x, x4.y, x4.z, x4.w};
      float xi[4] = {y4.x, y4.y, y4.z, y4.w};
      float cs[4] = {c4.x, c4.y, c4.z, c4.w};
      float sn[4] = {s4.x, s4.y, s4.z, s4.w};
      #pragma unroll
      for (int j = 0; j < 4; j++)
        #pragma unroll
        for (int k = 0; k < 4; k++) {
          ar[j][k] += xr[j] * cs[k] - xi[j] * sn[k];
          ai[j][k] += xr[j] * sn[k] + xi[j] * cs[k];
        }
    }
  }
  for (int k = 0; k < 4; k++) {
    int c = c0 + tc * 4 + k;
    if (c >= 160) continue;
    for (int j = 0; j < 4; j++) {
      int a = a0 + ta * 4 + j;
      if (a >= 160) continue;
      outr[(size_t)plane * HWp + c * 160 + a] = f2b(ar[j][k] * scale);
      outi[(size_t)plane * HWp + c * 160 + a] = f2b(ai[j][k] * scale);
    }
  }
}

// ---------------- final inverse pass, fused |.|, *gamma, += y (fp32 d_out) ----------------
__global__ __launch_bounds__(256) void k_cpass_final(
    const bf16* __restrict__ inr, const bf16* __restrict__ ini,
    float sgn, float scale,
    const float* __restrict__ gamma, float* __restrict__ dout) {
  int plane = blockIdx.z;
  int a0 = blockIdx.x * 64, c0 = blockIdx.y * 64;
  __shared__ __align__(16) float Lr[32][68], Li[32][68], Lc[32][68], Ls[32][68];
  int t = threadIdx.x;
  int ta = t & 15, tc = t >> 4;
  float ar[4][4], ai[4][4];
  #pragma unroll
  for (int j = 0; j < 4; j++) for (int k = 0; k < 4; k++) { ar[j][k] = 0.f; ai[j][k] = 0.f; }
  const bf16* pr = inr + (size_t)plane * HWp;
  const bf16* pi = ini + (size_t)plane * HWp;
  for (int b0 = 0; b0 < 160; b0 += 32) {
    __syncthreads();
    for (int i = t; i < 32 * 64; i += 256) {
      int bb = i & 31, aa = i >> 5;
      int a = a0 + aa;
      float vr = 0.f, vi = 0.f;
      if (a < 160) { vr = b2f(pr[a * 160 + b0 + bb]); vi = b2f(pi[a * 160 + b0 + bb]); }
      Lr[bb][aa] = vr; Li[bb][aa] = vi;
    }
    for (int i = t; i < 32 * 64; i += 256) {
      int cc = i & 63, bb = i >> 6;
      int c = c0 + cc;
      float vc = 0.f, vs = 0.f;
      if (c < 160) {
        int m = ((b0 + bb) * c) % 160;
        float sv, cv;
        __sincosf((float)m * TWO_PI_160, &sv, &cv);
        vc = cv; vs = sv * sgn;
      }
      Lc[bb][cc] = vc; Ls[bb][cc] = vs;
    }
    __syncthreads();
    for (int bb = 0; bb < 32; bb++) {
      float4 x4 = *(const float4*)&Lr[bb][ta * 4];
      float4 y4 = *(const float4*)&Li[bb][ta * 4];
      float4 c4 = *(const float4*)&Lc[bb][tc * 4];
      float4 s4 = *(const float4*)&Ls[bb][tc * 4];
      float xr[4] = {x4.x, x4.y, x4.z, x4.w};
      float xi[4] = {y4.x, y4.y, y4.z, y4.w};
      float cs[4] = {c4.x, c4.y, c4.z, c4.w};
      float sn[4] = {s4.x, s4.y, s4.z, s4.w};
      #pragma unroll
      for (int j = 0; j < 4; j++)
        #pragma unroll
        for (int k = 0; k < 4; k++) {
          ar[j][k] += xr[j] * cs[k] - xi[j] * sn[k];
          ai[j][k] += xr[j] * sn[k] + xi[j] * cs[k];
        }
    }
  }
  int ch = plane & 63;
  float gm = gamma[ch];
  for (int k = 0; k < 4; k++) {
    int c = c0 + tc * 4 + k;          // = h
    if (c >= 160) continue;
    for (int j = 0; j < 4; j++) {
      int a = a0 + ta * 4 + j;        // = w
      if (a >= 160) continue;
      float rr = ar[j][k] * scale, ii = ai[j][k] * scale;
      float z = sqrtf(rr * rr + ii * ii);
      size_t oi = (size_t)plane * HWp + c * 160 + a;
      dout[oi] = dout[oi] + z * gm;   // dout currently holds y
    }
  }
}

// ---------------- fc1 (128->256) + simple_gate ----------------
__global__ void k_fc1gate(const bf16* __restrict__ Fr, const bf16* __restrict__ Fi,
                          const float* __restrict__ w, const float* __restrict__ bias,
                          bf16* __restrict__ G1, bf16* __restrict__ G2) {
  int p = blockIdx.x * 64 + threadIdx.x;
  int o = blockIdx.y * 4 + threadIdx.y;   // 0..127
  int b = blockIdx.z;
  float acc1 = bias[o], acc2 = bias[o + 128];
  const float* w1 = w + (size_t)o * 128;
  const float* w2 = w + (size_t)(o + 128) * 128;
  const bf16* fr = Fr + (size_t)b * Cc * HWp + p;
  const bf16* fi = Fi + (size_t)b * Cc * HWp + p;
  for (int k = 0; k < 64; k++) {
    float v = b2f(fr[(size_t)k * HWp]);
    acc1 += w1[k] * v; acc2 += w2[k] * v;
  }
  for (int k = 0; k < 64; k++) {
    float v = b2f(fi[(size_t)k * HWp]);
    acc1 += w1[64 + k] * v; acc2 += w2[64 + k] * v;
  }
  float gv = acc1 * acc2;
  if (o < 64) G1[((size_t)b * Cc + o) * HWp + p] = f2b(gv);
  else        G2[((size_t)b * Cc + o - 64) * HWp + p] = f2b(gv);
}

// ---------------- fc2 (128->128), split output into r / i planes ----------------
__global__ void k_fc2(const bf16* __restrict__ G1, const bf16* __restrict__ G2,
                      const float* __restrict__ w, const float* __restrict__ bias,
                      bf16* __restrict__ Or, bf16* __restrict__ Oi) {
  int p = blockIdx.x * 64 + threadIdx.x;
  int o = blockIdx.y * 4 + threadIdx.y;   // 0..127
  int b = blockIdx.z;
  float acc = bias[o];
  const float* wr = w + (size_t)o * 128;
  const bf16* g1 = G1 + (size_t)b * Cc * HWp + p;
  const bf16* g2 = G2 + (size_t)b * Cc * HWp + p;
  for (int k = 0; k < 64; k++) acc += wr[k] * b2f(g1[(size_t)k * HWp]);
  for (int k = 0; k < 64; k++) acc += wr[64 + k] * b2f(g2[(size_t)k * HWp]);
  if (o < 64) Or[((size_t)b * Cc + o) * HWp + p] = f2b(acc);
  else        Oi[((size_t)b * Cc + o - 64) * HWp + p] = f2b(acc);
}

extern "C" void kernel_launch(void* const* d_in, const int* in_sizes, int n_in,
                              void* d_out, int out_size, void* d_ws, size_t ws_size,
                              hipStream_t stream) {
  const float* inp   = (const float*)d_in[0];
  const float* n1w   = (const float*)d_in[1];
  const float* n1b   = (const float*)d_in[2];
  const float* n2w   = (const float*)d_in[3];
  const float* n2b   = (const float*)d_in[4];
  const float* scaw  = (const float*)d_in[5];
  const float* scab  = (const float*)d_in[6];
  const float* c11aw = (const float*)d_in[7];
  const float* c11ab = (const float*)d_in[8];
  const float* c11bw = (const float*)d_in[9];
  const float* c11bb = (const float*)d_in[10];
  const float* c1w   = (const float*)d_in[11];
  const float* c1b   = (const float*)d_in[12];
  const float* c21w  = (const float*)d_in[13];
  const float* c21b  = (const float*)d_in[14];
  const float* c2aw  = (const float*)d_in[15];
  const float* c2ab  = (const float*)d_in[16];
  const float* c2cw  = (const float*)d_in[17];
  const float* c2cb  = (const float*)d_in[18];
  const float* c211w = (const float*)d_in[19];
  const float* c211b = (const float*)d_in[20];
  const float* c3w   = (const float*)d_in[21];
  const float* c3b   = (const float*)d_in[22];
  const float* kbw   = (const float*)d_in[23];
  const float* kbb   = (const float*)d_in[24];
  const float* ga1   = (const float*)d_in[25];
  const float* attg  = (const float*)d_in[26];
  const float* beta  = (const float*)d_in[27];
  const float* gamma = (const float*)d_in[28];
  const float* fc1w  = (const float*)d_in[29];
  const float* fc1b  = (const float*)d_in[30];
  const float* fc2w  = (const float*)d_in[31];
  const float* fc2b  = (const float*)d_in[32];
  const float* fscaw = (const float*)d_in[33];
  const float* fscab = (const float*)d_in[34];

  const size_t S = (size_t)Bn * Cc * HWp;   // 3,276,800 elements per slot
  bf16* A  = (bf16*)d_ws;                   // 4 bf16 slots = 26.2 MB total
  bf16* Bs = A + S;
  bf16* Cs = A + 2 * S;
  bf16* Ds = A + 3 * S;
  float* smalls = (float*)(A + 4 * S);      // 768 floats = 3 KB
  float* xm   = smalls;
  float* scaV = smalls + 128;
  float* rmv  = smalls + 256;
  float* imv  = smalls + 384;
  float* sra  = smalls + 512;
  float* sia  = smalls + 640;
  bf16* gbuf = Bs;            // [B,32,HW] (first half of Bs)
  bf16* attb = Bs + S / 2;    // [B,32,HW] (second half of Bs)
  float* yb  = (float*)d_out; // y lives in d_out (fp32)

  dim3 blk(64, 4, 1);

  k_ln<<<dim3(200), dim3(256), 0, stream>>>(inp, n1w, n1b, A);          // A = x
  k_meanhw<<<dim3(128), dim3(256), 0, stream>>>(A, xm);
  k_small_mv<<<dim3(1), dim3(128), 0, stream>>>(xm, scaw, scab, scaV, 0);
  k_conv1x1<<<dim3(400, 16, Bn), blk, 0, stream>>>(A, c11aw, c11ab, Bs, 64, 64);   // B = t1
  k_c11b<<<dim3(400, 16, Bn), blk, 0, stream>>>(Bs, c11bw, c11bb, Cs);             // C = x1 (B dead)
  k_c2a<<<dim3(400, 8, Bn), blk, 0, stream>>>(A, c2aw, c2ab, gbuf);                // B.lo = g
  k_att<<<dim3(400, 8, Bn), blk, 0, stream>>>(gbuf, A, c2cw, c2cb, c211w, c211b, attg, attb); // B.hi = att
  k_conv1x1<<<dim3(400, 16, Bn), blk, 0, stream>>>(A, c1w, c1b, Ds, 64, 64);       // D = t2 (A dead after)
  k_c21dw<<<dim3(400, 16, Bn), blk, 0, stream>>>(Ds, c21w, c21b, A);               // A = uf
  k_kba<<<dim3(3, 160, Bn), dim3(256), 0, stream>>>(A, attb, Cs, scaV, kbw, kbb, ga1, Ds); // D = xprod
  k_c3y<<<dim3(400, 16, Bn), blk, 0, stream>>>(Ds, c3w, c3b, beta, inp, yb);       // d_out = y (fp32)
  k_ln2<<<dim3(200), dim3(256), 0, stream>>>(yb, n2w, n2b, A);                     // A = X
  // forward FFT2: pass over W ([h][w] -> [u][h]), then over H ([u][h] -> [v][u])
  k_cpass<<<dim3(3, 3, Bn * Cc), dim3(256), 0, stream>>>(A, (const bf16*)nullptr, Bs, Cs, -1.f, SCL, nullptr, nullptr); // B,C = F1 (A dead)
  k_cpass<<<dim3(3, 3, Bn * Cc), dim3(256), 0, stream>>>(Bs, Cs, Ds, A, -1.f, SCL, nullptr, nullptr);                   // D,A = F2
  k_fc1gate<<<dim3(400, 32, Bn), blk, 0, stream>>>(Ds, A, fc1w, fc1b, Bs, Cs);     // B,C = gated
  k_fc2<<<dim3(400, 32, Bn), blk, 0, stream>>>(Bs, Cs, fc2w, fc2b, Ds, A);         // D = r, A = i
  k_meanhw<<<dim3(128), dim3(256), 0, stream>>>(Ds, rmv);
  k_meanhw<<<dim3(128), dim3(256), 0, stream>>>(A, imv);
  k_small_mv<<<dim3(1), dim3(128), 0, stream>>>(rmv, fscaw, fscab, sra, 1);
  k_small_mv<<<dim3(1), dim3(128), 0, stream>>>(imv, fscaw, fscab, sia, 1);
  // inverse FFT2 with per-plane (1+ra)/(1+ia) scaling fused into first pass
  k_cpass<<<dim3(3, 3, Bn * Cc), dim3(256), 0, stream>>>(Ds, A, Bs, Cs, 1.f, SCL, sra, sia);  // B,C
  k_cpass_final<<<dim3(3, 3, Bn * Cc), dim3(256), 0, stream>>>(Bs, Cs, 1.f, SCL, gamma, yb);  // d_out = y + |z|*gamma
}

// Round 6
// 1955.262 us; speedup vs baseline: 1.0046x; 1.0046x over previous
//
#include <hip/hip_runtime.h>
#include <hip/hip_bf16.h>

typedef __hip_bfloat16 bf16;

#define Hh 160
#define Wd 160
#define HWp (Hh*Wd)       // 25600
#define Bn 2
#define Cc 64
#define NPIX (Bn*HWp)     // 51200
#define SCL 0.07905694150420949f   // 1/sqrt(160)
#define TWO_PI_160 0.039269908169872414f  // 2*pi/160

static __device__ __forceinline__ float b2f(bf16 x) { return __bfloat162float(x); }
static __device__ __forceinline__ bf16 f2b(float f) { return __float2bfloat16(f); }
static __device__ __forceinline__ float bfu(unsigned short u) {
  union { unsigned int i; float f; } z; z.i = ((unsigned int)u) << 16; return z.f;
}

// ---------------- LayerNorm over channel dim (per pixel), fp32 in -> bf16 out ----------------
__global__ void k_ln(const float* __restrict__ in, const float* __restrict__ w,
                     const float* __restrict__ bb, bf16* __restrict__ out) {
  int idx = blockIdx.x * 256 + threadIdx.x;   // grid covers exactly NPIX
  int b = idx / HWp, p = idx - b * HWp;
  const float* src = in + (size_t)b * Cc * HWp + p;
  float s = 0.f, s2 = 0.f;
  for (int c = 0; c < Cc; c++) { float v = src[(size_t)c * HWp]; s += v; s2 += v * v; }
  float mu = s * (1.f / 64.f);
  float var = s2 * (1.f / 64.f) - mu * mu;
  float rs = rsqrtf(fmaxf(var, 0.f) + 1e-6f);
  bf16* dst = out + (size_t)b * Cc * HWp + p;
  for (int c = 0; c < Cc; c++) {
    float v = src[(size_t)c * HWp];
    dst[(size_t)c * HWp] = f2b((v - mu) * rs * w[c] + bb[c]);
  }
}

// ---------------- mean over HW per (b,c) plane (bf16 in) ----------------
__global__ void k_meanhw(const bf16* __restrict__ in, float* __restrict__ out) {
  int bc = blockIdx.x;
  const bf16* src = in + (size_t)bc * HWp;
  int t = threadIdx.x;
  float s = 0.f;
  for (int i = t; i < HWp; i += 256) s += b2f(src[i]);
  __shared__ float sm[256];
  sm[t] = s; __syncthreads();
  for (int off = 128; off; off >>= 1) { if (t < off) sm[t] += sm[t + off]; __syncthreads(); }
  if (t == 0) out[bc] = sm[0] * (1.f / HWp);
}

// ---------------- small matvec: out[b,o] = (addone) + W[o,:]·xin[b,:] + bias[o] ----------------
__global__ void k_small_mv(const float* __restrict__ xin, const float* __restrict__ w,
                           const float* __restrict__ bias, float* __restrict__ out, int addone) {
  int t = threadIdx.x;              // 128 threads
  int b = t >> 6, o = t & 63;
  float acc = bias[o];
  for (int k = 0; k < 64; k++) acc += w[o * 64 + k] * xin[b * 64 + k];
  out[t] = addone ? (1.f + acc) : acc;
}

// ---------------- generic 1x1 conv, bf16 ws in/out, fp32 weights ----------------
__global__ void k_conv1x1(const bf16* __restrict__ in, const float* __restrict__ w,
                          const float* __restrict__ bias, bf16* __restrict__ out,
                          int Cin, int Cout) {
  int p = blockIdx.x * 64 + threadIdx.x;
  int o = blockIdx.y * 4 + threadIdx.y;
  int b = blockIdx.z;
  float acc = bias[o];
  const bf16* src = in + (size_t)b * Cin * HWp + p;
  const float* wr = w + (size_t)o * Cin;
  for (int k = 0; k < Cin; k++) acc += wr[k] * b2f(src[(size_t)k * HWp]);
  out[((size_t)b * Cout + o) * HWp + p] = f2b(acc);
}

// ---------------- c11b: grouped 5x5 conv, groups=16 (4ch/group), pad 2 ----------------
__global__ void k_c11b(const bf16* __restrict__ in, const float* __restrict__ w,
                       const float* __restrict__ bias, bf16* __restrict__ out) {
  int p = blockIdx.x * 64 + threadIdx.x;
  int o = blockIdx.y * 4 + threadIdx.y;
  int b = blockIdx.z;
  int h = p / Wd, x = p - h * Wd;
  int gb = (o >> 2) << 2;
  float acc = bias[o];
  for (int ci = 0; ci < 4; ci++) {
    const bf16* src = in + ((size_t)b * Cc + gb + ci) * HWp;
    for (int ki = 0; ki < 5; ki++) {
      int hh = h + ki - 2; if ((unsigned)hh >= Hh) continue;
      for (int kj = 0; kj < 5; kj++) {
        int ww = x + kj - 2; if ((unsigned)ww >= Wd) continue;
        acc += w[((o * 4 + ci) * 5 + ki) * 5 + kj] * b2f(src[hh * Wd + ww]);
      }
    }
  }
  out[((size_t)b * Cc + o) * HWp + p] = f2b(acc);
}

// ---------------- c2a: grouped 3x3, 64->32, groups=32 (2 in-ch/group), pad 1 ----------------
__global__ void k_c2a(const bf16* __restrict__ in, const float* __restrict__ w,
                      const float* __restrict__ bias, bf16* __restrict__ out) {
  int p = blockIdx.x * 64 + threadIdx.x;
  int o = blockIdx.y * 4 + threadIdx.y;   // 0..31
  int b = blockIdx.z;
  int h = p / Wd, x = p - h * Wd;
  float acc = bias[o];
  for (int ci = 0; ci < 2; ci++) {
    const bf16* src = in + ((size_t)b * Cc + o * 2 + ci) * HWp;
    for (int ki = 0; ki < 3; ki++) {
      int hh = h + ki - 1; if ((unsigned)hh >= Hh) continue;
      for (int kj = 0; kj < 3; kj++) {
        int ww = x + kj - 1; if ((unsigned)ww >= Wd) continue;
        acc += w[((o * 2 + ci) * 3 + ki) * 3 + kj] * b2f(src[hh * Wd + ww]);
      }
    }
  }
  out[((size_t)b * 32 + o) * HWp + p] = f2b(acc);
}

// ---------------- att = c2c(gate(g))*attgamma + c211(x) ----------------
__global__ void k_att(const bf16* __restrict__ g, const bf16* __restrict__ x,
                      const float* __restrict__ c2cw, const float* __restrict__ c2cb,
                      const float* __restrict__ c211w, const float* __restrict__ c211b,
                      const float* __restrict__ attg, bf16* __restrict__ att) {
  int p = blockIdx.x * 64 + threadIdx.x;
  int s = blockIdx.y * 4 + threadIdx.y;   // 0..31
  int b = blockIdx.z;
  float a1 = c2cb[s];
  const bf16* gs = g + (size_t)b * 32 * HWp + p;
  for (int k = 0; k < 16; k++)
    a1 += c2cw[s * 16 + k] * b2f(gs[(size_t)k * HWp]) * b2f(gs[(size_t)(16 + k) * HWp]);
  float acc = a1 * attg[s] + c211b[s];
  const bf16* xs = x + (size_t)b * Cc * HWp + p;
  for (int c = 0; c < Cc; c++) acc += c211w[s * 64 + c] * b2f(xs[(size_t)c * HWp]);
  att[((size_t)b * 32 + s) * HWp + p] = f2b(acc);
}

// ---------------- depthwise 3x3, pad 1 ----------------
__global__ void k_c21dw(const bf16* __restrict__ in, const float* __restrict__ w,
                        const float* __restrict__ bias, bf16* __restrict__ out) {
  int p = blockIdx.x * 64 + threadIdx.x;
  int c = blockIdx.y * 4 + threadIdx.y;
  int b = blockIdx.z;
  int h = p / Wd, x = p - h * Wd;
  float acc = bias[c];
  const bf16* src = in + ((size_t)b * Cc + c) * HWp;
  for (int ki = 0; ki < 3; ki++) {
    int hh = h + ki - 1; if ((unsigned)hh >= Hh) continue;
    for (int kj = 0; kj < 3; kj++) {
      int ww = x + kj - 1; if ((unsigned)ww >= Wd) continue;
      acc += w[c * 9 + ki * 3 + kj] * b2f(src[hh * Wd + ww]);
    }
  }
  out[((size_t)b * Cc + c) * HWp + p] = f2b(acc);
}

// ---------------- KBA fused: out = ((kba+bias)*ga1 + uf) * x1 * sca ----------------
// tile = 64 pixels of one row. thread: g=t&15 (group), pq=t>>4 (4 px each).
// Patch window in registers (s-invariant). Weights staged fp32 in LDS as
// [si][d][g][o] so each tap's float4 lands on banks (g*4..g*4+3): the 16
// g-addresses tile all 32 banks twice -> 2-way aliasing = free (m136).
__global__ __launch_bounds__(256) void k_kba(
    const bf16* __restrict__ uf, const bf16* __restrict__ att,
    const bf16* __restrict__ x1, const float* __restrict__ scaV,
    const float* __restrict__ kbw, const float* __restrict__ kbb,
    const float* __restrict__ ga1, bf16* __restrict__ out) {
  __shared__ unsigned short patchL[64 * 3 * 66];        // 25344 B, bf16 [c][ki][col]
  __shared__ float attL[64][33];                        // 8448 B
  __shared__ __align__(16) float kwL[2 * 36 * 16 * 4];  // 18432 B, [si][d][g][o]
  int b = blockIdx.z, h = blockIdx.y;
  int w0 = blockIdx.x * 64;
  int width = min(64, Wd - w0);
  int t = threadIdx.x;
  const unsigned short* uf_u = (const unsigned short*)uf;
  for (int i = t; i < 64 * 3 * 66; i += 256) {
    int c = i / 198, rem = i - c * 198;
    int r = rem / 66, col = rem - r * 66;
    int hh = h + r - 1, ww = w0 + col - 1;
    unsigned short v = 0;
    if ((unsigned)hh < Hh && (unsigned)ww < Wd)
      v = uf_u[((size_t)b * Cc + c) * HWp + hh * Wd + ww];
    patchL[i] = v;
  }
  for (int i = t; i < 64 * 32; i += 256) {
    int px = i & 63, s = i >> 6;
    float v = 0.f;
    if (px < width) v = b2f(att[((size_t)b * 32 + s) * HWp + h * Wd + w0 + px]);
    attL[px][s] = v;
  }
  __syncthreads();
  int g = t & 15, pq = t >> 4;
  // hoist the 4ci x 3ki x 6col patch window into registers (s-invariant)
  float pf[4][3][6];
  #pragma unroll
  for (int ci = 0; ci < 4; ci++)
    #pragma unroll
    for (int ki = 0; ki < 3; ki++) {
      const unsigned int* pr32 =
          (const unsigned int*)&patchL[(g * 4 + ci) * 198 + ki * 66 + 4 * pq];  // 4B aligned
      #pragma unroll
      for (int m2 = 0; m2 < 3; m2++) {
        unsigned int u = pr32[m2];
        pf[ci][ki][2 * m2 + 0] = bfu((unsigned short)(u & 0xffffu));
        pf[ci][ki][2 * m2 + 1] = bfu((unsigned short)(u >> 16));
      }
    }
  float acc[4][4];
  #pragma unroll
  for (int j = 0; j < 4; j++)
    #pragma unroll
    for (int o = 0; o < 4; o++) acc[j][o] = 0.f;

  for (int sc = 0; sc < 16; sc++) {        // 2 sets per chunk
    __syncthreads();
    // dest i = si*2304 + d*64 + g*4 + o  (lane-consecutive writes, conflict-free)
    for (int i = t; i < 2 * 2304; i += 256) {
      int o = i & 3, gg = (i >> 2) & 15, rest = i >> 6;   // rest = si*36 + d
      int dd = rest % 36, si = rest / 36;
      kwL[i] = kbw[(sc * 2 + si) * 2304 + gg * 144 + o * 36 + dd];
    }
    __syncthreads();
    #pragma unroll
    for (int si = 0; si < 2; si++) {
      int s = sc * 2 + si;
      float a0 = attL[4 * pq + 0][s], a1 = attL[4 * pq + 1][s];
      float a2 = attL[4 * pq + 2][s], a3 = attL[4 * pq + 3][s];
      const float* wbase = &kwL[si * 2304 + g * 4];
      #pragma unroll
      for (int ci = 0; ci < 4; ci++)
        #pragma unroll
        for (int ki = 0; ki < 3; ki++)
          #pragma unroll
          for (int kj = 0; kj < 3; kj++) {
            int d = ci * 9 + ki * 3 + kj;
            float4 wv = *(const float4*)&wbase[d * 64];
            float p0 = pf[ci][ki][kj + 0] * a0;
            float p1 = pf[ci][ki][kj + 1] * a1;
            float p2 = pf[ci][ki][kj + 2] * a2;
            float p3 = pf[ci][ki][kj + 3] * a3;
            acc[0][0] += p0 * wv.x; acc[0][1] += p0 * wv.y; acc[0][2] += p0 * wv.z; acc[0][3] += p0 * wv.w;
            acc[1][0] += p1 * wv.x; acc[1][1] += p1 * wv.y; acc[1][2] += p1 * wv.z; acc[1][3] += p1 * wv.w;
            acc[2][0] += p2 * wv.x; acc[2][1] += p2 * wv.y; acc[2][2] += p2 * wv.z; acc[2][3] += p2 * wv.w;
            acc[3][0] += p3 * wv.x; acc[3][1] += p3 * wv.y; acc[3][2] += p3 * wv.z; acc[3][3] += p3 * wv.w;
          }
    }
  }
  // bias = att @ kb_b
  float bias_[4][4];
  #pragma unroll
  for (int j = 0; j < 4; j++)
    #pragma unroll
    for (int o = 0; o < 4; o++) bias_[j][o] = 0.f;
  for (int s = 0; s < 32; s++) {
    float kv[4];
    #pragma unroll
    for (int o = 0; o < 4; o++) kv[o] = kbb[s * 64 + g * 4 + o];
    #pragma unroll
    for (int j = 0; j < 4; j++) {
      float av = attL[4 * pq + j][s];
      #pragma unroll
      for (int o = 0; o < 4; o++) bias_[j][o] += av * kv[o];
    }
  }
  #pragma unroll
  for (int j = 0; j < 4; j++) {
    int px = 4 * pq + j;
    if (px >= width) continue;
    int p = h * Wd + w0 + px;
    #pragma unroll
    for (int o = 0; o < 4; o++) {
      int c = g * 4 + o;
      float kout = acc[j][o] + bias_[j][o];
      float ufc = pf[o][1][j + 1];                      // center tap (ki=1,kj=1)
      float xk = kout * ga1[c] + ufc;
      float xv = xk * b2f(x1[((size_t)b * Cc + c) * HWp + p]) * scaV[b * 64 + c];
      out[((size_t)b * Cc + c) * HWp + p] = f2b(xv);
    }
  }
}

// ---------------- c3 1x1 conv + residual: y = inp + (conv)*beta (fp32 out) ----------------
__global__ void k_c3y(const bf16* __restrict__ xprod, const float* __restrict__ w,
                      const float* __restrict__ bias, const float* __restrict__ beta,
                      const float* __restrict__ inp, float* __restrict__ y) {
  int p = blockIdx.x * 64 + threadIdx.x;
  int o = blockIdx.y * 4 + threadIdx.y;
  int b = blockIdx.z;
  float acc = bias[o];
  const bf16* src = xprod + (size_t)b * Cc * HWp + p;
  const float* wr = w + o * 64;
  for (int k = 0; k < 64; k++) acc += wr[k] * b2f(src[(size_t)k * HWp]);
  size_t oi = ((size_t)b * Cc + o) * HWp + p;
  y[oi] = inp[oi] + acc * beta[o];
}

// ---------------- LayerNorm, fp32 in (y in d_out) -> bf16 ws out ----------------
__global__ void k_ln2(const float* __restrict__ in, const float* __restrict__ w,
                      const float* __restrict__ bb, bf16* __restrict__ out) {
  int idx = blockIdx.x * 256 + threadIdx.x;
  int b = idx / HWp, p = idx - b * HWp;
  const float* src = in + (size_t)b * Cc * HWp + p;
  float s = 0.f, s2 = 0.f;
  for (int c = 0; c < Cc; c++) { float v = src[(size_t)c * HWp]; s += v; s2 += v * v; }
  float mu = s * (1.f / 64.f);
  float var = s2 * (1.f / 64.f) - mu * mu;
  float rs = rsqrtf(fmaxf(var, 0.f) + 1e-6f);
  bf16* dst = out + (size_t)b * Cc * HWp + p;
  for (int c = 0; c < Cc; c++) {
    float v = src[(size_t)c * HWp];
    dst[(size_t)c * HWp] = f2b((v - mu) * rs * w[c] + bb[c]);
  }
}

// ---------------- one DFT pass with transpose: out[c][a] = scale * sum_b in[a][b] e^{i*sgn*2pi*b*c/N}
__global__ __launch_bounds__(256) void k_cpass(
    const bf16* __restrict__ inr, const bf16* __restrict__ ini,
    bf16* __restrict__ outr, bf16* __restrict__ outi,
    float sgn, float scale,
    const float* __restrict__ sclr, const float* __restrict__ scli) {
  int plane = blockIdx.z;
  int a0 = blockIdx.x * 64, c0 = blockIdx.y * 64;
  __shared__ __align__(16) float Lr[32][68], Li[32][68], Lc[32][68], Ls[32][68];
  int t = threadIdx.x;
  int ta = t & 15, tc = t >> 4;
  float ar[4][4], ai[4][4];
  #pragma unroll
  for (int j = 0; j < 4; j++) for (int k = 0; k < 4; k++) { ar[j][k] = 0.f; ai[j][k] = 0.f; }
  const bf16* pr = inr + (size_t)plane * HWp;
  const bf16* pi = ini ? ini + (size_t)plane * HWp : nullptr;
  float srm = sclr ? sclr[plane] : 1.f;
  float sim = scli ? scli[plane] : 1.f;
  for (int b0 = 0; b0 < 160; b0 += 32) {
    __syncthreads();
    for (int i = t; i < 32 * 64; i += 256) {
      int bb = i & 31, aa = i >> 5;
      int a = a0 + aa;
      float vr = 0.f, vi = 0.f;
      if (a < 160) {
        vr = b2f(pr[a * 160 + b0 + bb]) * srm;
        if (pi) vi = b2f(pi[a * 160 + b0 + bb]) * sim;
      }
      Lr[bb][aa] = vr; Li[bb][aa] = vi;
    }
    for (int i = t; i < 32 * 64; i += 256) {
      int cc = i & 63, bb = i >> 6;
      int c = c0 + cc;
      float vc = 0.f, vs = 0.f;
      if (c < 160) {
        int m = ((b0 + bb) * c) % 160;
        float sv, cv;
        __sincosf((float)m * TWO_PI_160, &sv, &cv);
        vc = cv; vs = sv * sgn;
      }
      Lc[bb][cc] = vc; Ls[bb][cc] = vs;
    }
    __syncthreads();
    for (int bb = 0; bb < 32; bb++) {
      float4 x4 = *(const float4*)&Lr[bb][ta * 4];
      float4 y4 = *(const float4*)&Li[bb][ta * 4];
      float4 c4 = *(const float4*)&Lc[bb][tc * 4];
      float4 s4 = *(const float4*)&Ls[bb][tc * 4];
      float xr[4] = {x4.x, x4.y, x4.z, x4.w};
      float xi[4] = {y4.x, y4.y, y4.z, y4.w};
      float cs[4] = {c4.x, c4.y, c4.z, c4.w};
      float sn[4] = {s4.x, s4.y, s4.z, s4.w};
      #pragma unroll
      for (int j = 0; j < 4; j++)
        #pragma unroll
        for (int k = 0; k < 4; k++) {
          ar[j][k] += xr[j] * cs[k] - xi[j] * sn[k];
          ai[j][k] += xr[j] * sn[k] + xi[j] * cs[k];
        }
    }
  }
  for (int k = 0; k < 4; k++) {
    int c = c0 + tc * 4 + k;
    if (c >= 160) continue;
    for (int j = 0; j < 4; j++) {
      int a = a0 + ta * 4 + j;
      if (a >= 160) continue;
      outr[(size_t)plane * HWp + c * 160 + a] = f2b(ar[j][k] * scale);
      outi[(size_t)plane * HWp + c * 160 + a] = f2b(ai[j][k] * scale);
    }
  }
}

// ---------------- final inverse pass, fused |.|, *gamma, += y (fp32 d_out) ----------------
__global__ __launch_bounds__(256) void k_cpass_final(
    const bf16* __restrict__ inr, const bf16* __restrict__ ini,
    float sgn, float scale,
    const float* __restrict__ gamma, float* __restrict__ dout) {
  int plane = blockIdx.z;
  int a0 = blockIdx.x * 64, c0 = blockIdx.y * 64;
  __shared__ __align__(16) float Lr[32][68], Li[32][68], Lc[32][68], Ls[32][68];
  int t = threadIdx.x;
  int ta = t & 15, tc = t >> 4;
  float ar[4][4], ai[4][4];
  #pragma unroll
  for (int j = 0; j < 4; j++) for (int k = 0; k < 4; k++) { ar[j][k] = 0.f; ai[j][k] = 0.f; }
  const bf16* pr = inr + (size_t)plane * HWp;
  const bf16* pi = ini + (size_t)plane * HWp;
  for (int b0 = 0; b0 < 160; b0 += 32) {
    __syncthreads();
    for (int i = t; i < 32 * 64; i += 256) {
      int bb = i & 31, aa = i >> 5;
      int a = a0 + aa;
      float vr = 0.f, vi = 0.f;
      if (a < 160) { vr = b2f(pr[a * 160 + b0 + bb]); vi = b2f(pi[a * 160 + b0 + bb]); }
      Lr[bb][aa] = vr; Li[bb][aa] = vi;
    }
    for (int i = t; i < 32 * 64; i += 256) {
      int cc = i & 63, bb = i >> 6;
      int c = c0 + cc;
      float vc = 0.f, vs = 0.f;
      if (c < 160) {
        int m = ((b0 + bb) * c) % 160;
        float sv, cv;
        __sincosf((float)m * TWO_PI_160, &sv, &cv);
        vc = cv; vs = sv * sgn;
      }
      Lc[bb][cc] = vc; Ls[bb][cc] = vs;
    }
    __syncthreads();
    for (int bb = 0; bb < 32; bb++) {
      float4 x4 = *(const float4*)&Lr[bb][ta * 4];
      float4 y4 = *(const float4*)&Li[bb][ta * 4];
      float4 c4 = *(const float4*)&Lc[bb][tc * 4];
      float4 s4 = *(const float4*)&Ls[bb][tc * 4];
      float xr[4] = {x4.x, x4.y, x4.z, x4.w};
      float xi[4] = {y4.x, y4.y, y4.z, y4.w};
      float cs[4] = {c4.x, c4.y, c4.z, c4.w};
      float sn[4] = {s4.x, s4.y, s4.z, s4.w};
      #pragma unroll
      for (int j = 0; j < 4; j++)
        #pragma unroll
        for (int k = 0; k < 4; k++) {
          ar[j][k] += xr[j] * cs[k] - xi[j] * sn[k];
          ai[j][k] += xr[j] * sn[k] + xi[j] * cs[k];
        }
    }
  }
  int ch = plane & 63;
  float gm = gamma[ch];
  for (int k = 0; k < 4; k++) {
    int c = c0 + tc * 4 + k;          // = h
    if (c >= 160) continue;
    for (int j = 0; j < 4; j++) {
      int a = a0 + ta * 4 + j;        // = w
      if (a >= 160) continue;
      float rr = ar[j][k] * scale, ii = ai[j][k] * scale;
      float z = sqrtf(rr * rr + ii * ii);
      size_t oi = (size_t)plane * HWp + c * 160 + a;
      dout[oi] = dout[oi] + z * gm;   // dout currently holds y
    }
  }
}

// ---------------- fc1 (128->256) + simple_gate ----------------
__global__ void k_fc1gate(const bf16* __restrict__ Fr, const bf16* __restrict__ Fi,
                          const float* __restrict__ w, const float* __restrict__ bias,
                          bf16* __restrict__ G1, bf16* __restrict__ G2) {
  int p = blockIdx.x * 64 + threadIdx.x;
  int o = blockIdx.y * 4 + threadIdx.y;   // 0..127
  int b = blockIdx.z;
  float acc1 = bias[o], acc2 = bias[o + 128];
  const float* w1 = w + (size_t)o * 128;
  const float* w2 = w + (size_t)(o + 128) * 128;
  const bf16* fr = Fr + (size_t)b * Cc * HWp + p;
  const bf16* fi = Fi + (size_t)b * Cc * HWp + p;
  for (int k = 0; k < 64; k++) {
    float v = b2f(fr[(size_t)k * HWp]);
    acc1 += w1[k] * v; acc2 += w2[k] * v;
  }
  for (int k = 0; k < 64; k++) {
    float v = b2f(fi[(size_t)k * HWp]);
    acc1 += w1[64 + k] * v; acc2 += w2[64 + k] * v;
  }
  float gv = acc1 * acc2;
  if (o < 64) G1[((size_t)b * Cc + o) * HWp + p] = f2b(gv);
  else        G2[((size_t)b * Cc + o - 64) * HWp + p] = f2b(gv);
}

// ---------------- fc2 (128->128), split output into r / i planes ----------------
__global__ void k_fc2(const bf16* __restrict__ G1, const bf16* __restrict__ G2,
                      const float* __restrict__ w, const float* __restrict__ bias,
                      bf16* __restrict__ Or, bf16* __restrict__ Oi) {
  int p = blockIdx.x * 64 + threadIdx.x;
  int o = blockIdx.y * 4 + threadIdx.y;   // 0..127
  int b = blockIdx.z;
  float acc = bias[o];
  const float* wr = w + (size_t)o * 128;
  const bf16* g1 = G1 + (size_t)b * Cc * HWp + p;
  const bf16* g2 = G2 + (size_t)b * Cc * HWp + p;
  for (int k = 0; k < 64; k++) acc += wr[k] * b2f(g1[(size_t)k * HWp]);
  for (int k = 0; k < 64; k++) acc += wr[64 + k] * b2f(g2[(size_t)k * HWp]);
  if (o < 64) Or[((size_t)b * Cc + o) * HWp + p] = f2b(acc);
  else        Oi[((size_t)b * Cc + o - 64) * HWp + p] = f2b(acc);
}

extern "C" void kernel_launch(void* const* d_in, const int* in_sizes, int n_in,
                              void* d_out, int out_size, void* d_ws, size_t ws_size,
                              hipStream_t stream) {
  const float* inp   = (const float*)d_in[0];
  const float* n1w   = (const float*)d_in[1];
  const float* n1b   = (const float*)d_in[2];
  const float* n2w   = (const float*)d_in[3];
  const float* n2b   = (const float*)d_in[4];
  const float* scaw  = (const float*)d_in[5];
  const float* scab  = (const float*)d_in[6];
  const float* c11aw = (const float*)d_in[7];
  const float* c11ab = (const float*)d_in[8];
  const float* c11bw = (const float*)d_in[9];
  const float* c11bb = (const float*)d_in[10];
  const float* c1w   = (const float*)d_in[11];
  const float* c1b   = (const float*)d_in[12];
  const float* c21w  = (const float*)d_in[13];
  const float* c21b  = (const float*)d_in[14];
  const float* c2aw  = (const float*)d_in[15];
  const float* c2ab  = (const float*)d_in[16];
  const float* c2cw  = (const float*)d_in[17];
  const float* c2cb  = (const float*)d_in[18];
  const float* c211w = (const float*)d_in[19];
  const float* c211b = (const float*)d_in[20];
  const float* c3w   = (const float*)d_in[21];
  const float* c3b   = (const float*)d_in[22];
  const float* kbw   = (const float*)d_in[23];
  const float* kbb   = (const float*)d_in[24];
  const float* ga1   = (const float*)d_in[25];
  const float* attg  = (const float*)d_in[26];
  const float* beta  = (const float*)d_in[27];
  const float* gamma = (const float*)d_in[28];
  const float* fc1w  = (const float*)d_in[29];
  const float* fc1b  = (const float*)d_in[30];
  const float* fc2w  = (const float*)d_in[31];
  const float* fc2b  = (const float*)d_in[32];
  const float* fscaw = (const float*)d_in[33];
  const float* fscab = (const float*)d_in[34];

  const size_t S = (size_t)Bn * Cc * HWp;   // 3,276,800 elements per slot
  bf16* A  = (bf16*)d_ws;                   // 4 bf16 slots = 26.2 MB total
  bf16* Bs = A + S;
  bf16* Cs = A + 2 * S;
  bf16* Ds = A + 3 * S;
  float* smalls = (float*)(A + 4 * S);      // 768 floats = 3 KB
  float* xm   = smalls;
  float* scaV = smalls + 128;
  float* rmv  = smalls + 256;
  float* imv  = smalls + 384;
  float* sra  = smalls + 512;
  float* sia  = smalls + 640;
  bf16* gbuf = Bs;            // [B,32,HW] (first half of Bs)
  bf16* attb = Bs + S / 2;    // [B,32,HW] (second half of Bs)
  float* yb  = (float*)d_out; // y lives in d_out (fp32)

  dim3 blk(64, 4, 1);

  k_ln<<<dim3(200), dim3(256), 0, stream>>>(inp, n1w, n1b, A);          // A = x
  k_meanhw<<<dim3(128), dim3(256), 0, stream>>>(A, xm);
  k_small_mv<<<dim3(1), dim3(128), 0, stream>>>(xm, scaw, scab, scaV, 0);
  k_conv1x1<<<dim3(400, 16, Bn), blk, 0, stream>>>(A, c11aw, c11ab, Bs, 64, 64);   // B = t1
  k_c11b<<<dim3(400, 16, Bn), blk, 0, stream>>>(Bs, c11bw, c11bb, Cs);             // C = x1 (B dead)
  k_c2a<<<dim3(400, 8, Bn), blk, 0, stream>>>(A, c2aw, c2ab, gbuf);                // B.lo = g
  k_att<<<dim3(400, 8, Bn), blk, 0, stream>>>(gbuf, A, c2cw, c2cb, c211w, c211b, attg, attb); // B.hi = att
  k_conv1x1<<<dim3(400, 16, Bn), blk, 0, stream>>>(A, c1w, c1b, Ds, 64, 64);       // D = t2 (A dead after)
  k_c21dw<<<dim3(400, 16, Bn), blk, 0, stream>>>(Ds, c21w, c21b, A);               // A = uf
  k_kba<<<dim3(3, 160, Bn), dim3(256), 0, stream>>>(A, attb, Cs, scaV, kbw, kbb, ga1, Ds); // D = xprod
  k_c3y<<<dim3(400, 16, Bn), blk, 0, stream>>>(Ds, c3w, c3b, beta, inp, yb);       // d_out = y (fp32)
  k_ln2<<<dim3(200), dim3(256), 0, stream>>>(yb, n2w, n2b, A);                     // A = X
  // forward FFT2: pass over W ([h][w] -> [u][h]), then over H ([u][h] -> [v][u])
  k_cpass<<<dim3(3, 3, Bn * Cc), dim3(256), 0, stream>>>(A, (const bf16*)nullptr, Bs, Cs, -1.f, SCL, nullptr, nullptr); // B,C = F1 (A dead)
  k_cpass<<<dim3(3, 3, Bn * Cc), dim3(256), 0, stream>>>(Bs, Cs, Ds, A, -1.f, SCL, nullptr, nullptr);                   // D,A = F2
  k_fc1gate<<<dim3(400, 32, Bn), blk, 0, stream>>>(Ds, A, fc1w, fc1b, Bs, Cs);     // B,C = gated
  k_fc2<<<dim3(400, 32, Bn), blk, 0, stream>>>(Bs, Cs, fc2w, fc2b, Ds, A);         // D = r, A = i
  k_meanhw<<<dim3(128), dim3(256), 0, stream>>>(Ds, rmv);
  k_meanhw<<<dim3(128), dim3(256), 0, stream>>>(A, imv);
  k_small_mv<<<dim3(1), dim3(128), 0, stream>>>(rmv, fscaw, fscab, sra, 1);
  k_small_mv<<<dim3(1), dim3(128), 0, stream>>>(imv, fscaw, fscab, sia, 1);
  // inverse FFT2 with per-plane (1+ra)/(1+ia) scaling fused into first pass
  k_cpass<<<dim3(3, 3, Bn * Cc), dim3(256), 0, stream>>>(Ds, A, Bs, Cs, 1.f, SCL, sra, sia);  // B,C
  k_cpass_final<<<dim3(3, 3, Bn * Cc), dim3(256), 0, stream>>>(Bs, Cs, 1.f, SCL, gamma, yb);  // d_out = y + |z|*gamma
}

// Round 7
// 1737.375 us; speedup vs baseline: 1.1306x; 1.1254x over previous
//
#include <hip/hip_runtime.h>
#include <hip/hip_bf16.h>

typedef __hip_bfloat16 bf16;

#define Hh 160
#define Wd 160
#define HWp (Hh*Wd)       // 25600
#define Bn 2
#define Cc 64
#define NPIX (Bn*HWp)     // 51200
#define SCL 0.07905694150420949f   // 1/sqrt(160)
#define TWO_PI_160 0.039269908169872414f  // 2*pi/160

static __device__ __forceinline__ float b2f(bf16 x) { return __bfloat162float(x); }
static __device__ __forceinline__ bf16 f2b(float f) { return __float2bfloat16(f); }
static __device__ __forceinline__ float bfu(unsigned short u) {
  union { unsigned int i; float f; } z; z.i = ((unsigned int)u) << 16; return z.f;
}
static __device__ __forceinline__ float bflo(unsigned int u) {
  union { unsigned int i; float f; } z; z.i = u << 16; return z.f;
}
static __device__ __forceinline__ float bfhi(unsigned int u) {
  union { unsigned int i; float f; } z; z.i = u & 0xffff0000u; return z.f;
}

// ---------------- LayerNorm over channel dim (per pixel), fp32 in -> bf16 out ----------------
__global__ void k_ln(const float* __restrict__ in, const float* __restrict__ w,
                     const float* __restrict__ bb, bf16* __restrict__ out) {
  int idx = blockIdx.x * 256 + threadIdx.x;   // grid covers exactly NPIX
  int b = idx / HWp, p = idx - b * HWp;
  const float* src = in + (size_t)b * Cc * HWp + p;
  float s = 0.f, s2 = 0.f;
  for (int c = 0; c < Cc; c++) { float v = src[(size_t)c * HWp]; s += v; s2 += v * v; }
  float mu = s * (1.f / 64.f);
  float var = s2 * (1.f / 64.f) - mu * mu;
  float rs = rsqrtf(fmaxf(var, 0.f) + 1e-6f);
  bf16* dst = out + (size_t)b * Cc * HWp + p;
  for (int c = 0; c < Cc; c++) {
    float v = src[(size_t)c * HWp];
    dst[(size_t)c * HWp] = f2b((v - mu) * rs * w[c] + bb[c]);
  }
}

// ---------------- mean over HW per (b,c) plane (bf16 in) ----------------
__global__ void k_meanhw(const bf16* __restrict__ in, float* __restrict__ out) {
  int bc = blockIdx.x;
  const bf16* src = in + (size_t)bc * HWp;
  int t = threadIdx.x;
  float s = 0.f;
  for (int i = t; i < HWp; i += 256) s += b2f(src[i]);
  __shared__ float sm[256];
  sm[t] = s; __syncthreads();
  for (int off = 128; off; off >>= 1) { if (t < off) sm[t] += sm[t + off]; __syncthreads(); }
  if (t == 0) out[bc] = sm[0] * (1.f / HWp);
}

// ---------------- small matvec: out[b,o] = (addone) + W[o,:]·xin[b,:] + bias[o] ----------------
__global__ void k_small_mv(const float* __restrict__ xin, const float* __restrict__ w,
                           const float* __restrict__ bias, float* __restrict__ out, int addone) {
  int t = threadIdx.x;              // 128 threads
  int b = t >> 6, o = t & 63;
  float acc = bias[o];
  for (int k = 0; k < 64; k++) acc += w[o * 64 + k] * xin[b * 64 + k];
  out[t] = addone ? (1.f + acc) : acc;
}

// ---------------- generic 1x1 conv, bf16 ws in/out, fp32 weights ----------------
__global__ void k_conv1x1(const bf16* __restrict__ in, const float* __restrict__ w,
                          const float* __restrict__ bias, bf16* __restrict__ out,
                          int Cin, int Cout) {
  int p = blockIdx.x * 64 + threadIdx.x;
  int o = blockIdx.y * 4 + threadIdx.y;
  int b = blockIdx.z;
  float acc = bias[o];
  const bf16* src = in + (size_t)b * Cin * HWp + p;
  const float* wr = w + (size_t)o * Cin;
  for (int k = 0; k < Cin; k++) acc += wr[k] * b2f(src[(size_t)k * HWp]);
  out[((size_t)b * Cout + o) * HWp + p] = f2b(acc);
}

// ---------------- c11b: grouped 5x5 conv, groups=16 (4ch/group), pad 2 ----------------
__global__ void k_c11b(const bf16* __restrict__ in, const float* __restrict__ w,
                       const float* __restrict__ bias, bf16* __restrict__ out) {
  int p = blockIdx.x * 64 + threadIdx.x;
  int o = blockIdx.y * 4 + threadIdx.y;
  int b = blockIdx.z;
  int h = p / Wd, x = p - h * Wd;
  int gb = (o >> 2) << 2;
  float acc = bias[o];
  for (int ci = 0; ci < 4; ci++) {
    const bf16* src = in + ((size_t)b * Cc + gb + ci) * HWp;
    for (int ki = 0; ki < 5; ki++) {
      int hh = h + ki - 2; if ((unsigned)hh >= Hh) continue;
      for (int kj = 0; kj < 5; kj++) {
        int ww = x + kj - 2; if ((unsigned)ww >= Wd) continue;
        acc += w[((o * 4 + ci) * 5 + ki) * 5 + kj] * b2f(src[hh * Wd + ww]);
      }
    }
  }
  out[((size_t)b * Cc + o) * HWp + p] = f2b(acc);
}

// ---------------- c2a: grouped 3x3, 64->32, groups=32 (2 in-ch/group), pad 1 ----------------
__global__ void k_c2a(const bf16* __restrict__ in, const float* __restrict__ w,
                      const float* __restrict__ bias, bf16* __restrict__ out) {
  int p = blockIdx.x * 64 + threadIdx.x;
  int o = blockIdx.y * 4 + threadIdx.y;   // 0..31
  int b = blockIdx.z;
  int h = p / Wd, x = p - h * Wd;
  float acc = bias[o];
  for (int ci = 0; ci < 2; ci++) {
    const bf16* src = in + ((size_t)b * Cc + o * 2 + ci) * HWp;
    for (int ki = 0; ki < 3; ki++) {
      int hh = h + ki - 1; if ((unsigned)hh >= Hh) continue;
      for (int kj = 0; kj < 3; kj++) {
        int ww = x + kj - 1; if ((unsigned)ww >= Wd) continue;
        acc += w[((o * 2 + ci) * 3 + ki) * 3 + kj] * b2f(src[hh * Wd + ww]);
      }
    }
  }
  out[((size_t)b * 32 + o) * HWp + p] = f2b(acc);
}

// ---------------- att = c2c(gate(g))*attgamma + c211(x) ----------------
__global__ void k_att(const bf16* __restrict__ g, const bf16* __restrict__ x,
                      const float* __restrict__ c2cw, const float* __restrict__ c2cb,
                      const float* __restrict__ c211w, const float* __restrict__ c211b,
                      const float* __restrict__ attg, bf16* __restrict__ att) {
  int p = blockIdx.x * 64 + threadIdx.x;
  int s = blockIdx.y * 4 + threadIdx.y;   // 0..31
  int b = blockIdx.z;
  float a1 = c2cb[s];
  const bf16* gs = g + (size_t)b * 32 * HWp + p;
  for (int k = 0; k < 16; k++)
    a1 += c2cw[s * 16 + k] * b2f(gs[(size_t)k * HWp]) * b2f(gs[(size_t)(16 + k) * HWp]);
  float acc = a1 * attg[s] + c211b[s];
  const bf16* xs = x + (size_t)b * Cc * HWp + p;
  for (int c = 0; c < Cc; c++) acc += c211w[s * 64 + c] * b2f(xs[(size_t)c * HWp]);
  att[((size_t)b * 32 + s) * HWp + p] = f2b(acc);
}

// ---------------- depthwise 3x3, pad 1 ----------------
__global__ void k_c21dw(const bf16* __restrict__ in, const float* __restrict__ w,
                        const float* __restrict__ bias, bf16* __restrict__ out) {
  int p = blockIdx.x * 64 + threadIdx.x;
  int c = blockIdx.y * 4 + threadIdx.y;
  int b = blockIdx.z;
  int h = p / Wd, x = p - h * Wd;
  float acc = bias[c];
  const bf16* src = in + ((size_t)b * Cc + c) * HWp;
  for (int ki = 0; ki < 3; ki++) {
    int hh = h + ki - 1; if ((unsigned)hh >= Hh) continue;
    for (int kj = 0; kj < 3; kj++) {
      int ww = x + kj - 1; if ((unsigned)ww >= Wd) continue;
      acc += w[c * 9 + ki * 3 + kj] * b2f(src[hh * Wd + ww]);
    }
  }
  out[((size_t)b * Cc + c) * HWp + p] = f2b(acc);
}

// ---------------- kb_w pre-transpose: kbwT[s][d][g][o] <- kbw[s][g][o][d] ----------------
__global__ void k_kbwT(const float* __restrict__ kbw, float* __restrict__ kbwT) {
  int i = blockIdx.x * 256 + threadIdx.x;       // 73728 total (288 blocks)
  int o = i & 3, g = (i >> 2) & 15, rest = i >> 6;  // rest = s*36 + d
  int d = rest % 36, s = rest / 36;
  kbwT[i] = kbw[s * 2304 + g * 144 + o * 36 + d];
}

// ---------------- KBA fused: out = ((kba+bias)*ga1 + uf) * x1 * sca ----------------
// tile = 64 pixels of one row. thread: g=t&15 (group), pq=t>>4 (4 px each).
// v3: patchL and kwL share one LDS buffer (patch is dead after register hoist);
// patch window kept as packed bf16 pairs (36 VGPRs); bias folded into acc;
// weights staged via coalesced reads from pre-transposed kbwT[s][d][g][o].
// launch_bounds(256,4): <=128 VGPR so LDS(33.8KB) x VGPR both allow 4 blocks/CU
// -> all 960 blocks co-resident in one round.
__global__ __launch_bounds__(256, 4) void k_kba(
    const bf16* __restrict__ uf, const bf16* __restrict__ att,
    const bf16* __restrict__ x1, const float* __restrict__ scaV,
    const float* __restrict__ kbwT, const float* __restrict__ kbb,
    const float* __restrict__ ga1, bf16* __restrict__ out) {
  __shared__ __align__(16) unsigned char shmem[64 * 3 * 66 * 2];  // 25344 B
  unsigned short* patchL = (unsigned short*)shmem;   // [c][ki][col] bf16, live until hoist
  float* kwL = (float*)shmem;                        // [si][d][g][o] fp32 (2*36*16*4=4608 floats=18432B)
  __shared__ float attL[64][33];                     // 8448 B
  int b = blockIdx.z, h = blockIdx.y;
  int w0 = blockIdx.x * 64;
  int width = min(64, Wd - w0);
  int t = threadIdx.x;
  const unsigned short* uf_u = (const unsigned short*)uf;
  for (int i = t; i < 64 * 3 * 66; i += 256) {
    int c = i / 198, rem = i - c * 198;
    int r = rem / 66, col = rem - r * 66;
    int hh = h + r - 1, ww = w0 + col - 1;
    unsigned short v = 0;
    if ((unsigned)hh < Hh && (unsigned)ww < Wd)
      v = uf_u[((size_t)b * Cc + c) * HWp + hh * Wd + ww];
    patchL[i] = v;
  }
  for (int i = t; i < 64 * 32; i += 256) {
    int px = i & 63, s = i >> 6;
    float v = 0.f;
    if (px < width) v = b2f(att[((size_t)b * 32 + s) * HWp + h * Wd + w0 + px]);
    attL[px][s] = v;
  }
  __syncthreads();
  int g = t & 15, pq = t >> 4;
  // hoist the 4ci x 3ki x 6col patch window as packed bf16 pairs (s-invariant)
  unsigned int pf2[4][3][3];
  #pragma unroll
  for (int ci = 0; ci < 4; ci++)
    #pragma unroll
    for (int ki = 0; ki < 3; ki++) {
      const unsigned int* pr32 =
          (const unsigned int*)&patchL[(g * 4 + ci) * 198 + ki * 66 + 4 * pq];  // 4B aligned
      #pragma unroll
      for (int m2 = 0; m2 < 3; m2++) pf2[ci][ki][m2] = pr32[m2];
    }
  float acc[4][4];
  #pragma unroll
  for (int j = 0; j < 4; j++)
    #pragma unroll
    for (int o = 0; o < 4; o++) acc[j][o] = 0.f;
  // bias = att @ kb_b, folded directly into acc
  for (int s = 0; s < 32; s++) {
    float kv[4];
    #pragma unroll
    for (int o = 0; o < 4; o++) kv[o] = kbb[s * 64 + g * 4 + o];
    #pragma unroll
    for (int j = 0; j < 4; j++) {
      float av = attL[4 * pq + j][s];
      #pragma unroll
      for (int o = 0; o < 4; o++) acc[j][o] += av * kv[o];
    }
  }

  for (int sc = 0; sc < 16; sc++) {        // 2 sets per chunk
    __syncthreads();                       // prior reads of kwL (or patchL hoist) done
    for (int i = t; i < 2 * 2304; i += 256)
      kwL[i] = kbwT[sc * 4608 + i];        // fully coalesced
    __syncthreads();
    #pragma unroll
    for (int si = 0; si < 2; si++) {
      int s = sc * 2 + si;
      float a0 = attL[4 * pq + 0][s], a1 = attL[4 * pq + 1][s];
      float a2 = attL[4 * pq + 2][s], a3 = attL[4 * pq + 3][s];
      const float* wbase = &kwL[si * 2304 + g * 4];
      #pragma unroll
      for (int ci = 0; ci < 4; ci++)
        #pragma unroll
        for (int ki = 0; ki < 3; ki++) {
          float w0f = bflo(pf2[ci][ki][0]), w1f = bfhi(pf2[ci][ki][0]);
          float w2f = bflo(pf2[ci][ki][1]), w3f = bfhi(pf2[ci][ki][1]);
          float w4f = bflo(pf2[ci][ki][2]), w5f = bfhi(pf2[ci][ki][2]);
          float win[6] = {w0f, w1f, w2f, w3f, w4f, w5f};
          #pragma unroll
          for (int kj = 0; kj < 3; kj++) {
            int d = ci * 9 + ki * 3 + kj;
            float4 wv = *(const float4*)&wbase[d * 64];
            float p0 = win[kj + 0] * a0;
            float p1 = win[kj + 1] * a1;
            float p2 = win[kj + 2] * a2;
            float p3 = win[kj + 3] * a3;
            acc[0][0] += p0 * wv.x; acc[0][1] += p0 * wv.y; acc[0][2] += p0 * wv.z; acc[0][3] += p0 * wv.w;
            acc[1][0] += p1 * wv.x; acc[1][1] += p1 * wv.y; acc[1][2] += p1 * wv.z; acc[1][3] += p1 * wv.w;
            acc[2][0] += p2 * wv.x; acc[2][1] += p2 * wv.y; acc[2][2] += p2 * wv.z; acc[2][3] += p2 * wv.w;
            acc[3][0] += p3 * wv.x; acc[3][1] += p3 * wv.y; acc[3][2] += p3 * wv.z; acc[3][3] += p3 * wv.w;
          }
        }
    }
  }
  #pragma unroll
  for (int j = 0; j < 4; j++) {
    int px = 4 * pq + j;
    if (px >= width) continue;
    int p = h * Wd + w0 + px;
    #pragma unroll
    for (int o = 0; o < 4; o++) {
      int c = g * 4 + o;
      // center tap (ki=1, col j+1): pair (j+1)>>1, half (j+1)&1
      unsigned int cu = pf2[o][1][(j + 1) >> 1];
      float ufc = ((j + 1) & 1) ? bfhi(cu) : bflo(cu);
      float xk = acc[j][o] * ga1[c] + ufc;
      float xv = xk * b2f(x1[((size_t)b * Cc + c) * HWp + p]) * scaV[b * 64 + c];
      out[((size_t)b * Cc + c) * HWp + p] = f2b(xv);
    }
  }
}

// ---------------- c3 1x1 conv + residual: y = inp + (conv)*beta (fp32 out) ----------------
__global__ void k_c3y(const bf16* __restrict__ xprod, const float* __restrict__ w,
                      const float* __restrict__ bias, const float* __restrict__ beta,
                      const float* __restrict__ inp, float* __restrict__ y) {
  int p = blockIdx.x * 64 + threadIdx.x;
  int o = blockIdx.y * 4 + threadIdx.y;
  int b = blockIdx.z;
  float acc = bias[o];
  const bf16* src = xprod + (size_t)b * Cc * HWp + p;
  const float* wr = w + o * 64;
  for (int k = 0; k < 64; k++) acc += wr[k] * b2f(src[(size_t)k * HWp]);
  size_t oi = ((size_t)b * Cc + o) * HWp + p;
  y[oi] = inp[oi] + acc * beta[o];
}

// ---------------- LayerNorm, fp32 in (y in d_out) -> bf16 ws out ----------------
__global__ void k_ln2(const float* __restrict__ in, const float* __restrict__ w,
                      const float* __restrict__ bb, bf16* __restrict__ out) {
  int idx = blockIdx.x * 256 + threadIdx.x;
  int b = idx / HWp, p = idx - b * HWp;
  const float* src = in + (size_t)b * Cc * HWp + p;
  float s = 0.f, s2 = 0.f;
  for (int c = 0; c < Cc; c++) { float v = src[(size_t)c * HWp]; s += v; s2 += v * v; }
  float mu = s * (1.f / 64.f);
  float var = s2 * (1.f / 64.f) - mu * mu;
  float rs = rsqrtf(fmaxf(var, 0.f) + 1e-6f);
  bf16* dst = out + (size_t)b * Cc * HWp + p;
  for (int c = 0; c < Cc; c++) {
    float v = src[(size_t)c * HWp];
    dst[(size_t)c * HWp] = f2b((v - mu) * rs * w[c] + bb[c]);
  }
}

// ---------------- one DFT pass with transpose: out[c][a] = scale * sum_b in[a][b] e^{i*sgn*2pi*b*c/N}
__global__ __launch_bounds__(256) void k_cpass(
    const bf16* __restrict__ inr, const bf16* __restrict__ ini,
    bf16* __restrict__ outr, bf16* __restrict__ outi,
    float sgn, float scale,
    const float* __restrict__ sclr, const float* __restrict__ scli) {
  int plane = blockIdx.z;
  int a0 = blockIdx.x * 64, c0 = blockIdx.y * 64;
  __shared__ __align__(16) float Lr[32][68], Li[32][68], Lc[32][68], Ls[32][68];
  int t = threadIdx.x;
  int ta = t & 15, tc = t >> 4;
  float ar[4][4], ai[4][4];
  #pragma unroll
  for (int j = 0; j < 4; j++) for (int k = 0; k < 4; k++) { ar[j][k] = 0.f; ai[j][k] = 0.f; }
  const bf16* pr = inr + (size_t)plane * HWp;
  const bf16* pi = ini ? ini + (size_t)plane * HWp : nullptr;
  float srm = sclr ? sclr[plane] : 1.f;
  float sim = scli ? scli[plane] : 1.f;
  for (int b0 = 0; b0 < 160; b0 += 32) {
    __syncthreads();
    for (int i = t; i < 32 * 64; i += 256) {
      int bb = i & 31, aa = i >> 5;
      int a = a0 + aa;
      float vr = 0.f, vi = 0.f;
      if (a < 160) {
        vr = b2f(pr[a * 160 + b0 + bb]) * srm;
        if (pi) vi = b2f(pi[a * 160 + b0 + bb]) * sim;
      }
      Lr[bb][aa] = vr; Li[bb][aa] = vi;
    }
    for (int i = t; i < 32 * 64; i += 256) {
      int cc = i & 63, bb = i >> 6;
      int c = c0 + cc;
      float vc = 0.f, vs = 0.f;
      if (c < 160) {
        int m = ((b0 + bb) * c) % 160;
        float sv, cv;
        __sincosf((float)m * TWO_PI_160, &sv, &cv);
        vc = cv; vs = sv * sgn;
      }
      Lc[bb][cc] = vc; Ls[bb][cc] = vs;
    }
    __syncthreads();
    for (int bb = 0; bb < 32; bb++) {
      float4 x4 = *(const float4*)&Lr[bb][ta * 4];
      float4 y4 = *(const float4*)&Li[bb][ta * 4];
      float4 c4 = *(const float4*)&Lc[bb][tc * 4];
      float4 s4 = *(const float4*)&Ls[bb][tc * 4];
      float xr[4] = {x4.x, x4.y, x4.z, x4.w};
      float xi[4] = {y4.x, y4.y, y4.z, y4.w};
      float cs[4] = {c4.x, c4.y, c4.z, c4.w};
      float sn[4] = {s4.x, s4.y, s4.z, s4.w};
      #pragma unroll
      for (int j = 0; j < 4; j++)
        #pragma unroll
        for (int k = 0; k < 4; k++) {
          ar[j][k] += xr[j] * cs[k] - xi[j] * sn[k];
          ai[j][k] += xr[j] * sn[k] + xi[j] * cs[k];
        }
    }
  }
  for (int k = 0; k < 4; k++) {
    int c = c0 + tc * 4 + k;
    if (c >= 160) continue;
    for (int j = 0; j < 4; j++) {
      int a = a0 + ta * 4 + j;
      if (a >= 160) continue;
      outr[(size_t)plane * HWp + c * 160 + a] = f2b(ar[j][k] * scale);
      outi[(size_t)plane * HWp + c * 160 + a] = f2b(ai[j][k] * scale);
    }
  }
}

// ---------------- final inverse pass, fused |.|, *gamma, += y (fp32 d_out) ----------------
__global__ __launch_bounds__(256) void k_cpass_final(
    const bf16* __restrict__ inr, const bf16* __restrict__ ini,
    float sgn, float scale,
    const float* __restrict__ gamma, float* __restrict__ dout) {
  int plane = blockIdx.z;
  int a0 = blockIdx.x * 64, c0 = blockIdx.y * 64;
  __shared__ __align__(16) float Lr[32][68], Li[32][68], Lc[32][68], Ls[32][68];
  int t = threadIdx.x;
  int ta = t & 15, tc = t >> 4;
  float ar[4][4], ai[4][4];
  #pragma unroll
  for (int j = 0; j < 4; j++) for (int k = 0; k < 4; k++) { ar[j][k] = 0.f; ai[j][k] = 0.f; }
  const bf16* pr = inr + (size_t)plane * HWp;
  const bf16* pi = ini + (size_t)plane * HWp;
  for (int b0 = 0; b0 < 160; b0 += 32) {
    __syncthreads();
    for (int i = t; i < 32 * 64; i += 256) {
      int bb = i & 31, aa = i >> 5;
      int a = a0 + aa;
      float vr = 0.f, vi = 0.f;
      if (a < 160) { vr = b2f(pr[a * 160 + b0 + bb]); vi = b2f(pi[a * 160 + b0 + bb]); }
      Lr[bb][aa] = vr; Li[bb][aa] = vi;
    }
    for (int i = t; i < 32 * 64; i += 256) {
      int cc = i & 63, bb = i >> 6;
      int c = c0 + cc;
      float vc = 0.f, vs = 0.f;
      if (c < 160) {
        int m = ((b0 + bb) * c) % 160;
        float sv, cv;
        __sincosf((float)m * TWO_PI_160, &sv, &cv);
        vc = cv; vs = sv * sgn;
      }
      Lc[bb][cc] = vc; Ls[bb][cc] = vs;
    }
    __syncthreads();
    for (int bb = 0; bb < 32; bb++) {
      float4 x4 = *(const float4*)&Lr[bb][ta * 4];
      float4 y4 = *(const float4*)&Li[bb][ta * 4];
      float4 c4 = *(const float4*)&Lc[bb][tc * 4];
      float4 s4 = *(const float4*)&Ls[bb][tc * 4];
      float xr[4] = {x4.x, x4.y, x4.z, x4.w};
      float xi[4] = {y4.x, y4.y, y4.z, y4.w};
      float cs[4] = {c4.x, c4.y, c4.z, c4.w};
      float sn[4] = {s4.x, s4.y, s4.z, s4.w};
      #pragma unroll
      for (int j = 0; j < 4; j++)
        #pragma unroll
        for (int k = 0; k < 4; k++) {
          ar[j][k] += xr[j] * cs[k] - xi[j] * sn[k];
          ai[j][k] += xr[j] * sn[k] + xi[j] * cs[k];
        }
    }
  }
  int ch = plane & 63;
  float gm = gamma[ch];
  for (int k = 0; k < 4; k++) {
    int c = c0 + tc * 4 + k;          // = h
    if (c >= 160) continue;
    for (int j = 0; j < 4; j++) {
      int a = a0 + ta * 4 + j;        // = w
      if (a >= 160) continue;
      float rr = ar[j][k] * scale, ii = ai[j][k] * scale;
      float z = sqrtf(rr * rr + ii * ii);
      size_t oi = (size_t)plane * HWp + c * 160 + a;
      dout[oi] = dout[oi] + z * gm;   // dout currently holds y
    }
  }
}

// ---------------- fc1 (128->256) + simple_gate ----------------
__global__ void k_fc1gate(const bf16* __restrict__ Fr, const bf16* __restrict__ Fi,
                          const float* __restrict__ w, const float* __restrict__ bias,
                          bf16* __restrict__ G1, bf16* __restrict__ G2) {
  int p = blockIdx.x * 64 + threadIdx.x;
  int o = blockIdx.y * 4 + threadIdx.y;   // 0..127
  int b = blockIdx.z;
  float acc1 = bias[o], acc2 = bias[o + 128];
  const float* w1 = w + (size_t)o * 128;
  const float* w2 = w + (size_t)(o + 128) * 128;
  const bf16* fr = Fr + (size_t)b * Cc * HWp + p;
  const bf16* fi = Fi + (size_t)b * Cc * HWp + p;
  for (int k = 0; k < 64; k++) {
    float v = b2f(fr[(size_t)k * HWp]);
    acc1 += w1[k] * v; acc2 += w2[k] * v;
  }
  for (int k = 0; k < 64; k++) {
    float v = b2f(fi[(size_t)k * HWp]);
    acc1 += w1[64 + k] * v; acc2 += w2[64 + k] * v;
  }
  float gv = acc1 * acc2;
  if (o < 64) G1[((size_t)b * Cc + o) * HWp + p] = f2b(gv);
  else        G2[((size_t)b * Cc + o - 64) * HWp + p] = f2b(gv);
}

// ---------------- fc2 (128->128), split output into r / i planes ----------------
__global__ void k_fc2(const bf16* __restrict__ G1, const bf16* __restrict__ G2,
                      const float* __restrict__ w, const float* __restrict__ bias,
                      bf16* __restrict__ Or, bf16* __restrict__ Oi) {
  int p = blockIdx.x * 64 + threadIdx.x;
  int o = blockIdx.y * 4 + threadIdx.y;   // 0..127
  int b = blockIdx.z;
  float acc = bias[o];
  const float* wr = w + (size_t)o * 128;
  const bf16* g1 = G1 + (size_t)b * Cc * HWp + p;
  const bf16* g2 = G2 + (size_t)b * Cc * HWp + p;
  for (int k = 0; k < 64; k++) acc += wr[k] * b2f(g1[(size_t)k * HWp]);
  for (int k = 0; k < 64; k++) acc += wr[64 + k] * b2f(g2[(size_t)k * HWp]);
  if (o < 64) Or[((size_t)b * Cc + o) * HWp + p] = f2b(acc);
  else        Oi[((size_t)b * Cc + o - 64) * HWp + p] = f2b(acc);
}

extern "C" void kernel_launch(void* const* d_in, const int* in_sizes, int n_in,
                              void* d_out, int out_size, void* d_ws, size_t ws_size,
                              hipStream_t stream) {
  const float* inp   = (const float*)d_in[0];
  const float* n1w   = (const float*)d_in[1];
  const float* n1b   = (const float*)d_in[2];
  const float* n2w   = (const float*)d_in[3];
  const float* n2b   = (const float*)d_in[4];
  const float* scaw  = (const float*)d_in[5];
  const float* scab  = (const float*)d_in[6];
  const float* c11aw = (const float*)d_in[7];
  const float* c11ab = (const float*)d_in[8];
  const float* c11bw = (const float*)d_in[9];
  const float* c11bb = (const float*)d_in[10];
  const float* c1w   = (const float*)d_in[11];
  const float* c1b   = (const float*)d_in[12];
  const float* c21w  = (const float*)d_in[13];
  const float* c21b  = (const float*)d_in[14];
  const float* c2aw  = (const float*)d_in[15];
  const float* c2ab  = (const float*)d_in[16];
  const float* c2cw  = (const float*)d_in[17];
  const float* c2cb  = (const float*)d_in[18];
  const float* c211w = (const float*)d_in[19];
  const float* c211b = (const float*)d_in[20];
  const float* c3w   = (const float*)d_in[21];
  const float* c3b   = (const float*)d_in[22];
  const float* kbw   = (const float*)d_in[23];
  const float* kbb   = (const float*)d_in[24];
  const float* ga1   = (const float*)d_in[25];
  const float* attg  = (const float*)d_in[26];
  const float* beta  = (const float*)d_in[27];
  const float* gamma = (const float*)d_in[28];
  const float* fc1w  = (const float*)d_in[29];
  const float* fc1b  = (const float*)d_in[30];
  const float* fc2w  = (const float*)d_in[31];
  const float* fc2b  = (const float*)d_in[32];
  const float* fscaw = (const float*)d_in[33];
  const float* fscab = (const float*)d_in[34];

  const size_t S = (size_t)Bn * Cc * HWp;   // 3,276,800 elements per slot
  bf16* A  = (bf16*)d_ws;                   // 4 bf16 slots = 26.2 MB total
  bf16* Bs = A + S;
  bf16* Cs = A + 2 * S;
  bf16* Ds = A + 3 * S;
  float* smalls = (float*)(A + 4 * S);      // fp32 smalls
  float* xm   = smalls;
  float* scaV = smalls + 128;
  float* rmv  = smalls + 256;
  float* imv  = smalls + 384;
  float* sra  = smalls + 512;
  float* sia  = smalls + 640;
  float* kbwT = smalls + 1024;              // 73728 floats = 295 KB (ws total ~26.5 MB)
  bf16* gbuf = Bs;            // [B,32,HW] (first half of Bs)
  bf16* attb = Bs + S / 2;    // [B,32,HW] (second half of Bs)
  float* yb  = (float*)d_out; // y lives in d_out (fp32)

  dim3 blk(64, 4, 1);

  k_kbwT<<<dim3(288), dim3(256), 0, stream>>>(kbw, kbwT);               // kbwT (independent)
  k_ln<<<dim3(200), dim3(256), 0, stream>>>(inp, n1w, n1b, A);          // A = x
  k_meanhw<<<dim3(128), dim3(256), 0, stream>>>(A, xm);
  k_small_mv<<<dim3(1), dim3(128), 0, stream>>>(xm, scaw, scab, scaV, 0);
  k_conv1x1<<<dim3(400, 16, Bn), blk, 0, stream>>>(A, c11aw, c11ab, Bs, 64, 64);   // B = t1
  k_c11b<<<dim3(400, 16, Bn), blk, 0, stream>>>(Bs, c11bw, c11bb, Cs);             // C = x1 (B dead)
  k_c2a<<<dim3(400, 8, Bn), blk, 0, stream>>>(A, c2aw, c2ab, gbuf);                // B.lo = g
  k_att<<<dim3(400, 8, Bn), blk, 0, stream>>>(gbuf, A, c2cw, c2cb, c211w, c211b, attg, attb); // B.hi = att
  k_conv1x1<<<dim3(400, 16, Bn), blk, 0, stream>>>(A, c1w, c1b, Ds, 64, 64);       // D = t2 (A dead after)
  k_c21dw<<<dim3(400, 16, Bn), blk, 0, stream>>>(Ds, c21w, c21b, A);               // A = uf
  k_kba<<<dim3(3, 160, Bn), dim3(256), 0, stream>>>(A, attb, Cs, scaV, kbwT, kbb, ga1, Ds); // D = xprod
  k_c3y<<<dim3(400, 16, Bn), blk, 0, stream>>>(Ds, c3w, c3b, beta, inp, yb);       // d_out = y (fp32)
  k_ln2<<<dim3(200), dim3(256), 0, stream>>>(yb, n2w, n2b, A);                     // A = X
  // forward FFT2: pass over W ([h][w] -> [u][h]), then over H ([u][h] -> [v][u])
  k_cpass<<<dim3(3, 3, Bn * Cc), dim3(256), 0, stream>>>(A, (const bf16*)nullptr, Bs, Cs, -1.f, SCL, nullptr, nullptr); // B,C = F1 (A dead)
  k_cpass<<<dim3(3, 3, Bn * Cc), dim3(256), 0, stream>>>(Bs, Cs, Ds, A, -1.f, SCL, nullptr, nullptr);                   // D,A = F2
  k_fc1gate<<<dim3(400, 32, Bn), blk, 0, stream>>>(Ds, A, fc1w, fc1b, Bs, Cs);     // B,C = gated
  k_fc2<<<dim3(400, 32, Bn), blk, 0, stream>>>(Bs, Cs, fc2w, fc2b, Ds, A);         // D = r, A = i
  k_meanhw<<<dim3(128), dim3(256), 0, stream>>>(Ds, rmv);
  k_meanhw<<<dim3(128), dim3(256), 0, stream>>>(A, imv);
  k_small_mv<<<dim3(1), dim3(128), 0, stream>>>(rmv, fscaw, fscab, sra, 1);
  k_small_mv<<<dim3(1), dim3(128), 0, stream>>>(imv, fscaw, fscab, sia, 1);
  // inverse FFT2 with per-plane (1+ra)/(1+ia) scaling fused into first pass
  k_cpass<<<dim3(3, 3, Bn * Cc), dim3(256), 0, stream>>>(Ds, A, Bs, Cs, 1.f, SCL, sra, sia);  // B,C
  k_cpass_final<<<dim3(3, 3, Bn * Cc), dim3(256), 0, stream>>>(Bs, Cs, 1.f, SCL, gamma, yb);  // d_out = y + |z|*gamma
}

// Round 8
// 1330.956 us; speedup vs baseline: 1.4758x; 1.3054x over previous
//
#include <hip/hip_runtime.h>
#include <hip/hip_bf16.h>

typedef __hip_bfloat16 bf16;
typedef __attribute__((ext_vector_type(8))) short short8;
typedef __attribute__((ext_vector_type(4))) float f32x4;

#define Hh 160
#define Wd 160
#define HWp (Hh*Wd)       // 25600
#define Bn 2
#define Cc 64
#define NPIX (Bn*HWp)     // 51200
#define SCL 0.07905694150420949f   // 1/sqrt(160)
#define TWO_PI_160 0.039269908169872414f  // 2*pi/160

static __device__ __forceinline__ float b2f(bf16 x) { return __bfloat162float(x); }
static __device__ __forceinline__ bf16 f2b(float f) { return __float2bfloat16(f); }
static __device__ __forceinline__ unsigned short f2bu(float f) {
  union { bf16 h; unsigned short u; } z; z.h = __float2bfloat16(f); return z.u;
}
static __device__ __forceinline__ float bflo(unsigned int u) {
  union { unsigned int i; float f; } z; z.i = u << 16; return z.f;
}
static __device__ __forceinline__ float bfhi(unsigned int u) {
  union { unsigned int i; float f; } z; z.i = u & 0xffff0000u; return z.f;
}

// ---------------- LayerNorm over channel dim (per pixel), fp32 in -> bf16 out ----------------
__global__ void k_ln(const float* __restrict__ in, const float* __restrict__ w,
                     const float* __restrict__ bb, bf16* __restrict__ out) {
  int idx = blockIdx.x * 256 + threadIdx.x;   // grid covers exactly NPIX
  int b = idx / HWp, p = idx - b * HWp;
  const float* src = in + (size_t)b * Cc * HWp + p;
  float s = 0.f, s2 = 0.f;
  for (int c = 0; c < Cc; c++) { float v = src[(size_t)c * HWp]; s += v; s2 += v * v; }
  float mu = s * (1.f / 64.f);
  float var = s2 * (1.f / 64.f) - mu * mu;
  float rs = rsqrtf(fmaxf(var, 0.f) + 1e-6f);
  bf16* dst = out + (size_t)b * Cc * HWp + p;
  for (int c = 0; c < Cc; c++) {
    float v = src[(size_t)c * HWp];
    dst[(size_t)c * HWp] = f2b((v - mu) * rs * w[c] + bb[c]);
  }
}

// ---------------- mean over HW per (b,c) plane (bf16 in) ----------------
__global__ void k_meanhw(const bf16* __restrict__ in, float* __restrict__ out) {
  int bc = blockIdx.x;
  const bf16* src = in + (size_t)bc * HWp;
  int t = threadIdx.x;
  float s = 0.f;
  for (int i = t; i < HWp; i += 256) s += b2f(src[i]);
  __shared__ float sm[256];
  sm[t] = s; __syncthreads();
  for (int off = 128; off; off >>= 1) { if (t < off) sm[t] += sm[t + off]; __syncthreads(); }
  if (t == 0) out[bc] = sm[0] * (1.f / HWp);
}

// ---------------- small matvec: out[b,o] = (addone) + W[o,:]·xin[b,:] + bias[o] ----------------
__global__ void k_small_mv(const float* __restrict__ xin, const float* __restrict__ w,
                           const float* __restrict__ bias, float* __restrict__ out, int addone) {
  int t = threadIdx.x;              // 128 threads
  int b = t >> 6, o = t & 63;
  float acc = bias[o];
  for (int k = 0; k < 64; k++) acc += w[o * 64 + k] * xin[b * 64 + k];
  out[t] = addone ? (1.f + acc) : acc;
}

// ---------------- generic 1x1 conv, bf16 ws in/out, fp32 weights ----------------
__global__ void k_conv1x1(const bf16* __restrict__ in, const float* __restrict__ w,
                          const float* __restrict__ bias, bf16* __restrict__ out,
                          int Cin, int Cout) {
  int p = blockIdx.x * 64 + threadIdx.x;
  int o = blockIdx.y * 4 + threadIdx.y;
  int b = blockIdx.z;
  float acc = bias[o];
  const bf16* src = in + (size_t)b * Cin * HWp + p;
  const float* wr = w + (size_t)o * Cin;
  for (int k = 0; k < Cin; k++) acc += wr[k] * b2f(src[(size_t)k * HWp]);
  out[((size_t)b * Cout + o) * HWp + p] = f2b(acc);
}

// ---------------- c11b: grouped 5x5 conv, groups=16 (4ch/group), pad 2 ----------------
__global__ void k_c11b(const bf16* __restrict__ in, const float* __restrict__ w,
                       const float* __restrict__ bias, bf16* __restrict__ out) {
  int p = blockIdx.x * 64 + threadIdx.x;
  int o = blockIdx.y * 4 + threadIdx.y;
  int b = blockIdx.z;
  int h = p / Wd, x = p - h * Wd;
  int gb = (o >> 2) << 2;
  float acc = bias[o];
  for (int ci = 0; ci < 4; ci++) {
    const bf16* src = in + ((size_t)b * Cc + gb + ci) * HWp;
    for (int ki = 0; ki < 5; ki++) {
      int hh = h + ki - 2; if ((unsigned)hh >= Hh) continue;
      for (int kj = 0; kj < 5; kj++) {
        int ww = x + kj - 2; if ((unsigned)ww >= Wd) continue;
        acc += w[((o * 4 + ci) * 5 + ki) * 5 + kj] * b2f(src[hh * Wd + ww]);
      }
    }
  }
  out[((size_t)b * Cc + o) * HWp + p] = f2b(acc);
}

// ---------------- c2a: grouped 3x3, 64->32, groups=32 (2 in-ch/group), pad 1 ----------------
__global__ void k_c2a(const bf16* __restrict__ in, const float* __restrict__ w,
                      const float* __restrict__ bias, bf16* __restrict__ out) {
  int p = blockIdx.x * 64 + threadIdx.x;
  int o = blockIdx.y * 4 + threadIdx.y;   // 0..31
  int b = blockIdx.z;
  int h = p / Wd, x = p - h * Wd;
  float acc = bias[o];
  for (int ci = 0; ci < 2; ci++) {
    const bf16* src = in + ((size_t)b * Cc + o * 2 + ci) * HWp;
    for (int ki = 0; ki < 3; ki++) {
      int hh = h + ki - 1; if ((unsigned)hh >= Hh) continue;
      for (int kj = 0; kj < 3; kj++) {
        int ww = x + kj - 1; if ((unsigned)ww >= Wd) continue;
        acc += w[((o * 2 + ci) * 3 + ki) * 3 + kj] * b2f(src[hh * Wd + ww]);
      }
    }
  }
  out[((size_t)b * 32 + o) * HWp + p] = f2b(acc);
}

// ---------------- att = c2c(gate(g))*attgamma + c211(x) ----------------
__global__ void k_att(const bf16* __restrict__ g, const bf16* __restrict__ x,
                      const float* __restrict__ c2cw, const float* __restrict__ c2cb,
                      const float* __restrict__ c211w, const float* __restrict__ c211b,
                      const float* __restrict__ attg, bf16* __restrict__ att) {
  int p = blockIdx.x * 64 + threadIdx.x;
  int s = blockIdx.y * 4 + threadIdx.y;   // 0..31
  int b = blockIdx.z;
  float a1 = c2cb[s];
  const bf16* gs = g + (size_t)b * 32 * HWp + p;
  for (int k = 0; k < 16; k++)
    a1 += c2cw[s * 16 + k] * b2f(gs[(size_t)k * HWp]) * b2f(gs[(size_t)(16 + k) * HWp]);
  float acc = a1 * attg[s] + c211b[s];
  const bf16* xs = x + (size_t)b * Cc * HWp + p;
  for (int c = 0; c < Cc; c++) acc += c211w[s * 64 + c] * b2f(xs[(size_t)c * HWp]);
  att[((size_t)b * 32 + s) * HWp + p] = f2b(acc);
}

// ---------------- depthwise 3x3, pad 1 ----------------
__global__ void k_c21dw(const bf16* __restrict__ in, const float* __restrict__ w,
                        const float* __restrict__ bias, bf16* __restrict__ out) {
  int p = blockIdx.x * 64 + threadIdx.x;
  int c = blockIdx.y * 4 + threadIdx.y;
  int b = blockIdx.z;
  int h = p / Wd, x = p - h * Wd;
  float acc = bias[c];
  const bf16* src = in + ((size_t)b * Cc + c) * HWp;
  for (int ki = 0; ki < 3; ki++) {
    int hh = h + ki - 1; if ((unsigned)hh >= Hh) continue;
    for (int kj = 0; kj < 3; kj++) {
      int ww = x + kj - 1; if ((unsigned)ww >= Wd) continue;
      acc += w[c * 9 + ki * 3 + kj] * b2f(src[hh * Wd + ww]);
    }
  }
  out[((size_t)b * Cc + c) * HWp + p] = f2b(acc);
}

// ---------------- kb_w pre-transpose: kbwT[s][d][g][o] <- kbw[s][g][o][d] ----------------
__global__ void k_kbwT(const float* __restrict__ kbw, float* __restrict__ kbwT) {
  int i = blockIdx.x * 256 + threadIdx.x;       // 73728 total (288 blocks)
  int o = i & 3, g = (i >> 2) & 15, rest = i >> 6;  // rest = s*36 + d
  int d = rest % 36, s = rest / 36;
  kbwT[i] = kbw[s * 2304 + g * 144 + o * 36 + d];
}

// ---------------- fc weight prep: bf16 MFMA A-fragment order ----------------
// frag[(mt*4+kc)*64 + lane][j] = W[mt*16 + (lane&15)][kc*32 + (lane>>4)*8 + j]
__global__ void k_wprep(const float* __restrict__ fc1w, const float* __restrict__ fc2w,
                        short* __restrict__ wAf1, short* __restrict__ wAf2) {
  int i = blockIdx.x * 256 + threadIdx.x;   // 49152 total (192 blocks)
  if (i < 32768) {
    int j = i & 7, lane = (i >> 3) & 63, fk = i >> 9;
    int kc = fk & 3, mt = fk >> 2;          // mt 0..15
    int o = mt * 16 + (lane & 15);
    int k = kc * 32 + (lane >> 4) * 8 + j;
    wAf1[i] = (short)f2bu(fc1w[o * 128 + k]);
  } else {
    int i2 = i - 32768;
    int j = i2 & 7, lane = (i2 >> 3) & 63, fk = i2 >> 9;
    int kc = fk & 3, mt = fk >> 2;          // mt 0..7
    int o = mt * 16 + (lane & 15);
    int k = kc * 32 + (lane >> 4) * 8 + j;
    wAf2[i2] = (short)f2bu(fc2w[o * 128 + k]);
  }
}

// ---------------- KBA fused: out = ((kba+bias)*ga1 + uf) * x1 * sca ----------------
__global__ __launch_bounds__(256, 4) void k_kba(
    const bf16* __restrict__ uf, const bf16* __restrict__ att,
    const bf16* __restrict__ x1, const float* __restrict__ scaV,
    const float* __restrict__ kbwT, const float* __restrict__ kbb,
    const float* __restrict__ ga1, bf16* __restrict__ out) {
  __shared__ __align__(16) unsigned char shmem[64 * 3 * 66 * 2];  // 25344 B
  unsigned short* patchL = (unsigned short*)shmem;   // [c][ki][col] bf16, live until hoist
  float* kwL = (float*)shmem;                        // [si][d][g][o] fp32 (4608 floats)
  __shared__ float attL[64][33];                     // 8448 B
  int b = blockIdx.z, h = blockIdx.y;
  int w0 = blockIdx.x * 64;
  int width = min(64, Wd - w0);
  int t = threadIdx.x;
  const unsigned short* uf_u = (const unsigned short*)uf;
  for (int i = t; i < 64 * 3 * 66; i += 256) {
    int c = i / 198, rem = i - c * 198;
    int r = rem / 66, col = rem - r * 66;
    int hh = h + r - 1, ww = w0 + col - 1;
    unsigned short v = 0;
    if ((unsigned)hh < Hh && (unsigned)ww < Wd)
      v = uf_u[((size_t)b * Cc + c) * HWp + hh * Wd + ww];
    patchL[i] = v;
  }
  for (int i = t; i < 64 * 32; i += 256) {
    int px = i & 63, s = i >> 6;
    float v = 0.f;
    if (px < width) v = b2f(att[((size_t)b * 32 + s) * HWp + h * Wd + w0 + px]);
    attL[px][s] = v;
  }
  __syncthreads();
  int g = t & 15, pq = t >> 4;
  unsigned int pf2[4][3][3];
  #pragma unroll
  for (int ci = 0; ci < 4; ci++)
    #pragma unroll
    for (int ki = 0; ki < 3; ki++) {
      const unsigned int* pr32 =
          (const unsigned int*)&patchL[(g * 4 + ci) * 198 + ki * 66 + 4 * pq];
      #pragma unroll
      for (int m2 = 0; m2 < 3; m2++) pf2[ci][ki][m2] = pr32[m2];
    }
  float acc[4][4];
  #pragma unroll
  for (int j = 0; j < 4; j++)
    #pragma unroll
    for (int o = 0; o < 4; o++) acc[j][o] = 0.f;
  for (int s = 0; s < 32; s++) {
    float kv[4];
    #pragma unroll
    for (int o = 0; o < 4; o++) kv[o] = kbb[s * 64 + g * 4 + o];
    #pragma unroll
    for (int j = 0; j < 4; j++) {
      float av = attL[4 * pq + j][s];
      #pragma unroll
      for (int o = 0; o < 4; o++) acc[j][o] += av * kv[o];
    }
  }
  for (int sc = 0; sc < 16; sc++) {
    __syncthreads();
    for (int i = t; i < 2 * 2304; i += 256)
      kwL[i] = kbwT[sc * 4608 + i];
    __syncthreads();
    #pragma unroll
    for (int si = 0; si < 2; si++) {
      int s = sc * 2 + si;
      float a0 = attL[4 * pq + 0][s], a1 = attL[4 * pq + 1][s];
      float a2 = attL[4 * pq + 2][s], a3 = attL[4 * pq + 3][s];
      const float* wbase = &kwL[si * 2304 + g * 4];
      #pragma unroll
      for (int ci = 0; ci < 4; ci++)
        #pragma unroll
        for (int ki = 0; ki < 3; ki++) {
          float w0f = bflo(pf2[ci][ki][0]), w1f = bfhi(pf2[ci][ki][0]);
          float w2f = bflo(pf2[ci][ki][1]), w3f = bfhi(pf2[ci][ki][1]);
          float w4f = bflo(pf2[ci][ki][2]), w5f = bfhi(pf2[ci][ki][2]);
          float win[6] = {w0f, w1f, w2f, w3f, w4f, w5f};
          #pragma unroll
          for (int kj = 0; kj < 3; kj++) {
            int d = ci * 9 + ki * 3 + kj;
            float4 wv = *(const float4*)&wbase[d * 64];
            float p0 = win[kj + 0] * a0;
            float p1 = win[kj + 1] * a1;
            float p2 = win[kj + 2] * a2;
            float p3 = win[kj + 3] * a3;
            acc[0][0] += p0 * wv.x; acc[0][1] += p0 * wv.y; acc[0][2] += p0 * wv.z; acc[0][3] += p0 * wv.w;
            acc[1][0] += p1 * wv.x; acc[1][1] += p1 * wv.y; acc[1][2] += p1 * wv.z; acc[1][3] += p1 * wv.w;
            acc[2][0] += p2 * wv.x; acc[2][1] += p2 * wv.y; acc[2][2] += p2 * wv.z; acc[2][3] += p2 * wv.w;
            acc[3][0] += p3 * wv.x; acc[3][1] += p3 * wv.y; acc[3][2] += p3 * wv.z; acc[3][3] += p3 * wv.w;
          }
        }
    }
  }
  #pragma unroll
  for (int j = 0; j < 4; j++) {
    int px = 4 * pq + j;
    if (px >= width) continue;
    int p = h * Wd + w0 + px;
    #pragma unroll
    for (int o = 0; o < 4; o++) {
      int c = g * 4 + o;
      unsigned int cu = pf2[o][1][(j + 1) >> 1];
      float ufc = ((j + 1) & 1) ? bfhi(cu) : bflo(cu);
      float xk = acc[j][o] * ga1[c] + ufc;
      float xv = xk * b2f(x1[((size_t)b * Cc + c) * HWp + p]) * scaV[b * 64 + c];
      out[((size_t)b * Cc + c) * HWp + p] = f2b(xv);
    }
  }
}

// ---------------- c3 1x1 conv + residual: y = inp + (conv)*beta (fp32 out) ----------------
__global__ void k_c3y(const bf16* __restrict__ xprod, const float* __restrict__ w,
                      const float* __restrict__ bias, const float* __restrict__ beta,
                      const float* __restrict__ inp, float* __restrict__ y) {
  int p = blockIdx.x * 64 + threadIdx.x;
  int o = blockIdx.y * 4 + threadIdx.y;
  int b = blockIdx.z;
  float acc = bias[o];
  const bf16* src = xprod + (size_t)b * Cc * HWp + p;
  const float* wr = w + o * 64;
  for (int k = 0; k < 64; k++) acc += wr[k] * b2f(src[(size_t)k * HWp]);
  size_t oi = ((size_t)b * Cc + o) * HWp + p;
  y[oi] = inp[oi] + acc * beta[o];
}

// ---------------- LayerNorm, fp32 in (y in d_out) -> bf16 ws out ----------------
__global__ void k_ln2(const float* __restrict__ in, const float* __restrict__ w,
                      const float* __restrict__ bb, bf16* __restrict__ out) {
  int idx = blockIdx.x * 256 + threadIdx.x;
  int b = idx / HWp, p = idx - b * HWp;
  const float* src = in + (size_t)b * Cc * HWp + p;
  float s = 0.f, s2 = 0.f;
  for (int c = 0; c < Cc; c++) { float v = src[(size_t)c * HWp]; s += v; s2 += v * v; }
  float mu = s * (1.f / 64.f);
  float var = s2 * (1.f / 64.f) - mu * mu;
  float rs = rsqrtf(fmaxf(var, 0.f) + 1e-6f);
  bf16* dst = out + (size_t)b * Cc * HWp + p;
  for (int c = 0; c < Cc; c++) {
    float v = src[(size_t)c * HWp];
    dst[(size_t)c * HWp] = f2b((v - mu) * rs * w[c] + bb[c]);
  }
}

// ---------------- one DFT pass with transpose ----------------
__global__ __launch_bounds__(256) void k_cpass(
    const bf16* __restrict__ inr, const bf16* __restrict__ ini,
    bf16* __restrict__ outr, bf16* __restrict__ outi,
    float sgn, float scale,
    const float* __restrict__ sclr, const float* __restrict__ scli) {
  int plane = blockIdx.z;
  int a0 = blockIdx.x * 64, c0 = blockIdx.y * 64;
  __shared__ __align__(16) float Lr[32][68], Li[32][68], Lc[32][68], Ls[32][68];
  int t = threadIdx.x;
  int ta = t & 15, tc = t >> 4;
  float ar[4][4], ai[4][4];
  #pragma unroll
  for (int j = 0; j < 4; j++) for (int k = 0; k < 4; k++) { ar[j][k] = 0.f; ai[j][k] = 0.f; }
  const bf16* pr = inr + (size_t)plane * HWp;
  const bf16* pi = ini ? ini + (size_t)plane * HWp : nullptr;
  float srm = sclr ? sclr[plane] : 1.f;
  float sim = scli ? scli[plane] : 1.f;
  for (int b0 = 0; b0 < 160; b0 += 32) {
    __syncthreads();
    for (int i = t; i < 32 * 64; i += 256) {
      int bb = i & 31, aa = i >> 5;
      int a = a0 + aa;
      float vr = 0.f, vi = 0.f;
      if (a < 160) {
        vr = b2f(pr[a * 160 + b0 + bb]) * srm;
        if (pi) vi = b2f(pi[a * 160 + b0 + bb]) * sim;
      }
      Lr[bb][aa] = vr; Li[bb][aa] = vi;
    }
    for (int i = t; i < 32 * 64; i += 256) {
      int cc = i & 63, bb = i >> 6;
      int c = c0 + cc;
      float vc = 0.f, vs = 0.f;
      if (c < 160) {
        int m = ((b0 + bb) * c) % 160;
        float sv, cv;
        __sincosf((float)m * TWO_PI_160, &sv, &cv);
        vc = cv; vs = sv * sgn;
      }
      Lc[bb][cc] = vc; Ls[bb][cc] = vs;
    }
    __syncthreads();
    for (int bb = 0; bb < 32; bb++) {
      float4 x4 = *(const float4*)&Lr[bb][ta * 4];
      float4 y4 = *(const float4*)&Li[bb][ta * 4];
      float4 c4 = *(const float4*)&Lc[bb][tc * 4];
      float4 s4 = *(const float4*)&Ls[bb][tc * 4];
      float xr[4] = {x4.x, x4.y, x4.z, x4.w};
      float xi[4] = {y4.x, y4.y, y4.z, y4.w};
      float cs[4] = {c4.x, c4.y, c4.z, c4.w};
      float sn[4] = {s4.x, s4.y, s4.z, s4.w};
      #pragma unroll
      for (int j = 0; j < 4; j++)
        #pragma unroll
        for (int k = 0; k < 4; k++) {
          ar[j][k] += xr[j] * cs[k] - xi[j] * sn[k];
          ai[j][k] += xr[j] * sn[k] + xi[j] * cs[k];
        }
    }
  }
  for (int k = 0; k < 4; k++) {
    int c = c0 + tc * 4 + k;
    if (c >= 160) continue;
    for (int j = 0; j < 4; j++) {
      int a = a0 + ta * 4 + j;
      if (a >= 160) continue;
      outr[(size_t)plane * HWp + c * 160 + a] = f2b(ar[j][k] * scale);
      outi[(size_t)plane * HWp + c * 160 + a] = f2b(ai[j][k] * scale);
    }
  }
}

// ---------------- final inverse pass, fused |.|, *gamma, += y (fp32 d_out) ----------------
__global__ __launch_bounds__(256) void k_cpass_final(
    const bf16* __restrict__ inr, const bf16* __restrict__ ini,
    float sgn, float scale,
    const float* __restrict__ gamma, float* __restrict__ dout) {
  int plane = blockIdx.z;
  int a0 = blockIdx.x * 64, c0 = blockIdx.y * 64;
  __shared__ __align__(16) float Lr[32][68], Li[32][68], Lc[32][68], Ls[32][68];
  int t = threadIdx.x;
  int ta = t & 15, tc = t >> 4;
  float ar[4][4], ai[4][4];
  #pragma unroll
  for (int j = 0; j < 4; j++) for (int k = 0; k < 4; k++) { ar[j][k] = 0.f; ai[j][k] = 0.f; }
  const bf16* pr = inr + (size_t)plane * HWp;
  const bf16* pi = ini + (size_t)plane * HWp;
  for (int b0 = 0; b0 < 160; b0 += 32) {
    __syncthreads();
    for (int i = t; i < 32 * 64; i += 256) {
      int bb = i & 31, aa = i >> 5;
      int a = a0 + aa;
      float vr = 0.f, vi = 0.f;
      if (a < 160) { vr = b2f(pr[a * 160 + b0 + bb]); vi = b2f(pi[a * 160 + b0 + bb]); }
      Lr[bb][aa] = vr; Li[bb][aa] = vi;
    }
    for (int i = t; i < 32 * 64; i += 256) {
      int cc = i & 63, bb = i >> 6;
      int c = c0 + cc;
      float vc = 0.f, vs = 0.f;
      if (c < 160) {
        int m = ((b0 + bb) * c) % 160;
        float sv, cv;
        __sincosf((float)m * TWO_PI_160, &sv, &cv);
        vc = cv; vs = sv * sgn;
      }
      Lc[bb][cc] = vc; Ls[bb][cc] = vs;
    }
    __syncthreads();
    for (int bb = 0; bb < 32; bb++) {
      float4 x4 = *(const float4*)&Lr[bb][ta * 4];
      float4 y4 = *(const float4*)&Li[bb][ta * 4];
      float4 c4 = *(const float4*)&Lc[bb][tc * 4];
      float4 s4 = *(const float4*)&Ls[bb][tc * 4];
      float xr[4] = {x4.x, x4.y, x4.z, x4.w};
      float xi[4] = {y4.x, y4.y, y4.z, y4.w};
      float cs[4] = {c4.x, c4.y, c4.z, c4.w};
      float sn[4] = {s4.x, s4.y, s4.z, s4.w};
      #pragma unroll
      for (int j = 0; j < 4; j++)
        #pragma unroll
        for (int k = 0; k < 4; k++) {
          ar[j][k] += xr[j] * cs[k] - xi[j] * sn[k];
          ai[j][k] += xr[j] * sn[k] + xi[j] * cs[k];
        }
    }
  }
  int ch = plane & 63;
  float gm = gamma[ch];
  for (int k = 0; k < 4; k++) {
    int c = c0 + tc * 4 + k;          // = h
    if (c >= 160) continue;
    for (int j = 0; j < 4; j++) {
      int a = a0 + ta * 4 + j;        // = w
      if (a >= 160) continue;
      float rr = ar[j][k] * scale, ii = ai[j][k] * scale;
      float z = sqrtf(rr * rr + ii * ii);
      size_t oi = (size_t)plane * HWp + c * 160 + a;
      dout[oi] = dout[oi] + z * gm;   // dout currently holds y
    }
  }
}

// ---------------- fc1 (128->256) + simple_gate, MFMA ----------------
// wave = 16 px, all 256 rows: 16 m-tiles x 4 k-chunks of mfma_f32_16x16x32_bf16.
// C/D layout: col=lane&15 (px), row=(lane>>4)*4+reg (o). Gating in-register.
__global__ __launch_bounds__(256) void k_fc1_mfma(
    const bf16* __restrict__ Fr, const bf16* __restrict__ Fi,
    const short* __restrict__ wA, const float* __restrict__ bias,
    bf16* __restrict__ G1, bf16* __restrict__ G2) {
  int b = blockIdx.z;
  int lane = threadIdx.x & 63, w = threadIdx.x >> 6;
  int px = blockIdx.x * 64 + w * 16 + (lane & 15);
  int q = lane >> 4;
  const unsigned short* fr = (const unsigned short*)Fr + (size_t)b * Cc * HWp;
  const unsigned short* fi = (const unsigned short*)Fi + (size_t)b * Cc * HWp;
  const short8* wf = (const short8*)wA;
  f32x4 acc[16];
  #pragma unroll
  for (int mt = 0; mt < 16; mt++) acc[mt] = (f32x4){0.f, 0.f, 0.f, 0.f};
  #pragma unroll
  for (int kc = 0; kc < 4; kc++) {
    const unsigned short* basep = (kc < 2) ? (fr + (size_t)(kc * 32) * HWp)
                                           : (fi + (size_t)((kc - 2) * 32) * HWp);
    short8 bfv;
    #pragma unroll
    for (int j = 0; j < 8; j++) bfv[j] = (short)basep[(size_t)(q * 8 + j) * HWp + px];
    #pragma unroll
    for (int mt = 0; mt < 16; mt++) {
      short8 af = wf[(mt * 4 + kc) * 64 + lane];
      acc[mt] = __builtin_amdgcn_mfma_f32_16x16x32_bf16(af, bfv, acc[mt], 0, 0, 0);
    }
  }
  unsigned short* g1 = (unsigned short*)G1 + (size_t)b * Cc * HWp;
  unsigned short* g2 = (unsigned short*)G2 + (size_t)b * Cc * HWp;
  #pragma unroll
  for (int mt = 0; mt < 8; mt++)
    #pragma unroll
    for (int j = 0; j < 4; j++) {
      int o = mt * 16 + q * 4 + j;
      float v1 = acc[mt][j] + bias[o];
      float v2 = acc[mt + 8][j] + bias[o + 128];
      unsigned short hv = f2bu(v1 * v2);
      if (o < 64) g1[(size_t)o * HWp + px] = hv;
      else        g2[(size_t)(o - 64) * HWp + px] = hv;
    }
}

// ---------------- fc2 (128->128) MFMA, split output into r / i planes ----------------
__global__ __launch_bounds__(256) void k_fc2_mfma(
    const bf16* __restrict__ G1, const bf16* __restrict__ G2,
    const short* __restrict__ wA, const float* __restrict__ bias,
    bf16* __restrict__ Or, bf16* __restrict__ Oi) {
  int b = blockIdx.z;
  int lane = threadIdx.x & 63, w = threadIdx.x >> 6;
  int px = blockIdx.x * 64 + w * 16 + (lane & 15);
  int q = lane >> 4;
  const unsigned short* g1 = (const unsigned short*)G1 + (size_t)b * Cc * HWp;
  const unsigned short* g2 = (const unsigned short*)G2 + (size_t)b * Cc * HWp;
  const short8* wf = (const short8*)wA;
  f32x4 acc[8];
  #pragma unroll
  for (int mt = 0; mt < 8; mt++) acc[mt] = (f32x4){0.f, 0.f, 0.f, 0.f};
  #pragma unroll
  for (int kc = 0; kc < 4; kc++) {
    const unsigned short* basep = (kc < 2) ? (g1 + (size_t)(kc * 32) * HWp)
                                           : (g2 + (size_t)((kc - 2) * 32) * HWp);
    short8 bfv;
    #pragma unroll
    for (int j = 0; j < 8; j++) bfv[j] = (short)basep[(size_t)(q * 8 + j) * HWp + px];
    #pragma unroll
    for (int mt = 0; mt < 8; mt++) {
      short8 af = wf[(mt * 4 + kc) * 64 + lane];
      acc[mt] = __builtin_amdgcn_mfma_f32_16x16x32_bf16(af, bfv, acc[mt], 0, 0, 0);
    }
  }
  unsigned short* orp = (unsigned short*)Or + (size_t)b * Cc * HWp;
  unsigned short* oip = (unsigned short*)Oi + (size_t)b * Cc * HWp;
  #pragma unroll
  for (int mt = 0; mt < 8; mt++)
    #pragma unroll
    for (int j = 0; j < 4; j++) {
      int o = mt * 16 + q * 4 + j;
      unsigned short hv = f2bu(acc[mt][j] + bias[o]);
      if (o < 64) orp[(size_t)o * HWp + px] = hv;
      else        oip[(size_t)(o - 64) * HWp + px] = hv;
    }
}

extern "C" void kernel_launch(void* const* d_in, const int* in_sizes, int n_in,
                              void* d_out, int out_size, void* d_ws, size_t ws_size,
                              hipStream_t stream) {
  const float* inp   = (const float*)d_in[0];
  const float* n1w   = (const float*)d_in[1];
  const float* n1b   = (const float*)d_in[2];
  const float* n2w   = (const float*)d_in[3];
  const float* n2b   = (const float*)d_in[4];
  const float* scaw  = (const float*)d_in[5];
  const float* scab  = (const float*)d_in[6];
  const float* c11aw = (const float*)d_in[7];
  const float* c11ab = (const float*)d_in[8];
  const float* c11bw = (const float*)d_in[9];
  const float* c11bb = (const float*)d_in[10];
  const float* c1w   = (const float*)d_in[11];
  const float* c1b   = (const float*)d_in[12];
  const float* c21w  = (const float*)d_in[13];
  const float* c21b  = (const float*)d_in[14];
  const float* c2aw  = (const float*)d_in[15];
  const float* c2ab  = (const float*)d_in[16];
  const float* c2cw  = (const float*)d_in[17];
  const float* c2cb  = (const float*)d_in[18];
  const float* c211w = (const float*)d_in[19];
  const float* c211b = (const float*)d_in[20];
  const float* c3w   = (const float*)d_in[21];
  const float* c3b   = (const float*)d_in[22];
  const float* kbw   = (const float*)d_in[23];
  const float* kbb   = (const float*)d_in[24];
  const float* ga1   = (const float*)d_in[25];
  const float* attg  = (const float*)d_in[26];
  const float* beta  = (const float*)d_in[27];
  const float* gamma = (const float*)d_in[28];
  const float* fc1w  = (const float*)d_in[29];
  const float* fc1b  = (const float*)d_in[30];
  const float* fc2w  = (const float*)d_in[31];
  const float* fc2b  = (const float*)d_in[32];
  const float* fscaw = (const float*)d_in[33];
  const float* fscab = (const float*)d_in[34];

  const size_t S = (size_t)Bn * Cc * HWp;   // 3,276,800 elements per slot
  bf16* A  = (bf16*)d_ws;                   // 4 bf16 slots = 26.2 MB total
  bf16* Bs = A + S;
  bf16* Cs = A + 2 * S;
  bf16* Ds = A + 3 * S;
  float* smalls = (float*)(A + 4 * S);      // fp32 smalls
  float* xm   = smalls;
  float* scaV = smalls + 128;
  float* rmv  = smalls + 256;
  float* imv  = smalls + 384;
  float* sra  = smalls + 512;
  float* sia  = smalls + 640;
  float* kbwT = smalls + 1024;              // 73728 floats = 295 KB
  short* wAf1 = (short*)(kbwT + 73728);     // 32768 shorts = 64 KB
  short* wAf2 = wAf1 + 32768;               // 16384 shorts = 32 KB  (ws ~26.6 MB)
  bf16* gbuf = Bs;            // [B,32,HW] (first half of Bs)
  bf16* attb = Bs + S / 2;    // [B,32,HW] (second half of Bs)
  float* yb  = (float*)d_out; // y lives in d_out (fp32)

  dim3 blk(64, 4, 1);

  k_kbwT<<<dim3(288), dim3(256), 0, stream>>>(kbw, kbwT);               // kbwT (independent)
  k_wprep<<<dim3(192), dim3(256), 0, stream>>>(fc1w, fc2w, wAf1, wAf2); // fc frags (independent)
  k_ln<<<dim3(200), dim3(256), 0, stream>>>(inp, n1w, n1b, A);          // A = x
  k_meanhw<<<dim3(128), dim3(256), 0, stream>>>(A, xm);
  k_small_mv<<<dim3(1), dim3(128), 0, stream>>>(xm, scaw, scab, scaV, 0);
  k_conv1x1<<<dim3(400, 16, Bn), blk, 0, stream>>>(A, c11aw, c11ab, Bs, 64, 64);   // B = t1
  k_c11b<<<dim3(400, 16, Bn), blk, 0, stream>>>(Bs, c11bw, c11bb, Cs);             // C = x1 (B dead)
  k_c2a<<<dim3(400, 8, Bn), blk, 0, stream>>>(A, c2aw, c2ab, gbuf);                // B.lo = g
  k_att<<<dim3(400, 8, Bn), blk, 0, stream>>>(gbuf, A, c2cw, c2cb, c211w, c211b, attg, attb); // B.hi = att
  k_conv1x1<<<dim3(400, 16, Bn), blk, 0, stream>>>(A, c1w, c1b, Ds, 64, 64);       // D = t2 (A dead after)
  k_c21dw<<<dim3(400, 16, Bn), blk, 0, stream>>>(Ds, c21w, c21b, A);               // A = uf
  k_kba<<<dim3(3, 160, Bn), dim3(256), 0, stream>>>(A, attb, Cs, scaV, kbwT, kbb, ga1, Ds); // D = xprod
  k_c3y<<<dim3(400, 16, Bn), blk, 0, stream>>>(Ds, c3w, c3b, beta, inp, yb);       // d_out = y (fp32)
  k_ln2<<<dim3(200), dim3(256), 0, stream>>>(yb, n2w, n2b, A);                     // A = X
  // forward FFT2: pass over W ([h][w] -> [u][h]), then over H ([u][h] -> [v][u])
  k_cpass<<<dim3(3, 3, Bn * Cc), dim3(256), 0, stream>>>(A, (const bf16*)nullptr, Bs, Cs, -1.f, SCL, nullptr, nullptr); // B,C = F1 (A dead)
  k_cpass<<<dim3(3, 3, Bn * Cc), dim3(256), 0, stream>>>(Bs, Cs, Ds, A, -1.f, SCL, nullptr, nullptr);                   // D,A = F2
  k_fc1_mfma<<<dim3(400, 1, Bn), dim3(256), 0, stream>>>(Ds, A, wAf1, fc1b, Bs, Cs);  // B,C = gated
  k_fc2_mfma<<<dim3(400, 1, Bn), dim3(256), 0, stream>>>(Bs, Cs, wAf2, fc2b, Ds, A);  // D = r, A = i
  k_meanhw<<<dim3(128), dim3(256), 0, stream>>>(Ds, rmv);
  k_meanhw<<<dim3(128), dim3(256), 0, stream>>>(A, imv);
  k_small_mv<<<dim3(1), dim3(128), 0, stream>>>(rmv, fscaw, fscab, sra, 1);
  k_small_mv<<<dim3(1), dim3(128), 0, stream>>>(imv, fscaw, fscab, sia, 1);
  // inverse FFT2 with per-plane (1+ra)/(1+ia) scaling fused into first pass
  k_cpass<<<dim3(3, 3, Bn * Cc), dim3(256), 0, stream>>>(Ds, A, Bs, Cs, 1.f, SCL, sra, sia);  // B,C
  k_cpass_final<<<dim3(3, 3, Bn * Cc), dim3(256), 0, stream>>>(Bs, Cs, 1.f, SCL, gamma, yb);  // d_out = y + |z|*gamma
}

// Round 9
// 916.534 us; speedup vs baseline: 2.1431x; 1.4522x over previous
//
#include <hip/hip_runtime.h>
#include <hip/hip_bf16.h>

typedef __hip_bfloat16 bf16;
typedef __attribute__((ext_vector_type(8))) short short8;
typedef __attribute__((ext_vector_type(4))) float f32x4;

#define Hh 160
#define Wd 160
#define HWp (Hh*Wd)       // 25600
#define Bn 2
#define Cc 64
#define NPIX (Bn*HWp)     // 51200
#define SCL 0.07905694150420949f   // 1/sqrt(160)
#define TWO_PI_160 0.039269908169872414f  // 2*pi/160

static __device__ __forceinline__ float b2f(bf16 x) { return __bfloat162float(x); }
static __device__ __forceinline__ bf16 f2b(float f) { return __float2bfloat16(f); }
static __device__ __forceinline__ unsigned short f2bu(float f) {
  union { bf16 h; unsigned short u; } z; z.h = __float2bfloat16(f); return z.u;
}
static __device__ __forceinline__ float bflo(unsigned int u) {
  union { unsigned int i; float f; } z; z.i = u << 16; return z.f;
}
static __device__ __forceinline__ float bfhi(unsigned int u) {
  union { unsigned int i; float f; } z; z.i = u & 0xffff0000u; return z.f;
}

// ---------------- LayerNorm over channel dim (per pixel), fp32 in -> bf16 out ----------------
__global__ void k_ln(const float* __restrict__ in, const float* __restrict__ w,
                     const float* __restrict__ bb, bf16* __restrict__ out) {
  int idx = blockIdx.x * 256 + threadIdx.x;   // grid covers exactly NPIX
  int b = idx / HWp, p = idx - b * HWp;
  const float* src = in + (size_t)b * Cc * HWp + p;
  float s = 0.f, s2 = 0.f;
  for (int c = 0; c < Cc; c++) { float v = src[(size_t)c * HWp]; s += v; s2 += v * v; }
  float mu = s * (1.f / 64.f);
  float var = s2 * (1.f / 64.f) - mu * mu;
  float rs = rsqrtf(fmaxf(var, 0.f) + 1e-6f);
  bf16* dst = out + (size_t)b * Cc * HWp + p;
  for (int c = 0; c < Cc; c++) {
    float v = src[(size_t)c * HWp];
    dst[(size_t)c * HWp] = f2b((v - mu) * rs * w[c] + bb[c]);
  }
}

// ---------------- mean over HW per (b,c) plane (bf16 in) ----------------
__global__ void k_meanhw(const bf16* __restrict__ in, float* __restrict__ out) {
  int bc = blockIdx.x;
  const bf16* src = in + (size_t)bc * HWp;
  int t = threadIdx.x;
  float s = 0.f;
  for (int i = t; i < HWp; i += 256) s += b2f(src[i]);
  __shared__ float sm[256];
  sm[t] = s; __syncthreads();
  for (int off = 128; off; off >>= 1) { if (t < off) sm[t] += sm[t + off]; __syncthreads(); }
  if (t == 0) out[bc] = sm[0] * (1.f / HWp);
}

// ---------------- small matvec: out[b,o] = (addone) + W[o,:]·xin[b,:] + bias[o] ----------------
__global__ void k_small_mv(const float* __restrict__ xin, const float* __restrict__ w,
                           const float* __restrict__ bias, float* __restrict__ out, int addone) {
  int t = threadIdx.x;              // 128 threads
  int b = t >> 6, o = t & 63;
  float acc = bias[o];
  for (int k = 0; k < 64; k++) acc += w[o * 64 + k] * xin[b * 64 + k];
  out[t] = addone ? (1.f + acc) : acc;
}

// ---------------- generic 1x1 conv, bf16 ws in/out, fp32 weights ----------------
__global__ void k_conv1x1(const bf16* __restrict__ in, const float* __restrict__ w,
                          const float* __restrict__ bias, bf16* __restrict__ out,
                          int Cin, int Cout) {
  int p = blockIdx.x * 64 + threadIdx.x;
  int o = blockIdx.y * 4 + threadIdx.y;
  int b = blockIdx.z;
  float acc = bias[o];
  const bf16* src = in + (size_t)b * Cin * HWp + p;
  const float* wr = w + (size_t)o * Cin;
  for (int k = 0; k < Cin; k++) acc += wr[k] * b2f(src[(size_t)k * HWp]);
  out[((size_t)b * Cout + o) * HWp + p] = f2b(acc);
}

// ---------------- c11b: grouped 5x5 conv, groups=16 (4ch/group), pad 2 ----------------
__global__ void k_c11b(const bf16* __restrict__ in, const float* __restrict__ w,
                       const float* __restrict__ bias, bf16* __restrict__ out) {
  int p = blockIdx.x * 64 + threadIdx.x;
  int o = blockIdx.y * 4 + threadIdx.y;
  int b = blockIdx.z;
  int h = p / Wd, x = p - h * Wd;
  int gb = (o >> 2) << 2;
  float acc = bias[o];
  for (int ci = 0; ci < 4; ci++) {
    const bf16* src = in + ((size_t)b * Cc + gb + ci) * HWp;
    for (int ki = 0; ki < 5; ki++) {
      int hh = h + ki - 2; if ((unsigned)hh >= Hh) continue;
      for (int kj = 0; kj < 5; kj++) {
        int ww = x + kj - 2; if ((unsigned)ww >= Wd) continue;
        acc += w[((o * 4 + ci) * 5 + ki) * 5 + kj] * b2f(src[hh * Wd + ww]);
      }
    }
  }
  out[((size_t)b * Cc + o) * HWp + p] = f2b(acc);
}

// ---------------- c2a: grouped 3x3, 64->32, groups=32 (2 in-ch/group), pad 1 ----------------
__global__ void k_c2a(const bf16* __restrict__ in, const float* __restrict__ w,
                      const float* __restrict__ bias, bf16* __restrict__ out) {
  int p = blockIdx.x * 64 + threadIdx.x;
  int o = blockIdx.y * 4 + threadIdx.y;   // 0..31
  int b = blockIdx.z;
  int h = p / Wd, x = p - h * Wd;
  float acc = bias[o];
  for (int ci = 0; ci < 2; ci++) {
    const bf16* src = in + ((size_t)b * Cc + o * 2 + ci) * HWp;
    for (int ki = 0; ki < 3; ki++) {
      int hh = h + ki - 1; if ((unsigned)hh >= Hh) continue;
      for (int kj = 0; kj < 3; kj++) {
        int ww = x + kj - 1; if ((unsigned)ww >= Wd) continue;
        acc += w[((o * 2 + ci) * 3 + ki) * 3 + kj] * b2f(src[hh * Wd + ww]);
      }
    }
  }
  out[((size_t)b * 32 + o) * HWp + p] = f2b(acc);
}

// ---------------- att = c2c(gate(g))*attgamma + c211(x) ----------------
__global__ void k_att(const bf16* __restrict__ g, const bf16* __restrict__ x,
                      const float* __restrict__ c2cw, const float* __restrict__ c2cb,
                      const float* __restrict__ c211w, const float* __restrict__ c211b,
                      const float* __restrict__ attg, bf16* __restrict__ att) {
  int p = blockIdx.x * 64 + threadIdx.x;
  int s = blockIdx.y * 4 + threadIdx.y;   // 0..31
  int b = blockIdx.z;
  float a1 = c2cb[s];
  const bf16* gs = g + (size_t)b * 32 * HWp + p;
  for (int k = 0; k < 16; k++)
    a1 += c2cw[s * 16 + k] * b2f(gs[(size_t)k * HWp]) * b2f(gs[(size_t)(16 + k) * HWp]);
  float acc = a1 * attg[s] + c211b[s];
  const bf16* xs = x + (size_t)b * Cc * HWp + p;
  for (int c = 0; c < Cc; c++) acc += c211w[s * 64 + c] * b2f(xs[(size_t)c * HWp]);
  att[((size_t)b * 32 + s) * HWp + p] = f2b(acc);
}

// ---------------- depthwise 3x3, pad 1 ----------------
__global__ void k_c21dw(const bf16* __restrict__ in, const float* __restrict__ w,
                        const float* __restrict__ bias, bf16* __restrict__ out) {
  int p = blockIdx.x * 64 + threadIdx.x;
  int c = blockIdx.y * 4 + threadIdx.y;
  int b = blockIdx.z;
  int h = p / Wd, x = p - h * Wd;
  float acc = bias[c];
  const bf16* src = in + ((size_t)b * Cc + c) * HWp;
  for (int ki = 0; ki < 3; ki++) {
    int hh = h + ki - 1; if ((unsigned)hh >= Hh) continue;
    for (int kj = 0; kj < 3; kj++) {
      int ww = x + kj - 1; if ((unsigned)ww >= Wd) continue;
      acc += w[c * 9 + ki * 3 + kj] * b2f(src[hh * Wd + ww]);
    }
  }
  out[((size_t)b * Cc + c) * HWp + p] = f2b(acc);
}

// ---------------- kb_w pre-transpose: kbwT[s][d][g][o] <- kbw[s][g][o][d] ----------------
__global__ void k_kbwT(const float* __restrict__ kbw, float* __restrict__ kbwT) {
  int i = blockIdx.x * 256 + threadIdx.x;       // 73728 total (288 blocks)
  int o = i & 3, g = (i >> 2) & 15, rest = i >> 6;  // rest = s*36 + d
  int d = rest % 36, s = rest / 36;
  kbwT[i] = kbw[s * 2304 + g * 144 + o * 36 + d];
}

// ---------------- fc weight prep: bf16 MFMA A-fragment order ----------------
// frag[(mt*4+kc)*64 + lane][j] = W[mt*16 + (lane&15)][kc*32 + (lane>>4)*8 + j]
__global__ void k_wprep(const float* __restrict__ fc1w, const float* __restrict__ fc2w,
                        short* __restrict__ wAf1, short* __restrict__ wAf2) {
  int i = blockIdx.x * 256 + threadIdx.x;   // 49152 total (192 blocks)
  if (i < 32768) {
    int j = i & 7, lane = (i >> 3) & 63, fk = i >> 9;
    int kc = fk & 3, mt = fk >> 2;          // mt 0..15
    int o = mt * 16 + (lane & 15);
    int k = kc * 32 + (lane >> 4) * 8 + j;
    wAf1[i] = (short)f2bu(fc1w[o * 128 + k]);
  } else {
    int i2 = i - 32768;
    int j = i2 & 7, lane = (i2 >> 3) & 63, fk = i2 >> 9;
    int kc = fk & 3, mt = fk >> 2;          // mt 0..7
    int o = mt * 16 + (lane & 15);
    int k = kc * 32 + (lane >> 4) * 8 + j;
    wAf2[i2] = (short)f2bu(fc2w[o * 128 + k]);
  }
}

// ---------------- DFT twiddle tables in MFMA A-fragment order ----------------
// A[m=c][k=b]: frag[(ct*5+kc)*512 + lane*8 + j] = T[b][c], c=ct*16+(lane&15),
// b=kc*32+(lane>>4)*8+j.  cos and sin stored separately (sign applied in epilogue).
__global__ void k_dftfrag(short* __restrict__ cosF, short* __restrict__ sinF) {
  int i = blockIdx.x * 256 + threadIdx.x;   // 25600 total (100 blocks)
  int j = i & 7, lane = (i >> 3) & 63, fk = i >> 9;   // fk = ct*5+kc, 0..49
  int kc = fk % 5, ct = fk / 5;
  int c = ct * 16 + (lane & 15);
  int b = kc * 32 + (lane >> 4) * 8 + j;
  int m = (b * c) % 160;
  float sv, cv;
  __sincosf((float)m * TWO_PI_160, &sv, &cv);
  cosF[i] = (short)f2bu(cv);
  sinF[i] = (short)f2bu(sv);
}

// ---------------- KBA fused: out = ((kba+bias)*ga1 + uf) * x1 * sca ----------------
__global__ __launch_bounds__(256, 4) void k_kba(
    const bf16* __restrict__ uf, const bf16* __restrict__ att,
    const bf16* __restrict__ x1, const float* __restrict__ scaV,
    const float* __restrict__ kbwT, const float* __restrict__ kbb,
    const float* __restrict__ ga1, bf16* __restrict__ out) {
  __shared__ __align__(16) unsigned char shmem[64 * 3 * 66 * 2];  // 25344 B
  unsigned short* patchL = (unsigned short*)shmem;   // [c][ki][col] bf16, live until hoist
  float* kwL = (float*)shmem;                        // [si][d][g][o] fp32 (4608 floats)
  __shared__ float attL[64][33];                     // 8448 B
  int b = blockIdx.z, h = blockIdx.y;
  int w0 = blockIdx.x * 64;
  int width = min(64, Wd - w0);
  int t = threadIdx.x;
  const unsigned short* uf_u = (const unsigned short*)uf;
  for (int i = t; i < 64 * 3 * 66; i += 256) {
    int c = i / 198, rem = i - c * 198;
    int r = rem / 66, col = rem - r * 66;
    int hh = h + r - 1, ww = w0 + col - 1;
    unsigned short v = 0;
    if ((unsigned)hh < Hh && (unsigned)ww < Wd)
      v = uf_u[((size_t)b * Cc + c) * HWp + hh * Wd + ww];
    patchL[i] = v;
  }
  for (int i = t; i < 64 * 32; i += 256) {
    int px = i & 63, s = i >> 6;
    float v = 0.f;
    if (px < width) v = b2f(att[((size_t)b * 32 + s) * HWp + h * Wd + w0 + px]);
    attL[px][s] = v;
  }
  __syncthreads();
  int g = t & 15, pq = t >> 4;
  unsigned int pf2[4][3][3];
  #pragma unroll
  for (int ci = 0; ci < 4; ci++)
    #pragma unroll
    for (int ki = 0; ki < 3; ki++) {
      const unsigned int* pr32 =
          (const unsigned int*)&patchL[(g * 4 + ci) * 198 + ki * 66 + 4 * pq];
      #pragma unroll
      for (int m2 = 0; m2 < 3; m2++) pf2[ci][ki][m2] = pr32[m2];
    }
  float acc[4][4];
  #pragma unroll
  for (int j = 0; j < 4; j++)
    #pragma unroll
    for (int o = 0; o < 4; o++) acc[j][o] = 0.f;
  for (int s = 0; s < 32; s++) {
    float kv[4];
    #pragma unroll
    for (int o = 0; o < 4; o++) kv[o] = kbb[s * 64 + g * 4 + o];
    #pragma unroll
    for (int j = 0; j < 4; j++) {
      float av = attL[4 * pq + j][s];
      #pragma unroll
      for (int o = 0; o < 4; o++) acc[j][o] += av * kv[o];
    }
  }
  for (int sc = 0; sc < 16; sc++) {
    __syncthreads();
    for (int i = t; i < 2 * 2304; i += 256)
      kwL[i] = kbwT[sc * 4608 + i];
    __syncthreads();
    #pragma unroll
    for (int si = 0; si < 2; si++) {
      int s = sc * 2 + si;
      float a0 = attL[4 * pq + 0][s], a1 = attL[4 * pq + 1][s];
      float a2 = attL[4 * pq + 2][s], a3 = attL[4 * pq + 3][s];
      const float* wbase = &kwL[si * 2304 + g * 4];
      #pragma unroll
      for (int ci = 0; ci < 4; ci++)
        #pragma unroll
        for (int ki = 0; ki < 3; ki++) {
          float w0f = bflo(pf2[ci][ki][0]), w1f = bfhi(pf2[ci][ki][0]);
          float w2f = bflo(pf2[ci][ki][1]), w3f = bfhi(pf2[ci][ki][1]);
          float w4f = bflo(pf2[ci][ki][2]), w5f = bfhi(pf2[ci][ki][2]);
          float win[6] = {w0f, w1f, w2f, w3f, w4f, w5f};
          #pragma unroll
          for (int kj = 0; kj < 3; kj++) {
            int d = ci * 9 + ki * 3 + kj;
            float4 wv = *(const float4*)&wbase[d * 64];
            float p0 = win[kj + 0] * a0;
            float p1 = win[kj + 1] * a1;
            float p2 = win[kj + 2] * a2;
            float p3 = win[kj + 3] * a3;
            acc[0][0] += p0 * wv.x; acc[0][1] += p0 * wv.y; acc[0][2] += p0 * wv.z; acc[0][3] += p0 * wv.w;
            acc[1][0] += p1 * wv.x; acc[1][1] += p1 * wv.y; acc[1][2] += p1 * wv.z; acc[1][3] += p1 * wv.w;
            acc[2][0] += p2 * wv.x; acc[2][1] += p2 * wv.y; acc[2][2] += p2 * wv.z; acc[2][3] += p2 * wv.w;
            acc[3][0] += p3 * wv.x; acc[3][1] += p3 * wv.y; acc[3][2] += p3 * wv.z; acc[3][3] += p3 * wv.w;
          }
        }
    }
  }
  #pragma unroll
  for (int j = 0; j < 4; j++) {
    int px = 4 * pq + j;
    if (px >= width) continue;
    int p = h * Wd + w0 + px;
    #pragma unroll
    for (int o = 0; o < 4; o++) {
      int c = g * 4 + o;
      unsigned int cu = pf2[o][1][(j + 1) >> 1];
      float ufc = ((j + 1) & 1) ? bfhi(cu) : bflo(cu);
      float xk = acc[j][o] * ga1[c] + ufc;
      float xv = xk * b2f(x1[((size_t)b * Cc + c) * HWp + p]) * scaV[b * 64 + c];
      out[((size_t)b * Cc + c) * HWp + p] = f2b(xv);
    }
  }
}

// ---------------- c3 1x1 conv + residual: y = inp + (conv)*beta (fp32 out) ----------------
__global__ void k_c3y(const bf16* __restrict__ xprod, const float* __restrict__ w,
                      const float* __restrict__ bias, const float* __restrict__ beta,
                      const float* __restrict__ inp, float* __restrict__ y) {
  int p = blockIdx.x * 64 + threadIdx.x;
  int o = blockIdx.y * 4 + threadIdx.y;
  int b = blockIdx.z;
  float acc = bias[o];
  const bf16* src = xprod + (size_t)b * Cc * HWp + p;
  const float* wr = w + o * 64;
  for (int k = 0; k < 64; k++) acc += wr[k] * b2f(src[(size_t)k * HWp]);
  size_t oi = ((size_t)b * Cc + o) * HWp + p;
  y[oi] = inp[oi] + acc * beta[o];
}

// ---------------- LayerNorm, fp32 in (y in d_out) -> bf16 ws out ----------------
__global__ void k_ln2(const float* __restrict__ in, const float* __restrict__ w,
                      const float* __restrict__ bb, bf16* __restrict__ out) {
  int idx = blockIdx.x * 256 + threadIdx.x;
  int b = idx / HWp, p = idx - b * HWp;
  const float* src = in + (size_t)b * Cc * HWp + p;
  float s = 0.f, s2 = 0.f;
  for (int c = 0; c < Cc; c++) { float v = src[(size_t)c * HWp]; s += v; s2 += v * v; }
  float mu = s * (1.f / 64.f);
  float var = s2 * (1.f / 64.f) - mu * mu;
  float rs = rsqrtf(fmaxf(var, 0.f) + 1e-6f);
  bf16* dst = out + (size_t)b * Cc * HWp + p;
  for (int c = 0; c < Cc; c++) {
    float v = src[(size_t)c * HWp];
    dst[(size_t)c * HWp] = f2b((v - mu) * rs * w[c] + bb[c]);
  }
}

// ---------------- DFT pass via MFMA: out[c][a] = scale * sum_b in[a][b] e^{i*sgn*2pi*b*c/160}
// One wave per (a-tile, c-half, plane). D[m=c][n=a] = A[c][b] (twiddle frags) x B[b][a]=in[a][b].
// B-frag loads are contiguous 16B; A-frags from precomputed L2-resident tables.
__global__ __launch_bounds__(64) void k_cpass_mfma(
    const bf16* __restrict__ inr, const bf16* __restrict__ ini,
    const short* __restrict__ cosF, const short* __restrict__ sinF,
    bf16* __restrict__ outr, bf16* __restrict__ outi,
    float sgn, float scale,
    const float* __restrict__ sclr, const float* __restrict__ scli) {
  int plane = blockIdx.z;
  int a0 = blockIdx.x * 16;
  int cth = blockIdx.y * 5;          // c-half: ct 0..4 or 5..9
  int lane = threadIdx.x;
  int n = lane & 15, q = lane >> 4;
  const unsigned short* pr = (const unsigned short*)inr + (size_t)plane * HWp;
  const unsigned short* pi = ini ? (const unsigned short*)ini + (size_t)plane * HWp : nullptr;
  float srm = sclr ? sclr[plane] : 1.f;
  float sim = scli ? scli[plane] : 1.f;
  short8 br[5], bi[5];
  #pragma unroll
  for (int kc = 0; kc < 5; kc++) {
    br[kc] = *(const short8*)(pr + (a0 + n) * 160 + kc * 32 + q * 8);
    if (pi) bi[kc] = *(const short8*)(pi + (a0 + n) * 160 + kc * 32 + q * 8);
  }
  const short8* cf = (const short8*)cosF;
  const short8* sf = (const short8*)sinF;
  unsigned short* qr = (unsigned short*)outr + (size_t)plane * HWp;
  unsigned short* qi = (unsigned short*)outi + (size_t)plane * HWp;
  for (int ctl = 0; ctl < 5; ctl++) {
    int ct = cth + ctl;
    f32x4 arr = (f32x4){0.f,0.f,0.f,0.f}, asr = (f32x4){0.f,0.f,0.f,0.f};
    f32x4 ari = (f32x4){0.f,0.f,0.f,0.f}, asi = (f32x4){0.f,0.f,0.f,0.f};
    #pragma unroll
    for (int kc = 0; kc < 5; kc++) {
      short8 ca = cf[(ct * 5 + kc) * 64 + lane];
      short8 sa = sf[(ct * 5 + kc) * 64 + lane];
      arr = __builtin_amdgcn_mfma_f32_16x16x32_bf16(ca, br[kc], arr, 0, 0, 0);
      asr = __builtin_amdgcn_mfma_f32_16x16x32_bf16(sa, br[kc], asr, 0, 0, 0);
      if (pi) {
        ari = __builtin_amdgcn_mfma_f32_16x16x32_bf16(ca, bi[kc], ari, 0, 0, 0);
        asi = __builtin_amdgcn_mfma_f32_16x16x32_bf16(sa, bi[kc], asi, 0, 0, 0);
      }
    }
    #pragma unroll
    for (int j = 0; j < 4; j++) {
      int c = ct * 16 + q * 4 + j;
      float xc = srm * arr[j], xs = srm * asr[j];
      float ic = pi ? sim * ari[j] : 0.f, is = pi ? sim * asi[j] : 0.f;
      float orv = (xc - sgn * is) * scale;
      float oiv = (sgn * xs + ic) * scale;
      qr[c * 160 + a0 + n] = f2bu(orv);
      qi[c * 160 + a0 + n] = f2bu(oiv);
    }
  }
}

// ---------------- final inverse DFT pass via MFMA, fused |.|, *gamma, += y (fp32 d_out) ----------------
__global__ __launch_bounds__(64) void k_cpass_final_mfma(
    const bf16* __restrict__ inr, const bf16* __restrict__ ini,
    const short* __restrict__ cosF, const short* __restrict__ sinF,
    float sgn, float scale,
    const float* __restrict__ gamma, float* __restrict__ dout) {
  int plane = blockIdx.z;
  int a0 = blockIdx.x * 16;
  int cth = blockIdx.y * 5;
  int lane = threadIdx.x;
  int n = lane & 15, q = lane >> 4;
  const unsigned short* pr = (const unsigned short*)inr + (size_t)plane * HWp;
  const unsigned short* pi = (const unsigned short*)ini + (size_t)plane * HWp;
  short8 br[5], bi[5];
  #pragma unroll
  for (int kc = 0; kc < 5; kc++) {
    br[kc] = *(const short8*)(pr + (a0 + n) * 160 + kc * 32 + q * 8);
    bi[kc] = *(const short8*)(pi + (a0 + n) * 160 + kc * 32 + q * 8);
  }
  const short8* cf = (const short8*)cosF;
  const short8* sf = (const short8*)sinF;
  float gm = gamma[plane & 63];
  float* dp = dout + (size_t)plane * HWp;
  for (int ctl = 0; ctl < 5; ctl++) {
    int ct = cth + ctl;
    f32x4 arr = (f32x4){0.f,0.f,0.f,0.f}, asr = (f32x4){0.f,0.f,0.f,0.f};
    f32x4 ari = (f32x4){0.f,0.f,0.f,0.f}, asi = (f32x4){0.f,0.f,0.f,0.f};
    #pragma unroll
    for (int kc = 0; kc < 5; kc++) {
      short8 ca = cf[(ct * 5 + kc) * 64 + lane];
      short8 sa = sf[(ct * 5 + kc) * 64 + lane];
      arr = __builtin_amdgcn_mfma_f32_16x16x32_bf16(ca, br[kc], arr, 0, 0, 0);
      asr = __builtin_amdgcn_mfma_f32_16x16x32_bf16(sa, br[kc], asr, 0, 0, 0);
      ari = __builtin_amdgcn_mfma_f32_16x16x32_bf16(ca, bi[kc], ari, 0, 0, 0);
      asi = __builtin_amdgcn_mfma_f32_16x16x32_bf16(sa, bi[kc], asi, 0, 0, 0);
    }
    #pragma unroll
    for (int j = 0; j < 4; j++) {
      int c = ct * 16 + q * 4 + j;
      float orv = (arr[j] - sgn * asi[j]) * scale;
      float oiv = (sgn * asr[j] + ari[j]) * scale;
      float z = sqrtf(orv * orv + oiv * oiv);
      dp[c * 160 + a0 + n] += z * gm;   // dout currently holds y
    }
  }
}

// ---------------- fc1 (128->256) + simple_gate, MFMA ----------------
__global__ __launch_bounds__(256) void k_fc1_mfma(
    const bf16* __restrict__ Fr, const bf16* __restrict__ Fi,
    const short* __restrict__ wA, const float* __restrict__ bias,
    bf16* __restrict__ G1, bf16* __restrict__ G2) {
  int b = blockIdx.z;
  int lane = threadIdx.x & 63, w = threadIdx.x >> 6;
  int px = blockIdx.x * 64 + w * 16 + (lane & 15);
  int q = lane >> 4;
  const unsigned short* fr = (const unsigned short*)Fr + (size_t)b * Cc * HWp;
  const unsigned short* fi = (const unsigned short*)Fi + (size_t)b * Cc * HWp;
  const short8* wf = (const short8*)wA;
  f32x4 acc[16];
  #pragma unroll
  for (int mt = 0; mt < 16; mt++) acc[mt] = (f32x4){0.f, 0.f, 0.f, 0.f};
  #pragma unroll
  for (int kc = 0; kc < 4; kc++) {
    const unsigned short* basep = (kc < 2) ? (fr + (size_t)(kc * 32) * HWp)
                                           : (fi + (size_t)((kc - 2) * 32) * HWp);
    short8 bfv;
    #pragma unroll
    for (int j = 0; j < 8; j++) bfv[j] = (short)basep[(size_t)(q * 8 + j) * HWp + px];
    #pragma unroll
    for (int mt = 0; mt < 16; mt++) {
      short8 af = wf[(mt * 4 + kc) * 64 + lane];
      acc[mt] = __builtin_amdgcn_mfma_f32_16x16x32_bf16(af, bfv, acc[mt], 0, 0, 0);
    }
  }
  unsigned short* g1 = (unsigned short*)G1 + (size_t)b * Cc * HWp;
  unsigned short* g2 = (unsigned short*)G2 + (size_t)b * Cc * HWp;
  #pragma unroll
  for (int mt = 0; mt < 8; mt++)
    #pragma unroll
    for (int j = 0; j < 4; j++) {
      int o = mt * 16 + q * 4 + j;
      float v1 = acc[mt][j] + bias[o];
      float v2 = acc[mt + 8][j] + bias[o + 128];
      unsigned short hv = f2bu(v1 * v2);
      if (o < 64) g1[(size_t)o * HWp + px] = hv;
      else        g2[(size_t)(o - 64) * HWp + px] = hv;
    }
}

// ---------------- fc2 (128->128) MFMA, split output into r / i planes ----------------
__global__ __launch_bounds__(256) void k_fc2_mfma(
    const bf16* __restrict__ G1, const bf16* __restrict__ G2,
    const short* __restrict__ wA, const float* __restrict__ bias,
    bf16* __restrict__ Or, bf16* __restrict__ Oi) {
  int b = blockIdx.z;
  int lane = threadIdx.x & 63, w = threadIdx.x >> 6;
  int px = blockIdx.x * 64 + w * 16 + (lane & 15);
  int q = lane >> 4;
  const unsigned short* g1 = (const unsigned short*)G1 + (size_t)b * Cc * HWp;
  const unsigned short* g2 = (const unsigned short*)G2 + (size_t)b * Cc * HWp;
  const short8* wf = (const short8*)wA;
  f32x4 acc[8];
  #pragma unroll
  for (int mt = 0; mt < 8; mt++) acc[mt] = (f32x4){0.f, 0.f, 0.f, 0.f};
  #pragma unroll
  for (int kc = 0; kc < 4; kc++) {
    const unsigned short* basep = (kc < 2) ? (g1 + (size_t)(kc * 32) * HWp)
                                           : (g2 + (size_t)((kc - 2) * 32) * HWp);
    short8 bfv;
    #pragma unroll
    for (int j = 0; j < 8; j++) bfv[j] = (short)basep[(size_t)(q * 8 + j) * HWp + px];
    #pragma unroll
    for (int mt = 0; mt < 8; mt++) {
      short8 af = wf[(mt * 4 + kc) * 64 + lane];
      acc[mt] = __builtin_amdgcn_mfma_f32_16x16x32_bf16(af, bfv, acc[mt], 0, 0, 0);
    }
  }
  unsigned short* orp = (unsigned short*)Or + (size_t)b * Cc * HWp;
  unsigned short* oip = (unsigned short*)Oi + (size_t)b * Cc * HWp;
  #pragma unroll
  for (int mt = 0; mt < 8; mt++)
    #pragma unroll
    for (int j = 0; j < 4; j++) {
      int o = mt * 16 + q * 4 + j;
      unsigned short hv = f2bu(acc[mt][j] + bias[o]);
      if (o < 64) orp[(size_t)o * HWp + px] = hv;
      else        oip[(size_t)(o - 64) * HWp + px] = hv;
    }
}

extern "C" void kernel_launch(void* const* d_in, const int* in_sizes, int n_in,
                              void* d_out, int out_size, void* d_ws, size_t ws_size,
                              hipStream_t stream) {
  const float* inp   = (const float*)d_in[0];
  const float* n1w   = (const float*)d_in[1];
  const float* n1b   = (const float*)d_in[2];
  const float* n2w   = (const float*)d_in[3];
  const float* n2b   = (const float*)d_in[4];
  const float* scaw  = (const float*)d_in[5];
  const float* scab  = (const float*)d_in[6];
  const float* c11aw = (const float*)d_in[7];
  const float* c11ab = (const float*)d_in[8];
  const float* c11bw = (const float*)d_in[9];
  const float* c11bb = (const float*)d_in[10];
  const float* c1w   = (const float*)d_in[11];
  const float* c1b   = (const float*)d_in[12];
  const float* c21w  = (const float*)d_in[13];
  const float* c21b  = (const float*)d_in[14];
  const float* c2aw  = (const float*)d_in[15];
  const float* c2ab  = (const float*)d_in[16];
  const float* c2cw  = (const float*)d_in[17];
  const float* c2cb  = (const float*)d_in[18];
  const float* c211w = (const float*)d_in[19];
  const float* c211b = (const float*)d_in[20];
  const float* c3w   = (const float*)d_in[21];
  const float* c3b   = (const float*)d_in[22];
  const float* kbw   = (const float*)d_in[23];
  const float* kbb   = (const float*)d_in[24];
  const float* ga1   = (const float*)d_in[25];
  const float* attg  = (const float*)d_in[26];
  const float* beta  = (const float*)d_in[27];
  const float* gamma = (const float*)d_in[28];
  const float* fc1w  = (const float*)d_in[29];
  const float* fc1b  = (const float*)d_in[30];
  const float* fc2w  = (const float*)d_in[31];
  const float* fc2b  = (const float*)d_in[32];
  const float* fscaw = (const float*)d_in[33];
  const float* fscab = (const float*)d_in[34];

  const size_t S = (size_t)Bn * Cc * HWp;   // 3,276,800 elements per slot
  bf16* A  = (bf16*)d_ws;                   // 4 bf16 slots = 26.2 MB total
  bf16* Bs = A + S;
  bf16* Cs = A + 2 * S;
  bf16* Ds = A + 3 * S;
  float* smalls = (float*)(A + 4 * S);      // fp32 smalls
  float* xm   = smalls;
  float* scaV = smalls + 128;
  float* rmv  = smalls + 256;
  float* imv  = smalls + 384;
  float* sra  = smalls + 512;
  float* sia  = smalls + 640;
  float* kbwT = smalls + 1024;              // 73728 floats = 295 KB
  short* wAf1 = (short*)(kbwT + 73728);     // 32768 shorts = 64 KB
  short* wAf2 = wAf1 + 32768;               // 16384 shorts = 32 KB
  short* cosF = wAf2 + 16384;               // 25600 shorts = 51.2 KB
  short* sinF = cosF + 25600;               // 25600 shorts (ws ~26.7 MB)
  bf16* gbuf = Bs;            // [B,32,HW] (first half of Bs)
  bf16* attb = Bs + S / 2;    // [B,32,HW] (second half of Bs)
  float* yb  = (float*)d_out; // y lives in d_out (fp32)

  dim3 blk(64, 4, 1);
  dim3 cgrid(10, 2, Bn * Cc);

  k_kbwT<<<dim3(288), dim3(256), 0, stream>>>(kbw, kbwT);               // kbwT (independent)
  k_wprep<<<dim3(192), dim3(256), 0, stream>>>(fc1w, fc2w, wAf1, wAf2); // fc frags (independent)
  k_dftfrag<<<dim3(100), dim3(256), 0, stream>>>(cosF, sinF);           // DFT frags (independent)
  k_ln<<<dim3(200), dim3(256), 0, stream>>>(inp, n1w, n1b, A);          // A = x
  k_meanhw<<<dim3(128), dim3(256), 0, stream>>>(A, xm);
  k_small_mv<<<dim3(1), dim3(128), 0, stream>>>(xm, scaw, scab, scaV, 0);
  k_conv1x1<<<dim3(400, 16, Bn), blk, 0, stream>>>(A, c11aw, c11ab, Bs, 64, 64);   // B = t1
  k_c11b<<<dim3(400, 16, Bn), blk, 0, stream>>>(Bs, c11bw, c11bb, Cs);             // C = x1 (B dead)
  k_c2a<<<dim3(400, 8, Bn), blk, 0, stream>>>(A, c2aw, c2ab, gbuf);                // B.lo = g
  k_att<<<dim3(400, 8, Bn), blk, 0, stream>>>(gbuf, A, c2cw, c2cb, c211w, c211b, attg, attb); // B.hi = att
  k_conv1x1<<<dim3(400, 16, Bn), blk, 0, stream>>>(A, c1w, c1b, Ds, 64, 64);       // D = t2 (A dead after)
  k_c21dw<<<dim3(400, 16, Bn), blk, 0, stream>>>(Ds, c21w, c21b, A);               // A = uf
  k_kba<<<dim3(3, 160, Bn), dim3(256), 0, stream>>>(A, attb, Cs, scaV, kbwT, kbb, ga1, Ds); // D = xprod
  k_c3y<<<dim3(400, 16, Bn), blk, 0, stream>>>(Ds, c3w, c3b, beta, inp, yb);       // d_out = y (fp32)
  k_ln2<<<dim3(200), dim3(256), 0, stream>>>(yb, n2w, n2b, A);                     // A = X
  // forward FFT2 (MFMA): pass over W ([h][w] -> [u][h]), then over H ([u][h] -> [v][u])
  k_cpass_mfma<<<cgrid, dim3(64), 0, stream>>>(A, (const bf16*)nullptr, cosF, sinF, Bs, Cs, -1.f, SCL, nullptr, nullptr); // B,C = F1
  k_cpass_mfma<<<cgrid, dim3(64), 0, stream>>>(Bs, Cs, cosF, sinF, Ds, A, -1.f, SCL, nullptr, nullptr);                   // D,A = F2
  k_fc1_mfma<<<dim3(400, 1, Bn), dim3(256), 0, stream>>>(Ds, A, wAf1, fc1b, Bs, Cs);  // B,C = gated
  k_fc2_mfma<<<dim3(400, 1, Bn), dim3(256), 0, stream>>>(Bs, Cs, wAf2, fc2b, Ds, A);  // D = r, A = i
  k_meanhw<<<dim3(128), dim3(256), 0, stream>>>(Ds, rmv);
  k_meanhw<<<dim3(128), dim3(256), 0, stream>>>(A, imv);
  k_small_mv<<<dim3(1), dim3(128), 0, stream>>>(rmv, fscaw, fscab, sra, 1);
  k_small_mv<<<dim3(1), dim3(128), 0, stream>>>(imv, fscaw, fscab, sia, 1);
  // inverse FFT2 (MFMA) with per-plane (1+ra)/(1+ia) scaling fused into first pass
  k_cpass_mfma<<<cgrid, dim3(64), 0, stream>>>(Ds, A, cosF, sinF, Bs, Cs, 1.f, SCL, sra, sia);  // B,C
  k_cpass_final_mfma<<<cgrid, dim3(64), 0, stream>>>(Bs, Cs, cosF, sinF, 1.f, SCL, gamma, yb);  // d_out = y + |z|*gamma
}

// Round 10
// 737.158 us; speedup vs baseline: 2.6646x; 1.2433x over previous
//
#include <hip/hip_runtime.h>
#include <hip/hip_bf16.h>

typedef __hip_bfloat16 bf16;
typedef __attribute__((ext_vector_type(8))) short short8;
typedef __attribute__((ext_vector_type(4))) float f32x4;

#define Hh 160
#define Wd 160
#define HWp (Hh*Wd)       // 25600
#define Bn 2
#define Cc 64
#define NPIX (Bn*HWp)     // 51200
#define SCL 0.07905694150420949f   // 1/sqrt(160)
#define TWO_PI_160 0.039269908169872414f  // 2*pi/160

static __device__ __forceinline__ float b2f(bf16 x) { return __bfloat162float(x); }
static __device__ __forceinline__ bf16 f2b(float f) { return __float2bfloat16(f); }
static __device__ __forceinline__ unsigned short f2bu(float f) {
  union { bf16 h; unsigned short u; } z; z.h = __float2bfloat16(f); return z.u;
}
static __device__ __forceinline__ float ubf(unsigned short u) {
  union { unsigned int i; float f; } z; z.i = ((unsigned int)u) << 16; return z.f;
}
static __device__ __forceinline__ float bflo(unsigned int u) {
  union { unsigned int i; float f; } z; z.i = u << 16; return z.f;
}
static __device__ __forceinline__ float bfhi(unsigned int u) {
  union { unsigned int i; float f; } z; z.i = u & 0xffff0000u; return z.f;
}

// ---------------- LayerNorm over channel dim (per pixel), fp32 in -> bf16 out ----------------
__global__ void k_ln(const float* __restrict__ in, const float* __restrict__ w,
                     const float* __restrict__ bb, bf16* __restrict__ out) {
  int idx = blockIdx.x * 256 + threadIdx.x;   // grid covers exactly NPIX
  int b = idx / HWp, p = idx - b * HWp;
  const float* src = in + (size_t)b * Cc * HWp + p;
  float s = 0.f, s2 = 0.f;
  for (int c = 0; c < Cc; c++) { float v = src[(size_t)c * HWp]; s += v; s2 += v * v; }
  float mu = s * (1.f / 64.f);
  float var = s2 * (1.f / 64.f) - mu * mu;
  float rs = rsqrtf(fmaxf(var, 0.f) + 1e-6f);
  bf16* dst = out + (size_t)b * Cc * HWp + p;
  for (int c = 0; c < Cc; c++) {
    float v = src[(size_t)c * HWp];
    dst[(size_t)c * HWp] = f2b((v - mu) * rs * w[c] + bb[c]);
  }
}

// ---------------- mean over HW per (b,c) plane (bf16 in) ----------------
__global__ void k_meanhw(const bf16* __restrict__ in, float* __restrict__ out) {
  int bc = blockIdx.x;
  const bf16* src = in + (size_t)bc * HWp;
  int t = threadIdx.x;
  float s = 0.f;
  for (int i = t; i < HWp; i += 256) s += b2f(src[i]);
  __shared__ float sm[256];
  sm[t] = s; __syncthreads();
  for (int off = 128; off; off >>= 1) { if (t < off) sm[t] += sm[t + off]; __syncthreads(); }
  if (t == 0) out[bc] = sm[0] * (1.f / HWp);
}

// ---------------- small matvec: out[b,o] = (addone) + W[o,:]·xin[b,:] + bias[o] ----------------
__global__ void k_small_mv(const float* __restrict__ xin, const float* __restrict__ w,
                           const float* __restrict__ bias, float* __restrict__ out, int addone) {
  int t = threadIdx.x;              // 128 threads
  int b = t >> 6, o = t & 63;
  float acc = bias[o];
  for (int k = 0; k < 64; k++) acc += w[o * 64 + k] * xin[b * 64 + k];
  out[t] = addone ? (1.f + acc) : acc;
}

// ---------------- c11b: grouped 5x5 conv, groups=16 (4ch/group), pad 2 ----------------
__global__ void k_c11b(const bf16* __restrict__ in, const float* __restrict__ w,
                       const float* __restrict__ bias, bf16* __restrict__ out) {
  int p = blockIdx.x * 64 + threadIdx.x;
  int o = blockIdx.y * 4 + threadIdx.y;
  int b = blockIdx.z;
  int h = p / Wd, x = p - h * Wd;
  int gb = (o >> 2) << 2;
  float acc = bias[o];
  for (int ci = 0; ci < 4; ci++) {
    const bf16* src = in + ((size_t)b * Cc + gb + ci) * HWp;
    for (int ki = 0; ki < 5; ki++) {
      int hh = h + ki - 2; if ((unsigned)hh >= Hh) continue;
      for (int kj = 0; kj < 5; kj++) {
        int ww = x + kj - 2; if ((unsigned)ww >= Wd) continue;
        acc += w[((o * 4 + ci) * 5 + ki) * 5 + kj] * b2f(src[hh * Wd + ww]);
      }
    }
  }
  out[((size_t)b * Cc + o) * HWp + p] = f2b(acc);
}

// ---------------- c2a: grouped 3x3, 64->32, groups=32 (2 in-ch/group), pad 1 ----------------
__global__ void k_c2a(const bf16* __restrict__ in, const float* __restrict__ w,
                      const float* __restrict__ bias, bf16* __restrict__ out) {
  int p = blockIdx.x * 64 + threadIdx.x;
  int o = blockIdx.y * 4 + threadIdx.y;   // 0..31
  int b = blockIdx.z;
  int h = p / Wd, x = p - h * Wd;
  float acc = bias[o];
  for (int ci = 0; ci < 2; ci++) {
    const bf16* src = in + ((size_t)b * Cc + o * 2 + ci) * HWp;
    for (int ki = 0; ki < 3; ki++) {
      int hh = h + ki - 1; if ((unsigned)hh >= Hh) continue;
      for (int kj = 0; kj < 3; kj++) {
        int ww = x + kj - 1; if ((unsigned)ww >= Wd) continue;
        acc += w[((o * 2 + ci) * 3 + ki) * 3 + kj] * b2f(src[hh * Wd + ww]);
      }
    }
  }
  out[((size_t)b * 32 + o) * HWp + p] = f2b(acc);
}

// ---------------- depthwise 3x3, pad 1 ----------------
__global__ void k_c21dw(const bf16* __restrict__ in, const float* __restrict__ w,
                        const float* __restrict__ bias, bf16* __restrict__ out) {
  int p = blockIdx.x * 64 + threadIdx.x;
  int c = blockIdx.y * 4 + threadIdx.y;
  int b = blockIdx.z;
  int h = p / Wd, x = p - h * Wd;
  float acc = bias[c];
  const bf16* src = in + ((size_t)b * Cc + c) * HWp;
  for (int ki = 0; ki < 3; ki++) {
    int hh = h + ki - 1; if ((unsigned)hh >= Hh) continue;
    for (int kj = 0; kj < 3; kj++) {
      int ww = x + kj - 1; if ((unsigned)ww >= Wd) continue;
      acc += w[c * 9 + ki * 3 + kj] * b2f(src[hh * Wd + ww]);
    }
  }
  out[((size_t)b * Cc + c) * HWp + p] = f2b(acc);
}

// ---------------- kb_w pre-transpose: kbwT[s][d][g][o] <- kbw[s][g][o][d] ----------------
__global__ void k_kbwT(const float* __restrict__ kbw, float* __restrict__ kbwT) {
  int i = blockIdx.x * 256 + threadIdx.x;       // 73728 total (288 blocks)
  int o = i & 3, g = (i >> 2) & 15, rest = i >> 6;  // rest = s*36 + d
  int d = rest % 36, s = rest / 36;
  kbwT[i] = kbw[s * 2304 + g * 144 + o * 36 + d];
}

// ---------------- fc weight prep: bf16 MFMA A-fragment order ----------------
__global__ void k_wprep(const float* __restrict__ fc1w, const float* __restrict__ fc2w,
                        short* __restrict__ wAf1, short* __restrict__ wAf2) {
  int i = blockIdx.x * 256 + threadIdx.x;   // 49152 total (192 blocks)
  if (i < 32768) {
    int j = i & 7, lane = (i >> 3) & 63, fk = i >> 9;
    int kc = fk & 3, mt = fk >> 2;          // mt 0..15
    int o = mt * 16 + (lane & 15);
    int k = kc * 32 + (lane >> 4) * 8 + j;
    wAf1[i] = (short)f2bu(fc1w[o * 128 + k]);
  } else {
    int i2 = i - 32768;
    int j = i2 & 7, lane = (i2 >> 3) & 63, fk = i2 >> 9;
    int kc = fk & 3, mt = fk >> 2;          // mt 0..7
    int o = mt * 16 + (lane & 15);
    int k = kc * 32 + (lane >> 4) * 8 + j;
    wAf2[i2] = (short)f2bu(fc2w[o * 128 + k]);
  }
}

// ---------------- 1x1-conv weight prep: A-frags for c11a/c1/c3 (64x64) + att (32x96) ----------------
__global__ void k_wprep1x1(const float* __restrict__ c11aw, const float* __restrict__ c1w,
                           const float* __restrict__ c3w, const float* __restrict__ c2cw,
                           const float* __restrict__ c211w, const float* __restrict__ attg,
                           short* __restrict__ wA_c11a, short* __restrict__ wA_c1,
                           short* __restrict__ wA_c3, short* __restrict__ wA_att) {
  int i = blockIdx.x * 256 + threadIdx.x;   // 15360 total (60 blocks)
  if (i < 12288) {
    int wi = i / 4096, r = i - wi * 4096;
    int j = r & 7, lane = (r >> 3) & 63, fk = r >> 9;  // fk = mt*2+kc
    int kc = fk & 1, mt = fk >> 1;
    int o = mt * 16 + (lane & 15);
    int k = kc * 32 + (lane >> 4) * 8 + j;
    const float* w = (wi == 0) ? c11aw : (wi == 1) ? c1w : c3w;
    short* dst = (wi == 0) ? wA_c11a : (wi == 1) ? wA_c1 : wA_c3;
    dst[r] = (short)f2bu(w[o * 64 + k]);
  } else {
    int r = i - 12288;                      // 3072: fk = mt*3+kc (2mt x 3kc)
    int j = r & 7, lane = (r >> 3) & 63, fk = r >> 9;
    int kc = fk % 3, mt = fk / 3;
    int s = mt * 16 + (lane & 15);
    int k = kc * 32 + (lane >> 4) * 8 + j;
    float v;
    if (k < 16) v = c2cw[s * 16 + k] * attg[s];
    else if (k < 32) v = 0.f;
    else v = c211w[s * 64 + (k - 32)];
    wA_att[r] = (short)f2bu(v);
  }
}

// ---------------- generic 1x1 conv 64->64 via MFMA ----------------
__global__ __launch_bounds__(256) void k_conv1x1_mfma(
    const bf16* __restrict__ in, const short* __restrict__ wA,
    const float* __restrict__ bias, bf16* __restrict__ out) {
  int b = blockIdx.z;
  int lane = threadIdx.x & 63, w = threadIdx.x >> 6;
  int px = blockIdx.x * 64 + w * 16 + (lane & 15);
  int q = lane >> 4;
  const unsigned short* src = (const unsigned short*)in + (size_t)b * Cc * HWp;
  const short8* wf = (const short8*)wA;
  f32x4 acc[4];
  #pragma unroll
  for (int mt = 0; mt < 4; mt++) acc[mt] = (f32x4){0.f, 0.f, 0.f, 0.f};
  #pragma unroll
  for (int kc = 0; kc < 2; kc++) {
    short8 bfv;
    #pragma unroll
    for (int j = 0; j < 8; j++) bfv[j] = (short)src[(size_t)(kc * 32 + q * 8 + j) * HWp + px];
    #pragma unroll
    for (int mt = 0; mt < 4; mt++) {
      short8 af = wf[(mt * 2 + kc) * 64 + lane];
      acc[mt] = __builtin_amdgcn_mfma_f32_16x16x32_bf16(af, bfv, acc[mt], 0, 0, 0);
    }
  }
  unsigned short* dst = (unsigned short*)out + (size_t)b * Cc * HWp;
  #pragma unroll
  for (int mt = 0; mt < 4; mt++)
    #pragma unroll
    for (int j = 0; j < 4; j++) {
      int o = mt * 16 + q * 4 + j;
      dst[(size_t)o * HWp + px] = f2bu(acc[mt][j] + bias[o]);
    }
}

// ---------------- c3 1x1 conv + residual via MFMA: y = inp + (conv)*beta (fp32 out) ----------------
__global__ __launch_bounds__(256) void k_c3y_mfma(
    const bf16* __restrict__ in, const short* __restrict__ wA,
    const float* __restrict__ bias, const float* __restrict__ beta,
    const float* __restrict__ inp, float* __restrict__ y) {
  int b = blockIdx.z;
  int lane = threadIdx.x & 63, w = threadIdx.x >> 6;
  int px = blockIdx.x * 64 + w * 16 + (lane & 15);
  int q = lane >> 4;
  const unsigned short* src = (const unsigned short*)in + (size_t)b * Cc * HWp;
  const short8* wf = (const short8*)wA;
  f32x4 acc[4];
  #pragma unroll
  for (int mt = 0; mt < 4; mt++) acc[mt] = (f32x4){0.f, 0.f, 0.f, 0.f};
  #pragma unroll
  for (int kc = 0; kc < 2; kc++) {
    short8 bfv;
    #pragma unroll
    for (int j = 0; j < 8; j++) bfv[j] = (short)src[(size_t)(kc * 32 + q * 8 + j) * HWp + px];
    #pragma unroll
    for (int mt = 0; mt < 4; mt++) {
      short8 af = wf[(mt * 2 + kc) * 64 + lane];
      acc[mt] = __builtin_amdgcn_mfma_f32_16x16x32_bf16(af, bfv, acc[mt], 0, 0, 0);
    }
  }
  #pragma unroll
  for (int mt = 0; mt < 4; mt++)
    #pragma unroll
    for (int j = 0; j < 4; j++) {
      int o = mt * 16 + q * 4 + j;
      size_t oi = ((size_t)b * Cc + o) * HWp + px;
      y[oi] = inp[oi] + (acc[mt][j] + bias[o]) * beta[o];
    }
}

// ---------------- att via MFMA: M=32, K = [gate16 | pad16 | x64] ----------------
__global__ __launch_bounds__(256) void k_att_mfma(
    const bf16* __restrict__ g, const bf16* __restrict__ x,
    const short* __restrict__ wA, const float* __restrict__ c2cb,
    const float* __restrict__ c211b, const float* __restrict__ attg,
    bf16* __restrict__ att) {
  int b = blockIdx.z;
  int lane = threadIdx.x & 63, w = threadIdx.x >> 6;
  int px = blockIdx.x * 64 + w * 16 + (lane & 15);
  int q = lane >> 4;
  const unsigned short* gs = (const unsigned short*)g + (size_t)b * 32 * HWp;
  const unsigned short* xs = (const unsigned short*)x + (size_t)b * Cc * HWp;
  const short8* wf = (const short8*)wA;
  f32x4 acc[2];
  acc[0] = (f32x4){0.f, 0.f, 0.f, 0.f};
  acc[1] = (f32x4){0.f, 0.f, 0.f, 0.f};
  // kc 0: gate product gv[k] = g[k]*g[16+k], k<16 (q>=2 lanes contribute zero-A anyway)
  {
    short8 bfv;
    #pragma unroll
    for (int j = 0; j < 8; j++) {
      int k = q * 8 + j;
      short v = 0;
      if (q < 2) {
        float gv = ubf(gs[(size_t)k * HWp + px]) * ubf(gs[(size_t)(16 + k) * HWp + px]);
        v = (short)f2bu(gv);
      }
      bfv[j] = v;
    }
    #pragma unroll
    for (int mt = 0; mt < 2; mt++) {
      short8 af = wf[(mt * 3 + 0) * 64 + lane];
      acc[mt] = __builtin_amdgcn_mfma_f32_16x16x32_bf16(af, bfv, acc[mt], 0, 0, 0);
    }
  }
  #pragma unroll
  for (int kc = 1; kc < 3; kc++) {
    short8 bfv;
    #pragma unroll
    for (int j = 0; j < 8; j++)
      bfv[j] = (short)xs[(size_t)((kc - 1) * 32 + q * 8 + j) * HWp + px];
    #pragma unroll
    for (int mt = 0; mt < 2; mt++) {
      short8 af = wf[(mt * 3 + kc) * 64 + lane];
      acc[mt] = __builtin_amdgcn_mfma_f32_16x16x32_bf16(af, bfv, acc[mt], 0, 0, 0);
    }
  }
  unsigned short* dst = (unsigned short*)att + (size_t)b * 32 * HWp;
  #pragma unroll
  for (int mt = 0; mt < 2; mt++)
    #pragma unroll
    for (int j = 0; j < 4; j++) {
      int s = mt * 16 + q * 4 + j;
      dst[(size_t)s * HWp + px] = f2bu(acc[mt][j] + c2cb[s] * attg[s] + c211b[s]);
    }
}

// ---------------- DFT twiddle tables in MFMA A-fragment order ----------------
__global__ void k_dftfrag(short* __restrict__ cosF, short* __restrict__ sinF) {
  int i = blockIdx.x * 256 + threadIdx.x;   // 25600 total (100 blocks)
  int j = i & 7, lane = (i >> 3) & 63, fk = i >> 9;   // fk = ct*5+kc, 0..49
  int kc = fk % 5, ct = fk / 5;
  int c = ct * 16 + (lane & 15);
  int b = kc * 32 + (lane >> 4) * 8 + j;
  int m = (b * c) % 160;
  float sv, cv;
  __sincosf((float)m * TWO_PI_160, &sv, &cv);
  cosF[i] = (short)f2bu(cv);
  sinF[i] = (short)f2bu(sv);
}

// ---------------- KBA fused: out = ((kba+bias)*ga1 + uf) * x1 * sca ----------------
__global__ __launch_bounds__(256, 4) void k_kba(
    const bf16* __restrict__ uf, const bf16* __restrict__ att,
    const bf16* __restrict__ x1, const float* __restrict__ scaV,
    const float* __restrict__ kbwT, const float* __restrict__ kbb,
    const float* __restrict__ ga1, bf16* __restrict__ out) {
  __shared__ __align__(16) unsigned char shmem[64 * 3 * 66 * 2];  // 25344 B
  unsigned short* patchL = (unsigned short*)shmem;   // [c][ki][col] bf16, live until hoist
  float* kwL = (float*)shmem;                        // [si][d][g][o] fp32 (4608 floats)
  __shared__ float attL[64][33];                     // 8448 B
  int b = blockIdx.z, h = blockIdx.y;
  int w0 = blockIdx.x * 64;
  int width = min(64, Wd - w0);
  int t = threadIdx.x;
  const unsigned short* uf_u = (const unsigned short*)uf;
  for (int i = t; i < 64 * 3 * 66; i += 256) {
    int c = i / 198, rem = i - c * 198;
    int r = rem / 66, col = rem - r * 66;
    int hh = h + r - 1, ww = w0 + col - 1;
    unsigned short v = 0;
    if ((unsigned)hh < Hh && (unsigned)ww < Wd)
      v = uf_u[((size_t)b * Cc + c) * HWp + hh * Wd + ww];
    patchL[i] = v;
  }
  for (int i = t; i < 64 * 32; i += 256) {
    int px = i & 63, s = i >> 6;
    float v = 0.f;
    if (px < width) v = b2f(att[((size_t)b * 32 + s) * HWp + h * Wd + w0 + px]);
    attL[px][s] = v;
  }
  __syncthreads();
  int g = t & 15, pq = t >> 4;
  unsigned int pf2[4][3][3];
  #pragma unroll
  for (int ci = 0; ci < 4; ci++)
    #pragma unroll
    for (int ki = 0; ki < 3; ki++) {
      const unsigned int* pr32 =
          (const unsigned int*)&patchL[(g * 4 + ci) * 198 + ki * 66 + 4 * pq];
      #pragma unroll
      for (int m2 = 0; m2 < 3; m2++) pf2[ci][ki][m2] = pr32[m2];
    }
  float acc[4][4];
  #pragma unroll
  for (int j = 0; j < 4; j++)
    #pragma unroll
    for (int o = 0; o < 4; o++) acc[j][o] = 0.f;
  for (int s = 0; s < 32; s++) {
    float kv[4];
    #pragma unroll
    for (int o = 0; o < 4; o++) kv[o] = kbb[s * 64 + g * 4 + o];
    #pragma unroll
    for (int j = 0; j < 4; j++) {
      float av = attL[4 * pq + j][s];
      #pragma unroll
      for (int o = 0; o < 4; o++) acc[j][o] += av * kv[o];
    }
  }
  for (int sc = 0; sc < 16; sc++) {
    __syncthreads();
    for (int i = t; i < 2 * 2304; i += 256)
      kwL[i] = kbwT[sc * 4608 + i];
    __syncthreads();
    #pragma unroll
    for (int si = 0; si < 2; si++) {
      int s = sc * 2 + si;
      float a0 = attL[4 * pq + 0][s], a1 = attL[4 * pq + 1][s];
      float a2 = attL[4 * pq + 2][s], a3 = attL[4 * pq + 3][s];
      const float* wbase = &kwL[si * 2304 + g * 4];
      #pragma unroll
      for (int ci = 0; ci < 4; ci++)
        #pragma unroll
        for (int ki = 0; ki < 3; ki++) {
          float w0f = bflo(pf2[ci][ki][0]), w1f = bfhi(pf2[ci][ki][0]);
          float w2f = bflo(pf2[ci][ki][1]), w3f = bfhi(pf2[ci][ki][1]);
          float w4f = bflo(pf2[ci][ki][2]), w5f = bfhi(pf2[ci][ki][2]);
          float win[6] = {w0f, w1f, w2f, w3f, w4f, w5f};
          #pragma unroll
          for (int kj = 0; kj < 3; kj++) {
            int d = ci * 9 + ki * 3 + kj;
            float4 wv = *(const float4*)&wbase[d * 64];
            float p0 = win[kj + 0] * a0;
            float p1 = win[kj + 1] * a1;
            float p2 = win[kj + 2] * a2;
            float p3 = win[kj + 3] * a3;
            acc[0][0] += p0 * wv.x; acc[0][1] += p0 * wv.y; acc[0][2] += p0 * wv.z; acc[0][3] += p0 * wv.w;
            acc[1][0] += p1 * wv.x; acc[1][1] += p1 * wv.y; acc[1][2] += p1 * wv.z; acc[1][3] += p1 * wv.w;
            acc[2][0] += p2 * wv.x; acc[2][1] += p2 * wv.y; acc[2][2] += p2 * wv.z; acc[2][3] += p2 * wv.w;
            acc[3][0] += p3 * wv.x; acc[3][1] += p3 * wv.y; acc[3][2] += p3 * wv.z; acc[3][3] += p3 * wv.w;
          }
        }
    }
  }
  #pragma unroll
  for (int j = 0; j < 4; j++) {
    int px = 4 * pq + j;
    if (px >= width) continue;
    int p = h * Wd + w0 + px;
    #pragma unroll
    for (int o = 0; o < 4; o++) {
      int c = g * 4 + o;
      unsigned int cu = pf2[o][1][(j + 1) >> 1];
      float ufc = ((j + 1) & 1) ? bfhi(cu) : bflo(cu);
      float xk = acc[j][o] * ga1[c] + ufc;
      float xv = xk * b2f(x1[((size_t)b * Cc + c) * HWp + p]) * scaV[b * 64 + c];
      out[((size_t)b * Cc + c) * HWp + p] = f2b(xv);
    }
  }
}

// ---------------- LayerNorm, fp32 in (y in d_out) -> bf16 ws out ----------------
__global__ void k_ln2(const float* __restrict__ in, const float* __restrict__ w,
                      const float* __restrict__ bb, bf16* __restrict__ out) {
  int idx = blockIdx.x * 256 + threadIdx.x;
  int b = idx / HWp, p = idx - b * HWp;
  const float* src = in + (size_t)b * Cc * HWp + p;
  float s = 0.f, s2 = 0.f;
  for (int c = 0; c < Cc; c++) { float v = src[(size_t)c * HWp]; s += v; s2 += v * v; }
  float mu = s * (1.f / 64.f);
  float var = s2 * (1.f / 64.f) - mu * mu;
  float rs = rsqrtf(fmaxf(var, 0.f) + 1e-6f);
  bf16* dst = out + (size_t)b * Cc * HWp + p;
  for (int c = 0; c < Cc; c++) {
    float v = src[(size_t)c * HWp];
    dst[(size_t)c * HWp] = f2b((v - mu) * rs * w[c] + bb[c]);
  }
}

// ---------------- DFT pass via MFMA ----------------
__global__ __launch_bounds__(64) void k_cpass_mfma(
    const bf16* __restrict__ inr, const bf16* __restrict__ ini,
    const short* __restrict__ cosF, const short* __restrict__ sinF,
    bf16* __restrict__ outr, bf16* __restrict__ outi,
    float sgn, float scale,
    const float* __restrict__ sclr, const float* __restrict__ scli) {
  int plane = blockIdx.z;
  int a0 = blockIdx.x * 16;
  int cth = blockIdx.y * 5;          // c-half: ct 0..4 or 5..9
  int lane = threadIdx.x;
  int n = lane & 15, q = lane >> 4;
  const unsigned short* pr = (const unsigned short*)inr + (size_t)plane * HWp;
  const unsigned short* pi = ini ? (const unsigned short*)ini + (size_t)plane * HWp : nullptr;
  float srm = sclr ? sclr[plane] : 1.f;
  float sim = scli ? scli[plane] : 1.f;
  short8 br[5], bi[5];
  #pragma unroll
  for (int kc = 0; kc < 5; kc++) {
    br[kc] = *(const short8*)(pr + (a0 + n) * 160 + kc * 32 + q * 8);
    if (pi) bi[kc] = *(const short8*)(pi + (a0 + n) * 160 + kc * 32 + q * 8);
  }
  const short8* cf = (const short8*)cosF;
  const short8* sf = (const short8*)sinF;
  unsigned short* qr = (unsigned short*)outr + (size_t)plane * HWp;
  unsigned short* qi = (unsigned short*)outi + (size_t)plane * HWp;
  for (int ctl = 0; ctl < 5; ctl++) {
    int ct = cth + ctl;
    f32x4 arr = (f32x4){0.f,0.f,0.f,0.f}, asr = (f32x4){0.f,0.f,0.f,0.f};
    f32x4 ari = (f32x4){0.f,0.f,0.f,0.f}, asi = (f32x4){0.f,0.f,0.f,0.f};
    #pragma unroll
    for (int kc = 0; kc < 5; kc++) {
      short8 ca = cf[(ct * 5 + kc) * 64 + lane];
      short8 sa = sf[(ct * 5 + kc) * 64 + lane];
      arr = __builtin_amdgcn_mfma_f32_16x16x32_bf16(ca, br[kc], arr, 0, 0, 0);
      asr = __builtin_amdgcn_mfma_f32_16x16x32_bf16(sa, br[kc], asr, 0, 0, 0);
      if (pi) {
        ari = __builtin_amdgcn_mfma_f32_16x16x32_bf16(ca, bi[kc], ari, 0, 0, 0);
        asi = __builtin_amdgcn_mfma_f32_16x16x32_bf16(sa, bi[kc], asi, 0, 0, 0);
      }
    }
    #pragma unroll
    for (int j = 0; j < 4; j++) {
      int c = ct * 16 + q * 4 + j;
      float xc = srm * arr[j], xs = srm * asr[j];
      float ic = pi ? sim * ari[j] : 0.f, is = pi ? sim * asi[j] : 0.f;
      float orv = (xc - sgn * is) * scale;
      float oiv = (sgn * xs + ic) * scale;
      qr[c * 160 + a0 + n] = f2bu(orv);
      qi[c * 160 + a0 + n] = f2bu(oiv);
    }
  }
}

// ---------------- final inverse DFT pass via MFMA, fused |.|, *gamma, += y (fp32 d_out) ----------------
__global__ __launch_bounds__(64) void k_cpass_final_mfma(
    const bf16* __restrict__ inr, const bf16* __restrict__ ini,
    const short* __restrict__ cosF, const short* __restrict__ sinF,
    float sgn, float scale,
    const float* __restrict__ gamma, float* __restrict__ dout) {
  int plane = blockIdx.z;
  int a0 = blockIdx.x * 16;
  int cth = blockIdx.y * 5;
  int lane = threadIdx.x;
  int n = lane & 15, q = lane >> 4;
  const unsigned short* pr = (const unsigned short*)inr + (size_t)plane * HWp;
  const unsigned short* pi = (const unsigned short*)ini + (size_t)plane * HWp;
  short8 br[5], bi[5];
  #pragma unroll
  for (int kc = 0; kc < 5; kc++) {
    br[kc] = *(const short8*)(pr + (a0 + n) * 160 + kc * 32 + q * 8);
    bi[kc] = *(const short8*)(pi + (a0 + n) * 160 + kc * 32 + q * 8);
  }
  const short8* cf = (const short8*)cosF;
  const short8* sf = (const short8*)sinF;
  float gm = gamma[plane & 63];
  float* dp = dout + (size_t)plane * HWp;
  for (int ctl = 0; ctl < 5; ctl++) {
    int ct = cth + ctl;
    f32x4 arr = (f32x4){0.f,0.f,0.f,0.f}, asr = (f32x4){0.f,0.f,0.f,0.f};
    f32x4 ari = (f32x4){0.f,0.f,0.f,0.f}, asi = (f32x4){0.f,0.f,0.f,0.f};
    #pragma unroll
    for (int kc = 0; kc < 5; kc++) {
      short8 ca = cf[(ct * 5 + kc) * 64 + lane];
      short8 sa = sf[(ct * 5 + kc) * 64 + lane];
      arr = __builtin_amdgcn_mfma_f32_16x16x32_bf16(ca, br[kc], arr, 0, 0, 0);
      asr = __builtin_amdgcn_mfma_f32_16x16x32_bf16(sa, br[kc], asr, 0, 0, 0);
      ari = __builtin_amdgcn_mfma_f32_16x16x32_bf16(ca, bi[kc], ari, 0, 0, 0);
      asi = __builtin_amdgcn_mfma_f32_16x16x32_bf16(sa, bi[kc], asi, 0, 0, 0);
    }
    #pragma unroll
    for (int j = 0; j < 4; j++) {
      int c = ct * 16 + q * 4 + j;
      float orv = (arr[j] - sgn * asi[j]) * scale;
      float oiv = (sgn * asr[j] + ari[j]) * scale;
      float z = sqrtf(orv * orv + oiv * oiv);
      dp[c * 160 + a0 + n] += z * gm;   // dout currently holds y
    }
  }
}

// ---------------- fc1 (128->256) + simple_gate, MFMA ----------------
__global__ __launch_bounds__(256) void k_fc1_mfma(
    const bf16* __restrict__ Fr, const bf16* __restrict__ Fi,
    const short* __restrict__ wA, const float* __restrict__ bias,
    bf16* __restrict__ G1, bf16* __restrict__ G2) {
  int b = blockIdx.z;
  int lane = threadIdx.x & 63, w = threadIdx.x >> 6;
  int px = blockIdx.x * 64 + w * 16 + (lane & 15);
  int q = lane >> 4;
  const unsigned short* fr = (const unsigned short*)Fr + (size_t)b * Cc * HWp;
  const unsigned short* fi = (const unsigned short*)Fi + (size_t)b * Cc * HWp;
  const short8* wf = (const short8*)wA;
  f32x4 acc[16];
  #pragma unroll
  for (int mt = 0; mt < 16; mt++) acc[mt] = (f32x4){0.f, 0.f, 0.f, 0.f};
  #pragma unroll
  for (int kc = 0; kc < 4; kc++) {
    const unsigned short* basep = (kc < 2) ? (fr + (size_t)(kc * 32) * HWp)
                                           : (fi + (size_t)((kc - 2) * 32) * HWp);
    short8 bfv;
    #pragma unroll
    for (int j = 0; j < 8; j++) bfv[j] = (short)basep[(size_t)(q * 8 + j) * HWp + px];
    #pragma unroll
    for (int mt = 0; mt < 16; mt++) {
      short8 af = wf[(mt * 4 + kc) * 64 + lane];
      acc[mt] = __builtin_amdgcn_mfma_f32_16x16x32_bf16(af, bfv, acc[mt], 0, 0, 0);
    }
  }
  unsigned short* g1 = (unsigned short*)G1 + (size_t)b * Cc * HWp;
  unsigned short* g2 = (unsigned short*)G2 + (size_t)b * Cc * HWp;
  #pragma unroll
  for (int mt = 0; mt < 8; mt++)
    #pragma unroll
    for (int j = 0; j < 4; j++) {
      int o = mt * 16 + q * 4 + j;
      float v1 = acc[mt][j] + bias[o];
      float v2 = acc[mt + 8][j] + bias[o + 128];
      unsigned short hv = f2bu(v1 * v2);
      if (o < 64) g1[(size_t)o * HWp + px] = hv;
      else        g2[(size_t)(o - 64) * HWp + px] = hv;
    }
}

// ---------------- fc2 (128->128) MFMA, split output into r / i planes ----------------
__global__ __launch_bounds__(256) void k_fc2_mfma(
    const bf16* __restrict__ G1, const bf16* __restrict__ G2,
    const short* __restrict__ wA, const float* __restrict__ bias,
    bf16* __restrict__ Or, bf16* __restrict__ Oi) {
  int b = blockIdx.z;
  int lane = threadIdx.x & 63, w = threadIdx.x >> 6;
  int px = blockIdx.x * 64 + w * 16 + (lane & 15);
  int q = lane >> 4;
  const unsigned short* g1 = (const unsigned short*)G1 + (size_t)b * Cc * HWp;
  const unsigned short* g2 = (const unsigned short*)G2 + (size_t)b * Cc * HWp;
  const short8* wf = (const short8*)wA;
  f32x4 acc[8];
  #pragma unroll
  for (int mt = 0; mt < 8; mt++) acc[mt] = (f32x4){0.f, 0.f, 0.f, 0.f};
  #pragma unroll
  for (int kc = 0; kc < 4; kc++) {
    const unsigned short* basep = (kc < 2) ? (g1 + (size_t)(kc * 32) * HWp)
                                           : (g2 + (size_t)((kc - 2) * 32) * HWp);
    short8 bfv;
    #pragma unroll
    for (int j = 0; j < 8; j++) bfv[j] = (short)basep[(size_t)(q * 8 + j) * HWp + px];
    #pragma unroll
    for (int mt = 0; mt < 8; mt++) {
      short8 af = wf[(mt * 4 + kc) * 64 + lane];
      acc[mt] = __builtin_amdgcn_mfma_f32_16x16x32_bf16(af, bfv, acc[mt], 0, 0, 0);
    }
  }
  unsigned short* orp = (unsigned short*)Or + (size_t)b * Cc * HWp;
  unsigned short* oip = (unsigned short*)Oi + (size_t)b * Cc * HWp;
  #pragma unroll
  for (int mt = 0; mt < 8; mt++)
    #pragma unroll
    for (int j = 0; j < 4; j++) {
      int o = mt * 16 + q * 4 + j;
      unsigned short hv = f2bu(acc[mt][j] + bias[o]);
      if (o < 64) orp[(size_t)o * HWp + px] = hv;
      else        oip[(size_t)(o - 64) * HWp + px] = hv;
    }
}

extern "C" void kernel_launch(void* const* d_in, const int* in_sizes, int n_in,
                              void* d_out, int out_size, void* d_ws, size_t ws_size,
                              hipStream_t stream) {
  const float* inp   = (const float*)d_in[0];
  const float* n1w   = (const float*)d_in[1];
  const float* n1b   = (const float*)d_in[2];
  const float* n2w   = (const float*)d_in[3];
  const float* n2b   = (const float*)d_in[4];
  const float* scaw  = (const float*)d_in[5];
  const float* scab  = (const float*)d_in[6];
  const float* c11aw = (const float*)d_in[7];
  const float* c11ab = (const float*)d_in[8];
  const float* c11bw = (const float*)d_in[9];
  const float* c11bb = (const float*)d_in[10];
  const float* c1w   = (const float*)d_in[11];
  const float* c1b   = (const float*)d_in[12];
  const float* c21w  = (const float*)d_in[13];
  const float* c21b  = (const float*)d_in[14];
  const float* c2aw  = (const float*)d_in[15];
  const float* c2ab  = (const float*)d_in[16];
  const float* c2cw  = (const float*)d_in[17];
  const float* c2cb  = (const float*)d_in[18];
  const float* c211w = (const float*)d_in[19];
  const float* c211b = (const float*)d_in[20];
  const float* c3w   = (const float*)d_in[21];
  const float* c3b   = (const float*)d_in[22];
  const float* kbw   = (const float*)d_in[23];
  const float* kbb   = (const float*)d_in[24];
  const float* ga1   = (const float*)d_in[25];
  const float* attg  = (const float*)d_in[26];
  const float* beta  = (const float*)d_in[27];
  const float* gamma = (const float*)d_in[28];
  const float* fc1w  = (const float*)d_in[29];
  const float* fc1b  = (const float*)d_in[30];
  const float* fc2w  = (const float*)d_in[31];
  const float* fc2b  = (const float*)d_in[32];
  const float* fscaw = (const float*)d_in[33];
  const float* fscab = (const float*)d_in[34];

  const size_t S = (size_t)Bn * Cc * HWp;   // 3,276,800 elements per slot
  bf16* A  = (bf16*)d_ws;                   // 4 bf16 slots = 26.2 MB total
  bf16* Bs = A + S;
  bf16* Cs = A + 2 * S;
  bf16* Ds = A + 3 * S;
  float* smalls = (float*)(A + 4 * S);      // fp32 smalls
  float* xm   = smalls;
  float* scaV = smalls + 128;
  float* rmv  = smalls + 256;
  float* imv  = smalls + 384;
  float* sra  = smalls + 512;
  float* sia  = smalls + 640;
  float* kbwT = smalls + 1024;              // 73728 floats = 295 KB
  short* wAf1 = (short*)(kbwT + 73728);     // 32768 shorts
  short* wAf2 = wAf1 + 32768;               // 16384 shorts
  short* cosF = wAf2 + 16384;               // 25600 shorts
  short* sinF = cosF + 25600;               // 25600 shorts
  short* wA_c11a = sinF + 25600;            // 4096 shorts
  short* wA_c1   = wA_c11a + 4096;          // 4096 shorts
  short* wA_c3   = wA_c1 + 4096;            // 4096 shorts
  short* wA_att  = wA_c3 + 4096;            // 3072 shorts (ws ~26.8 MB)
  bf16* gbuf = Bs;            // [B,32,HW] (first half of Bs)
  bf16* attb = Bs + S / 2;    // [B,32,HW] (second half of Bs)
  float* yb  = (float*)d_out; // y lives in d_out (fp32)

  dim3 blk(64, 4, 1);
  dim3 cgrid(10, 2, Bn * Cc);
  dim3 pgrid(400, 1, Bn);

  k_kbwT<<<dim3(288), dim3(256), 0, stream>>>(kbw, kbwT);               // kbwT (independent)
  k_wprep<<<dim3(192), dim3(256), 0, stream>>>(fc1w, fc2w, wAf1, wAf2); // fc frags (independent)
  k_dftfrag<<<dim3(100), dim3(256), 0, stream>>>(cosF, sinF);           // DFT frags (independent)
  k_wprep1x1<<<dim3(60), dim3(256), 0, stream>>>(c11aw, c1w, c3w, c2cw, c211w, attg,
                                                 wA_c11a, wA_c1, wA_c3, wA_att);
  k_ln<<<dim3(200), dim3(256), 0, stream>>>(inp, n1w, n1b, A);          // A = x
  k_meanhw<<<dim3(128), dim3(256), 0, stream>>>(A, xm);
  k_small_mv<<<dim3(1), dim3(128), 0, stream>>>(xm, scaw, scab, scaV, 0);
  k_conv1x1_mfma<<<pgrid, dim3(256), 0, stream>>>(A, wA_c11a, c11ab, Bs);          // B = t1
  k_c11b<<<dim3(400, 16, Bn), blk, 0, stream>>>(Bs, c11bw, c11bb, Cs);             // C = x1 (B dead)
  k_c2a<<<dim3(400, 8, Bn), blk, 0, stream>>>(A, c2aw, c2ab, gbuf);                // B.lo = g
  k_att_mfma<<<pgrid, dim3(256), 0, stream>>>(gbuf, A, wA_att, c2cb, c211b, attg, attb); // B.hi = att
  k_conv1x1_mfma<<<pgrid, dim3(256), 0, stream>>>(A, wA_c1, c1b, Ds);              // D = t2 (A dead after)
  k_c21dw<<<dim3(400, 16, Bn), blk, 0, stream>>>(Ds, c21w, c21b, A);               // A = uf
  k_kba<<<dim3(3, 160, Bn), dim3(256), 0, stream>>>(A, attb, Cs, scaV, kbwT, kbb, ga1, Ds); // D = xprod
  k_c3y_mfma<<<pgrid, dim3(256), 0, stream>>>(Ds, wA_c3, c3b, beta, inp, yb);      // d_out = y (fp32)
  k_ln2<<<dim3(200), dim3(256), 0, stream>>>(yb, n2w, n2b, A);                     // A = X
  // forward FFT2 (MFMA): pass over W ([h][w] -> [u][h]), then over H ([u][h] -> [v][u])
  k_cpass_mfma<<<cgrid, dim3(64), 0, stream>>>(A, (const bf16*)nullptr, cosF, sinF, Bs, Cs, -1.f, SCL, nullptr, nullptr); // B,C = F1
  k_cpass_mfma<<<cgrid, dim3(64), 0, stream>>>(Bs, Cs, cosF, sinF, Ds, A, -1.f, SCL, nullptr, nullptr);                   // D,A = F2
  k_fc1_mfma<<<pgrid, dim3(256), 0, stream>>>(Ds, A, wAf1, fc1b, Bs, Cs);          // B,C = gated
  k_fc2_mfma<<<pgrid, dim3(256), 0, stream>>>(Bs, Cs, wAf2, fc2b, Ds, A);          // D = r, A = i
  k_meanhw<<<dim3(128), dim3(256), 0, stream>>>(Ds, rmv);
  k_meanhw<<<dim3(128), dim3(256), 0, stream>>>(A, imv);
  k_small_mv<<<dim3(1), dim3(128), 0, stream>>>(rmv, fscaw, fscab, sra, 1);
  k_small_mv<<<dim3(1), dim3(128), 0, stream>>>(imv, fscaw, fscab, sia, 1);
  // inverse FFT2 (MFMA) with per-plane (1+ra)/(1+ia) scaling fused into first pass
  k_cpass_mfma<<<cgrid, dim3(64), 0, stream>>>(Ds, A, cosF, sinF, Bs, Cs, 1.f, SCL, sra, sia);  // B,C
  k_cpass_final_mfma<<<cgrid, dim3(64), 0, stream>>>(Bs, Cs, cosF, sinF, 1.f, SCL, gamma, yb);  // d_out = y + |z|*gamma
}

// Round 11
// 645.965 us; speedup vs baseline: 3.0408x; 1.1412x over previous
//
#include <hip/hip_runtime.h>
#include <hip/hip_bf16.h>

typedef __hip_bfloat16 bf16;
typedef __attribute__((ext_vector_type(8))) short short8;
typedef __attribute__((ext_vector_type(4))) float f32x4;

#define Hh 160
#define Wd 160
#define HWp (Hh*Wd)       // 25600
#define Bn 2
#define Cc 64
#define NPIX (Bn*HWp)     // 51200
#define SCL 0.07905694150420949f   // 1/sqrt(160)
#define TWO_PI_160 0.039269908169872414f  // 2*pi/160

static __device__ __forceinline__ float b2f(bf16 x) { return __bfloat162float(x); }
static __device__ __forceinline__ bf16 f2b(float f) { return __float2bfloat16(f); }
static __device__ __forceinline__ unsigned short f2bu(float f) {
  union { bf16 h; unsigned short u; } z; z.h = __float2bfloat16(f); return z.u;
}
static __device__ __forceinline__ float ubf(unsigned short u) {
  union { unsigned int i; float f; } z; z.i = ((unsigned int)u) << 16; return z.f;
}

// ---------------- LayerNorm over channel dim (per pixel), fp32 in -> bf16 out ----------------
__global__ void k_ln(const float* __restrict__ in, const float* __restrict__ w,
                     const float* __restrict__ bb, bf16* __restrict__ out) {
  int idx = blockIdx.x * 256 + threadIdx.x;   // grid covers exactly NPIX
  int b = idx / HWp, p = idx - b * HWp;
  const float* src = in + (size_t)b * Cc * HWp + p;
  float s = 0.f, s2 = 0.f;
  for (int c = 0; c < Cc; c++) { float v = src[(size_t)c * HWp]; s += v; s2 += v * v; }
  float mu = s * (1.f / 64.f);
  float var = s2 * (1.f / 64.f) - mu * mu;
  float rs = rsqrtf(fmaxf(var, 0.f) + 1e-6f);
  bf16* dst = out + (size_t)b * Cc * HWp + p;
  for (int c = 0; c < Cc; c++) {
    float v = src[(size_t)c * HWp];
    dst[(size_t)c * HWp] = f2b((v - mu) * rs * w[c] + bb[c]);
  }
}

// ---------------- mean over HW per (b,c) plane (bf16 in) ----------------
__global__ void k_meanhw(const bf16* __restrict__ in, float* __restrict__ out) {
  int bc = blockIdx.x;
  const bf16* src = in + (size_t)bc * HWp;
  int t = threadIdx.x;
  float s = 0.f;
  for (int i = t; i < HWp; i += 256) s += b2f(src[i]);
  __shared__ float sm[256];
  sm[t] = s; __syncthreads();
  for (int off = 128; off; off >>= 1) { if (t < off) sm[t] += sm[t + off]; __syncthreads(); }
  if (t == 0) out[bc] = sm[0] * (1.f / HWp);
}

// ---------------- small matvec: out[b,o] = (addone) + W[o,:]·xin[b,:] + bias[o] ----------------
__global__ void k_small_mv(const float* __restrict__ xin, const float* __restrict__ w,
                           const float* __restrict__ bias, float* __restrict__ out, int addone) {
  int t = threadIdx.x;              // 128 threads
  int b = t >> 6, o = t & 63;
  float acc = bias[o];
  for (int k = 0; k < 64; k++) acc += w[o * 64 + k] * xin[b * 64 + k];
  out[t] = addone ? (1.f + acc) : acc;
}

// ---------------- c11b: grouped 5x5 conv, groups=16 (4ch/group), pad 2 ----------------
__global__ void k_c11b(const bf16* __restrict__ in, const float* __restrict__ w,
                       const float* __restrict__ bias, bf16* __restrict__ out) {
  int p = blockIdx.x * 64 + threadIdx.x;
  int o = blockIdx.y * 4 + threadIdx.y;
  int b = blockIdx.z;
  int h = p / Wd, x = p - h * Wd;
  int gb = (o >> 2) << 2;
  float acc = bias[o];
  for (int ci = 0; ci < 4; ci++) {
    const bf16* src = in + ((size_t)b * Cc + gb + ci) * HWp;
    for (int ki = 0; ki < 5; ki++) {
      int hh = h + ki - 2; if ((unsigned)hh >= Hh) continue;
      for (int kj = 0; kj < 5; kj++) {
        int ww = x + kj - 2; if ((unsigned)ww >= Wd) continue;
        acc += w[((o * 4 + ci) * 5 + ki) * 5 + kj] * b2f(src[hh * Wd + ww]);
      }
    }
  }
  out[((size_t)b * Cc + o) * HWp + p] = f2b(acc);
}

// ---------------- c2a: grouped 3x3, 64->32, groups=32 (2 in-ch/group), pad 1 ----------------
__global__ void k_c2a(const bf16* __restrict__ in, const float* __restrict__ w,
                      const float* __restrict__ bias, bf16* __restrict__ out) {
  int p = blockIdx.x * 64 + threadIdx.x;
  int o = blockIdx.y * 4 + threadIdx.y;   // 0..31
  int b = blockIdx.z;
  int h = p / Wd, x = p - h * Wd;
  float acc = bias[o];
  for (int ci = 0; ci < 2; ci++) {
    const bf16* src = in + ((size_t)b * Cc + o * 2 + ci) * HWp;
    for (int ki = 0; ki < 3; ki++) {
      int hh = h + ki - 1; if ((unsigned)hh >= Hh) continue;
      for (int kj = 0; kj < 3; kj++) {
        int ww = x + kj - 1; if ((unsigned)ww >= Wd) continue;
        acc += w[((o * 2 + ci) * 3 + ki) * 3 + kj] * b2f(src[hh * Wd + ww]);
      }
    }
  }
  out[((size_t)b * 32 + o) * HWp + p] = f2b(acc);
}

// ---------------- depthwise 3x3, pad 1 ----------------
__global__ void k_c21dw(const bf16* __restrict__ in, const float* __restrict__ w,
                        const float* __restrict__ bias, bf16* __restrict__ out) {
  int p = blockIdx.x * 64 + threadIdx.x;
  int c = blockIdx.y * 4 + threadIdx.y;
  int b = blockIdx.z;
  int h = p / Wd, x = p - h * Wd;
  float acc = bias[c];
  const bf16* src = in + ((size_t)b * Cc + c) * HWp;
  for (int ki = 0; ki < 3; ki++) {
    int hh = h + ki - 1; if ((unsigned)hh >= Hh) continue;
    for (int kj = 0; kj < 3; kj++) {
      int ww = x + kj - 1; if ((unsigned)ww >= Wd) continue;
      acc += w[c * 9 + ki * 3 + kj] * b2f(src[hh * Wd + ww]);
    }
  }
  out[((size_t)b * Cc + c) * HWp + p] = f2b(acc);
}

// ---------------- fc weight prep: bf16 MFMA A-fragment order ----------------
__global__ void k_wprep(const float* __restrict__ fc1w, const float* __restrict__ fc2w,
                        short* __restrict__ wAf1, short* __restrict__ wAf2) {
  int i = blockIdx.x * 256 + threadIdx.x;   // 49152 total (192 blocks)
  if (i < 32768) {
    int j = i & 7, lane = (i >> 3) & 63, fk = i >> 9;
    int kc = fk & 3, mt = fk >> 2;          // mt 0..15
    int o = mt * 16 + (lane & 15);
    int k = kc * 32 + (lane >> 4) * 8 + j;
    wAf1[i] = (short)f2bu(fc1w[o * 128 + k]);
  } else {
    int i2 = i - 32768;
    int j = i2 & 7, lane = (i2 >> 3) & 63, fk = i2 >> 9;
    int kc = fk & 3, mt = fk >> 2;          // mt 0..7
    int o = mt * 16 + (lane & 15);
    int k = kc * 32 + (lane >> 4) * 8 + j;
    wAf2[i2] = (short)f2bu(fc2w[o * 128 + k]);
  }
}

// ---------------- 1x1-conv weight prep: A-frags for c11a/c1/c3 (64x64) + att (32x96) ----------------
__global__ void k_wprep1x1(const float* __restrict__ c11aw, const float* __restrict__ c1w,
                           const float* __restrict__ c3w, const float* __restrict__ c2cw,
                           const float* __restrict__ c211w, const float* __restrict__ attg,
                           short* __restrict__ wA_c11a, short* __restrict__ wA_c1,
                           short* __restrict__ wA_c3, short* __restrict__ wA_att) {
  int i = blockIdx.x * 256 + threadIdx.x;   // 15360 total (60 blocks)
  if (i < 12288) {
    int wi = i / 4096, r = i - wi * 4096;
    int j = r & 7, lane = (r >> 3) & 63, fk = r >> 9;  // fk = mt*2+kc
    int kc = fk & 1, mt = fk >> 1;
    int o = mt * 16 + (lane & 15);
    int k = kc * 32 + (lane >> 4) * 8 + j;
    const float* w = (wi == 0) ? c11aw : (wi == 1) ? c1w : c3w;
    short* dst = (wi == 0) ? wA_c11a : (wi == 1) ? wA_c1 : wA_c3;
    dst[r] = (short)f2bu(w[o * 64 + k]);
  } else {
    int r = i - 12288;                      // 3072: fk = mt*3+kc (2mt x 3kc)
    int j = r & 7, lane = (r >> 3) & 63, fk = r >> 9;
    int kc = fk % 3, mt = fk / 3;
    int s = mt * 16 + (lane & 15);
    int k = kc * 32 + (lane >> 4) * 8 + j;
    float v;
    if (k < 16) v = c2cw[s * 16 + k] * attg[s];
    else if (k < 32) v = 0.f;
    else v = c211w[s * 64 + (k - 32)];
    wA_att[r] = (short)f2bu(v);
  }
}

// ---------------- KBA weight prep: per-group A-frags, bias folded at k=36 ----------------
// kbwF[((g*16 + mt*2 + kc)*64 + lane)*8 + j] = A[m][k], m=mt*16+(lane&15) -> s=m>>2,o=m&3,
// k=kc*32+(lane>>4)*8+j: k<36 -> kbw[s,g,o,k]; k==36 -> kbb[s, g*4+o]; else 0.
__global__ void k_kbwF(const float* __restrict__ kbw, const float* __restrict__ kbb,
                       short* __restrict__ kbwF) {
  int i = blockIdx.x * 256 + threadIdx.x;   // 131072 total (512 blocks)
  int j = i & 7, lane = (i >> 3) & 63, fk = (i >> 9) & 15, g = i >> 13;
  int mt = fk >> 1, kc = fk & 1;
  int m = mt * 16 + (lane & 15);
  int s = m >> 2, o = m & 3;
  int k = kc * 32 + (lane >> 4) * 8 + j;
  float v = 0.f;
  if (k < 36) v = kbw[s * 2304 + g * 144 + o * 36 + k];
  else if (k == 36) v = kbb[s * 64 + g * 4 + o];
  kbwF[i] = (short)f2bu(v);
}

// ---------------- generic 1x1 conv 64->64 via MFMA ----------------
__global__ __launch_bounds__(256) void k_conv1x1_mfma(
    const bf16* __restrict__ in, const short* __restrict__ wA,
    const float* __restrict__ bias, bf16* __restrict__ out) {
  int b = blockIdx.z;
  int lane = threadIdx.x & 63, w = threadIdx.x >> 6;
  int px = blockIdx.x * 64 + w * 16 + (lane & 15);
  int q = lane >> 4;
  const unsigned short* src = (const unsigned short*)in + (size_t)b * Cc * HWp;
  const short8* wf = (const short8*)wA;
  f32x4 acc[4];
  #pragma unroll
  for (int mt = 0; mt < 4; mt++) acc[mt] = (f32x4){0.f, 0.f, 0.f, 0.f};
  #pragma unroll
  for (int kc = 0; kc < 2; kc++) {
    short8 bfv;
    #pragma unroll
    for (int j = 0; j < 8; j++) bfv[j] = (short)src[(size_t)(kc * 32 + q * 8 + j) * HWp + px];
    #pragma unroll
    for (int mt = 0; mt < 4; mt++) {
      short8 af = wf[(mt * 2 + kc) * 64 + lane];
      acc[mt] = __builtin_amdgcn_mfma_f32_16x16x32_bf16(af, bfv, acc[mt], 0, 0, 0);
    }
  }
  unsigned short* dst = (unsigned short*)out + (size_t)b * Cc * HWp;
  #pragma unroll
  for (int mt = 0; mt < 4; mt++)
    #pragma unroll
    for (int j = 0; j < 4; j++) {
      int o = mt * 16 + q * 4 + j;
      dst[(size_t)o * HWp + px] = f2bu(acc[mt][j] + bias[o]);
    }
}

// ---------------- c3 1x1 conv + residual via MFMA: y = inp + (conv)*beta (fp32 out) ----------------
__global__ __launch_bounds__(256) void k_c3y_mfma(
    const bf16* __restrict__ in, const short* __restrict__ wA,
    const float* __restrict__ bias, const float* __restrict__ beta,
    const float* __restrict__ inp, float* __restrict__ y) {
  int b = blockIdx.z;
  int lane = threadIdx.x & 63, w = threadIdx.x >> 6;
  int px = blockIdx.x * 64 + w * 16 + (lane & 15);
  int q = lane >> 4;
  const unsigned short* src = (const unsigned short*)in + (size_t)b * Cc * HWp;
  const short8* wf = (const short8*)wA;
  f32x4 acc[4];
  #pragma unroll
  for (int mt = 0; mt < 4; mt++) acc[mt] = (f32x4){0.f, 0.f, 0.f, 0.f};
  #pragma unroll
  for (int kc = 0; kc < 2; kc++) {
    short8 bfv;
    #pragma unroll
    for (int j = 0; j < 8; j++) bfv[j] = (short)src[(size_t)(kc * 32 + q * 8 + j) * HWp + px];
    #pragma unroll
    for (int mt = 0; mt < 4; mt++) {
      short8 af = wf[(mt * 2 + kc) * 64 + lane];
      acc[mt] = __builtin_amdgcn_mfma_f32_16x16x32_bf16(af, bfv, acc[mt], 0, 0, 0);
    }
  }
  #pragma unroll
  for (int mt = 0; mt < 4; mt++)
    #pragma unroll
    for (int j = 0; j < 4; j++) {
      int o = mt * 16 + q * 4 + j;
      size_t oi = ((size_t)b * Cc + o) * HWp + px;
      y[oi] = inp[oi] + (acc[mt][j] + bias[o]) * beta[o];
    }
}

// ---------------- att via MFMA: M=32, K = [gate16 | pad16 | x64] ----------------
__global__ __launch_bounds__(256) void k_att_mfma(
    const bf16* __restrict__ g, const bf16* __restrict__ x,
    const short* __restrict__ wA, const float* __restrict__ c2cb,
    const float* __restrict__ c211b, const float* __restrict__ attg,
    bf16* __restrict__ att) {
  int b = blockIdx.z;
  int lane = threadIdx.x & 63, w = threadIdx.x >> 6;
  int px = blockIdx.x * 64 + w * 16 + (lane & 15);
  int q = lane >> 4;
  const unsigned short* gs = (const unsigned short*)g + (size_t)b * 32 * HWp;
  const unsigned short* xs = (const unsigned short*)x + (size_t)b * Cc * HWp;
  const short8* wf = (const short8*)wA;
  f32x4 acc[2];
  acc[0] = (f32x4){0.f, 0.f, 0.f, 0.f};
  acc[1] = (f32x4){0.f, 0.f, 0.f, 0.f};
  {
    short8 bfv;
    #pragma unroll
    for (int j = 0; j < 8; j++) {
      int k = q * 8 + j;
      short v = 0;
      if (q < 2) {
        float gv = ubf(gs[(size_t)k * HWp + px]) * ubf(gs[(size_t)(16 + k) * HWp + px]);
        v = (short)f2bu(gv);
      }
      bfv[j] = v;
    }
    #pragma unroll
    for (int mt = 0; mt < 2; mt++) {
      short8 af = wf[(mt * 3 + 0) * 64 + lane];
      acc[mt] = __builtin_amdgcn_mfma_f32_16x16x32_bf16(af, bfv, acc[mt], 0, 0, 0);
    }
  }
  #pragma unroll
  for (int kc = 1; kc < 3; kc++) {
    short8 bfv;
    #pragma unroll
    for (int j = 0; j < 8; j++)
      bfv[j] = (short)xs[(size_t)((kc - 1) * 32 + q * 8 + j) * HWp + px];
    #pragma unroll
    for (int mt = 0; mt < 2; mt++) {
      short8 af = wf[(mt * 3 + kc) * 64 + lane];
      acc[mt] = __builtin_amdgcn_mfma_f32_16x16x32_bf16(af, bfv, acc[mt], 0, 0, 0);
    }
  }
  unsigned short* dst = (unsigned short*)att + (size_t)b * 32 * HWp;
  #pragma unroll
  for (int mt = 0; mt < 2; mt++)
    #pragma unroll
    for (int j = 0; j < 4; j++) {
      int s = mt * 16 + q * 4 + j;
      dst[(size_t)s * HWp + px] = f2bu(acc[mt][j] + c2cb[s] * attg[s] + c211b[s]);
    }
}

// ---------------- DFT twiddle tables in MFMA A-fragment order ----------------
__global__ void k_dftfrag(short* __restrict__ cosF, short* __restrict__ sinF) {
  int i = blockIdx.x * 256 + threadIdx.x;   // 25600 total (100 blocks)
  int j = i & 7, lane = (i >> 3) & 63, fk = i >> 9;   // fk = ct*5+kc, 0..49
  int kc = fk % 5, ct = fk / 5;
  int c = ct * 16 + (lane & 15);
  int b = kc * 32 + (lane >> 4) * 8 + j;
  int m = (b * c) % 160;
  float sv, cv;
  __sincosf((float)m * TWO_PI_160, &sv, &cv);
  cosF[i] = (short)f2bu(cv);
  sinF[i] = (short)f2bu(sv);
}

// ---------------- KBA via MFMA ----------------
// Per wave: 16 px, all 16 groups. Per group g: Z[(s,o)][px] via 16 MFMAs
// (M=128, K=64-padded-36 w/ bias at k=36), then s-reduction with att in-register
// + 2 butterfly shuffles; lane q writes channel g*4+q with fused epilogue.
__global__ __launch_bounds__(256) void k_kba_mfma(
    const bf16* __restrict__ uf, const bf16* __restrict__ att,
    const bf16* __restrict__ x1, const float* __restrict__ scaV,
    const short* __restrict__ kbwF, const float* __restrict__ ga1,
    bf16* __restrict__ out) {
  __shared__ unsigned short patchL[64 * 3 * 66];   // 25344 B, bf16 [c][ki][col]
  __shared__ float attL[64][33];                   // 8448 B
  int b = blockIdx.z, h = blockIdx.y;
  int w0 = blockIdx.x * 64;
  int width = min(64, Wd - w0);
  int t = threadIdx.x;
  const unsigned short* uf_u = (const unsigned short*)uf;
  for (int i = t; i < 64 * 3 * 66; i += 256) {
    int c = i / 198, rem = i - c * 198;
    int r = rem / 66, col = rem - r * 66;
    int hh = h + r - 1, ww = w0 + col - 1;
    unsigned short v = 0;
    if ((unsigned)hh < Hh && (unsigned)ww < Wd)
      v = uf_u[((size_t)b * Cc + c) * HWp + hh * Wd + ww];
    patchL[i] = v;
  }
  for (int i = t; i < 64 * 32; i += 256) {
    int px = i & 63, s = i >> 6;
    float v = 0.f;
    if (px < width) v = b2f(att[((size_t)b * 32 + s) * HWp + h * Wd + w0 + px]);
    attL[px][s] = v;
  }
  __syncthreads();
  int lane = t & 63, w = t >> 6;
  int n = lane & 15, q = lane >> 4;
  int pxl = w * 16 + n;
  float attR[8];
  #pragma unroll
  for (int mt = 0; mt < 8; mt++) attR[mt] = attL[pxl][4 * mt + q];
  int offA[8];
  #pragma unroll
  for (int j = 0; j < 8; j++) {
    int k = q * 8 + j;
    int ci = k / 9, r = k - ci * 9, ki = r / 3, kj = r - ki * 3;
    offA[j] = ci * 198 + ki * 66 + pxl + kj;
  }
  int offB[4];
  #pragma unroll
  for (int j = 0; j < 4; j++) {
    int k = 32 + j, r = k - 27, ki = r / 3, kj = r - ki * 3;
    offB[j] = 3 * 198 + ki * 66 + pxl + kj;
  }
  const short8* wf = (const short8*)kbwF;
  const unsigned short* x1u = (const unsigned short*)x1 + (size_t)b * Cc * HWp + h * Wd + w0;
  unsigned short* outu = (unsigned short*)out + (size_t)b * Cc * HWp + h * Wd + w0;
  for (int g = 0; g < 16; g++) {
    short8 b0, b1;
    #pragma unroll
    for (int j = 0; j < 8; j++) b0[j] = (short)patchL[g * 792 + offA[j]];
    #pragma unroll
    for (int j = 0; j < 8; j++) b1[j] = 0;
    if (q == 0) {
      #pragma unroll
      for (int j = 0; j < 4; j++) b1[j] = (short)patchL[g * 792 + offB[j]];
      b1[4] = (short)0x3F80;                 // B[36][*] = 1.0 (bias row)
    }
    f32x4 acc[8];
    #pragma unroll
    for (int mt = 0; mt < 8; mt++) acc[mt] = (f32x4){0.f, 0.f, 0.f, 0.f};
    #pragma unroll
    for (int mt = 0; mt < 8; mt++) {
      short8 a0 = wf[(g * 16 + mt * 2 + 0) * 64 + lane];
      acc[mt] = __builtin_amdgcn_mfma_f32_16x16x32_bf16(a0, b0, acc[mt], 0, 0, 0);
      short8 a1 = wf[(g * 16 + mt * 2 + 1) * 64 + lane];
      acc[mt] = __builtin_amdgcn_mfma_f32_16x16x32_bf16(a1, b1, acc[mt], 0, 0, 0);
    }
    // s-reduction: lane(q) holds rows s=4mt+q, o=j; butterfly over q-groups
    #pragma unroll
    for (int o = 0; o < 4; o++) {
      float P = 0.f;
      #pragma unroll
      for (int mt = 0; mt < 8; mt++) P += attR[mt] * acc[mt][o];
      P += __shfl_xor(P, 16);
      P += __shfl_xor(P, 32);
      if (o == q && pxl < width) {
        int c = g * 4 + q;
        float ufc = ubf(patchL[c * 198 + 66 + pxl + 1]);   // center tap
        float xk = P * ga1[c] + ufc;
        float xv = xk * ubf(x1u[(size_t)c * HWp + pxl]) * scaV[b * 64 + c];
        outu[(size_t)c * HWp + pxl] = f2bu(xv);
      }
    }
  }
}

// ---------------- LayerNorm, fp32 in (y in d_out) -> bf16 ws out ----------------
__global__ void k_ln2(const float* __restrict__ in, const float* __restrict__ w,
                      const float* __restrict__ bb, bf16* __restrict__ out) {
  int idx = blockIdx.x * 256 + threadIdx.x;
  int b = idx / HWp, p = idx - b * HWp;
  const float* src = in + (size_t)b * Cc * HWp + p;
  float s = 0.f, s2 = 0.f;
  for (int c = 0; c < Cc; c++) { float v = src[(size_t)c * HWp]; s += v; s2 += v * v; }
  float mu = s * (1.f / 64.f);
  float var = s2 * (1.f / 64.f) - mu * mu;
  float rs = rsqrtf(fmaxf(var, 0.f) + 1e-6f);
  bf16* dst = out + (size_t)b * Cc * HWp + p;
  for (int c = 0; c < Cc; c++) {
    float v = src[(size_t)c * HWp];
    dst[(size_t)c * HWp] = f2b((v - mu) * rs * w[c] + bb[c]);
  }
}

// ---------------- DFT pass via MFMA ----------------
__global__ __launch_bounds__(64) void k_cpass_mfma(
    const bf16* __restrict__ inr, const bf16* __restrict__ ini,
    const short* __restrict__ cosF, const short* __restrict__ sinF,
    bf16* __restrict__ outr, bf16* __restrict__ outi,
    float sgn, float scale,
    const float* __restrict__ sclr, const float* __restrict__ scli) {
  int plane = blockIdx.z;
  int a0 = blockIdx.x * 16;
  int cth = blockIdx.y * 5;          // c-half: ct 0..4 or 5..9
  int lane = threadIdx.x;
  int n = lane & 15, q = lane >> 4;
  const unsigned short* pr = (const unsigned short*)inr + (size_t)plane * HWp;
  const unsigned short* pi = ini ? (const unsigned short*)ini + (size_t)plane * HWp : nullptr;
  float srm = sclr ? sclr[plane] : 1.f;
  float sim = scli ? scli[plane] : 1.f;
  short8 br[5], bi[5];
  #pragma unroll
  for (int kc = 0; kc < 5; kc++) {
    br[kc] = *(const short8*)(pr + (a0 + n) * 160 + kc * 32 + q * 8);
    if (pi) bi[kc] = *(const short8*)(pi + (a0 + n) * 160 + kc * 32 + q * 8);
  }
  const short8* cf = (const short8*)cosF;
  const short8* sf = (const short8*)sinF;
  unsigned short* qr = (unsigned short*)outr + (size_t)plane * HWp;
  unsigned short* qi = (unsigned short*)outi + (size_t)plane * HWp;
  for (int ctl = 0; ctl < 5; ctl++) {
    int ct = cth + ctl;
    f32x4 arr = (f32x4){0.f,0.f,0.f,0.f}, asr = (f32x4){0.f,0.f,0.f,0.f};
    f32x4 ari = (f32x4){0.f,0.f,0.f,0.f}, asi = (f32x4){0.f,0.f,0.f,0.f};
    #pragma unroll
    for (int kc = 0; kc < 5; kc++) {
      short8 ca = cf[(ct * 5 + kc) * 64 + lane];
      short8 sa = sf[(ct * 5 + kc) * 64 + lane];
      arr = __builtin_amdgcn_mfma_f32_16x16x32_bf16(ca, br[kc], arr, 0, 0, 0);
      asr = __builtin_amdgcn_mfma_f32_16x16x32_bf16(sa, br[kc], asr, 0, 0, 0);
      if (pi) {
        ari = __builtin_amdgcn_mfma_f32_16x16x32_bf16(ca, bi[kc], ari, 0, 0, 0);
        asi = __builtin_amdgcn_mfma_f32_16x16x32_bf16(sa, bi[kc], asi, 0, 0, 0);
      }
    }
    #pragma unroll
    for (int j = 0; j < 4; j++) {
      int c = ct * 16 + q * 4 + j;
      float xc = srm * arr[j], xs = srm * asr[j];
      float ic = pi ? sim * ari[j] : 0.f, is = pi ? sim * asi[j] : 0.f;
      float orv = (xc - sgn * is) * scale;
      float oiv = (sgn * xs + ic) * scale;
      qr[c * 160 + a0 + n] = f2bu(orv);
      qi[c * 160 + a0 + n] = f2bu(oiv);
    }
  }
}

// ---------------- final inverse DFT pass via MFMA, fused |.|, *gamma, += y (fp32 d_out) ----------------
__global__ __launch_bounds__(64) void k_cpass_final_mfma(
    const bf16* __restrict__ inr, const bf16* __restrict__ ini,
    const short* __restrict__ cosF, const short* __restrict__ sinF,
    float sgn, float scale,
    const float* __restrict__ gamma, float* __restrict__ dout) {
  int plane = blockIdx.z;
  int a0 = blockIdx.x * 16;
  int cth = blockIdx.y * 5;
  int lane = threadIdx.x;
  int n = lane & 15, q = lane >> 4;
  const unsigned short* pr = (const unsigned short*)inr + (size_t)plane * HWp;
  const unsigned short* pi = (const unsigned short*)ini + (size_t)plane * HWp;
  short8 br[5], bi[5];
  #pragma unroll
  for (int kc = 0; kc < 5; kc++) {
    br[kc] = *(const short8*)(pr + (a0 + n) * 160 + kc * 32 + q * 8);
    bi[kc] = *(const short8*)(pi + (a0 + n) * 160 + kc * 32 + q * 8);
  }
  const short8* cf = (const short8*)cosF;
  const short8* sf = (const short8*)sinF;
  float gm = gamma[plane & 63];
  float* dp = dout + (size_t)plane * HWp;
  for (int ctl = 0; ctl < 5; ctl++) {
    int ct = cth + ctl;
    f32x4 arr = (f32x4){0.f,0.f,0.f,0.f}, asr = (f32x4){0.f,0.f,0.f,0.f};
    f32x4 ari = (f32x4){0.f,0.f,0.f,0.f}, asi = (f32x4){0.f,0.f,0.f,0.f};
    #pragma unroll
    for (int kc = 0; kc < 5; kc++) {
      short8 ca = cf[(ct * 5 + kc) * 64 + lane];
      short8 sa = sf[(ct * 5 + kc) * 64 + lane];
      arr = __builtin_amdgcn_mfma_f32_16x16x32_bf16(ca, br[kc], arr, 0, 0, 0);
      asr = __builtin_amdgcn_mfma_f32_16x16x32_bf16(sa, br[kc], asr, 0, 0, 0);
      ari = __builtin_amdgcn_mfma_f32_16x16x32_bf16(ca, bi[kc], ari, 0, 0, 0);
      asi = __builtin_amdgcn_mfma_f32_16x16x32_bf16(sa, bi[kc], asi, 0, 0, 0);
    }
    #pragma unroll
    for (int j = 0; j < 4; j++) {
      int c = ct * 16 + q * 4 + j;
      float orv = (arr[j] - sgn * asi[j]) * scale;
      float oiv = (sgn * asr[j] + ari[j]) * scale;
      float z = sqrtf(orv * orv + oiv * oiv);
      dp[c * 160 + a0 + n] += z * gm;   // dout currently holds y
    }
  }
}

// ---------------- fc1 (128->256) + simple_gate, MFMA ----------------
__global__ __launch_bounds__(256) void k_fc1_mfma(
    const bf16* __restrict__ Fr, const bf16* __restrict__ Fi,
    const short* __restrict__ wA, const float* __restrict__ bias,
    bf16* __restrict__ G1, bf16* __restrict__ G2) {
  int b = blockIdx.z;
  int lane = threadIdx.x & 63, w = threadIdx.x >> 6;
  int px = blockIdx.x * 64 + w * 16 + (lane & 15);
  int q = lane >> 4;
  const unsigned short* fr = (const unsigned short*)Fr + (size_t)b * Cc * HWp;
  const unsigned short* fi = (const unsigned short*)Fi + (size_t)b * Cc * HWp;
  const short8* wf = (const short8*)wA;
  f32x4 acc[16];
  #pragma unroll
  for (int mt = 0; mt < 16; mt++) acc[mt] = (f32x4){0.f, 0.f, 0.f, 0.f};
  #pragma unroll
  for (int kc = 0; kc < 4; kc++) {
    const unsigned short* basep = (kc < 2) ? (fr + (size_t)(kc * 32) * HWp)
                                           : (fi + (size_t)((kc - 2) * 32) * HWp);
    short8 bfv;
    #pragma unroll
    for (int j = 0; j < 8; j++) bfv[j] = (short)basep[(size_t)(q * 8 + j) * HWp + px];
    #pragma unroll
    for (int mt = 0; mt < 16; mt++) {
      short8 af = wf[(mt * 4 + kc) * 64 + lane];
      acc[mt] = __builtin_amdgcn_mfma_f32_16x16x32_bf16(af, bfv, acc[mt], 0, 0, 0);
    }
  }
  unsigned short* g1 = (unsigned short*)G1 + (size_t)b * Cc * HWp;
  unsigned short* g2 = (unsigned short*)G2 + (size_t)b * Cc * HWp;
  #pragma unroll
  for (int mt = 0; mt < 8; mt++)
    #pragma unroll
    for (int j = 0; j < 4; j++) {
      int o = mt * 16 + q * 4 + j;
      float v1 = acc[mt][j] + bias[o];
      float v2 = acc[mt + 8][j] + bias[o + 128];
      unsigned short hv = f2bu(v1 * v2);
      if (o < 64) g1[(size_t)o * HWp + px] = hv;
      else        g2[(size_t)(o - 64) * HWp + px] = hv;
    }
}

// ---------------- fc2 (128->128) MFMA, split output into r / i planes ----------------
__global__ __launch_bounds__(256) void k_fc2_mfma(
    const bf16* __restrict__ G1, const bf16* __restrict__ G2,
    const short* __restrict__ wA, const float* __restrict__ bias,
    bf16* __restrict__ Or, bf16* __restrict__ Oi) {
  int b = blockIdx.z;
  int lane = threadIdx.x & 63, w = threadIdx.x >> 6;
  int px = blockIdx.x * 64 + w * 16 + (lane & 15);
  int q = lane >> 4;
  const unsigned short* g1 = (const unsigned short*)G1 + (size_t)b * Cc * HWp;
  const unsigned short* g2 = (const unsigned short*)G2 + (size_t)b * Cc * HWp;
  const short8* wf = (const short8*)wA;
  f32x4 acc[8];
  #pragma unroll
  for (int mt = 0; mt < 8; mt++) acc[mt] = (f32x4){0.f, 0.f, 0.f, 0.f};
  #pragma unroll
  for (int kc = 0; kc < 4; kc++) {
    const unsigned short* basep = (kc < 2) ? (g1 + (size_t)(kc * 32) * HWp)
                                           : (g2 + (size_t)((kc - 2) * 32) * HWp);
    short8 bfv;
    #pragma unroll
    for (int j = 0; j < 8; j++) bfv[j] = (short)basep[(size_t)(q * 8 + j) * HWp + px];
    #pragma unroll
    for (int mt = 0; mt < 8; mt++) {
      short8 af = wf[(mt * 4 + kc) * 64 + lane];
      acc[mt] = __builtin_amdgcn_mfma_f32_16x16x32_bf16(af, bfv, acc[mt], 0, 0, 0);
    }
  }
  unsigned short* orp = (unsigned short*)Or + (size_t)b * Cc * HWp;
  unsigned short* oip = (unsigned short*)Oi + (size_t)b * Cc * HWp;
  #pragma unroll
  for (int mt = 0; mt < 8; mt++)
    #pragma unroll
    for (int j = 0; j < 4; j++) {
      int o = mt * 16 + q * 4 + j;
      unsigned short hv = f2bu(acc[mt][j] + bias[o]);
      if (o < 64) orp[(size_t)o * HWp + px] = hv;
      else        oip[(size_t)(o - 64) * HWp + px] = hv;
    }
}

extern "C" void kernel_launch(void* const* d_in, const int* in_sizes, int n_in,
                              void* d_out, int out_size, void* d_ws, size_t ws_size,
                              hipStream_t stream) {
  const float* inp   = (const float*)d_in[0];
  const float* n1w   = (const float*)d_in[1];
  const float* n1b   = (const float*)d_in[2];
  const float* n2w   = (const float*)d_in[3];
  const float* n2b   = (const float*)d_in[4];
  const float* scaw  = (const float*)d_in[5];
  const float* scab  = (const float*)d_in[6];
  const float* c11aw = (const float*)d_in[7];
  const float* c11ab = (const float*)d_in[8];
  const float* c11bw = (const float*)d_in[9];
  const float* c11bb = (const float*)d_in[10];
  const float* c1w   = (const float*)d_in[11];
  const float* c1b   = (const float*)d_in[12];
  const float* c21w  = (const float*)d_in[13];
  const float* c21b  = (const float*)d_in[14];
  const float* c2aw  = (const float*)d_in[15];
  const float* c2ab  = (const float*)d_in[16];
  const float* c2cw  = (const float*)d_in[17];
  const float* c2cb  = (const float*)d_in[18];
  const float* c211w = (const float*)d_in[19];
  const float* c211b = (const float*)d_in[20];
  const float* c3w   = (const float*)d_in[21];
  const float* c3b   = (const float*)d_in[22];
  const float* kbw   = (const float*)d_in[23];
  const float* kbb   = (const float*)d_in[24];
  const float* ga1   = (const float*)d_in[25];
  const float* attg  = (const float*)d_in[26];
  const float* beta  = (const float*)d_in[27];
  const float* gamma = (const float*)d_in[28];
  const float* fc1w  = (const float*)d_in[29];
  const float* fc1b  = (const float*)d_in[30];
  const float* fc2w  = (const float*)d_in[31];
  const float* fc2b  = (const float*)d_in[32];
  const float* fscaw = (const float*)d_in[33];
  const float* fscab = (const float*)d_in[34];

  const size_t S = (size_t)Bn * Cc * HWp;   // 3,276,800 elements per slot
  bf16* A  = (bf16*)d_ws;                   // 4 bf16 slots = 26.2 MB total
  bf16* Bs = A + S;
  bf16* Cs = A + 2 * S;
  bf16* Ds = A + 3 * S;
  float* smalls = (float*)(A + 4 * S);      // fp32 smalls
  float* xm   = smalls;
  float* scaV = smalls + 128;
  float* rmv  = smalls + 256;
  float* imv  = smalls + 384;
  float* sra  = smalls + 512;
  float* sia  = smalls + 640;
  short* wS   = (short*)(smalls + 1024);    // bf16 frag tables (~490 KB total)
  short* wAf1 = wS;                         // 32768
  short* wAf2 = wAf1 + 32768;               // 16384
  short* cosF = wAf2 + 16384;               // 25600
  short* sinF = cosF + 25600;               // 25600
  short* wA_c11a = sinF + 25600;            // 4096
  short* wA_c1   = wA_c11a + 4096;          // 4096
  short* wA_c3   = wA_c1 + 4096;            // 4096
  short* wA_att  = wA_c3 + 4096;            // 3072
  short* kbwF    = wA_att + 3072;           // 131072 (256 KB)
  bf16* gbuf = Bs;            // [B,32,HW] (first half of Bs)
  bf16* attb = Bs + S / 2;    // [B,32,HW] (second half of Bs)
  float* yb  = (float*)d_out; // y lives in d_out (fp32)

  dim3 blk(64, 4, 1);
  dim3 cgrid(10, 2, Bn * Cc);
  dim3 pgrid(400, 1, Bn);

  k_kbwF<<<dim3(512), dim3(256), 0, stream>>>(kbw, kbb, kbwF);          // kba frags (independent)
  k_wprep<<<dim3(192), dim3(256), 0, stream>>>(fc1w, fc2w, wAf1, wAf2); // fc frags (independent)
  k_dftfrag<<<dim3(100), dim3(256), 0, stream>>>(cosF, sinF);           // DFT frags (independent)
  k_wprep1x1<<<dim3(60), dim3(256), 0, stream>>>(c11aw, c1w, c3w, c2cw, c211w, attg,
                                                 wA_c11a, wA_c1, wA_c3, wA_att);
  k_ln<<<dim3(200), dim3(256), 0, stream>>>(inp, n1w, n1b, A);          // A = x
  k_meanhw<<<dim3(128), dim3(256), 0, stream>>>(A, xm);
  k_small_mv<<<dim3(1), dim3(128), 0, stream>>>(xm, scaw, scab, scaV, 0);
  k_conv1x1_mfma<<<pgrid, dim3(256), 0, stream>>>(A, wA_c11a, c11ab, Bs);          // B = t1
  k_c11b<<<dim3(400, 16, Bn), blk, 0, stream>>>(Bs, c11bw, c11bb, Cs);             // C = x1 (B dead)
  k_c2a<<<dim3(400, 8, Bn), blk, 0, stream>>>(A, c2aw, c2ab, gbuf);                // B.lo = g
  k_att_mfma<<<pgrid, dim3(256), 0, stream>>>(gbuf, A, wA_att, c2cb, c211b, attg, attb); // B.hi = att
  k_conv1x1_mfma<<<pgrid, dim3(256), 0, stream>>>(A, wA_c1, c1b, Ds);              // D = t2 (A dead after)
  k_c21dw<<<dim3(400, 16, Bn), blk, 0, stream>>>(Ds, c21w, c21b, A);               // A = uf
  k_kba_mfma<<<dim3(3, 160, Bn), dim3(256), 0, stream>>>(A, attb, Cs, scaV, kbwF, ga1, Ds); // D = xprod
  k_c3y_mfma<<<pgrid, dim3(256), 0, stream>>>(Ds, wA_c3, c3b, beta, inp, yb);      // d_out = y (fp32)
  k_ln2<<<dim3(200), dim3(256), 0, stream>>>(yb, n2w, n2b, A);                     // A = X
  // forward FFT2 (MFMA): pass over W ([h][w] -> [u][h]), then over H ([u][h] -> [v][u])
  k_cpass_mfma<<<cgrid, dim3(64), 0, stream>>>(A, (const bf16*)nullptr, cosF, sinF, Bs, Cs, -1.f, SCL, nullptr, nullptr); // B,C = F1
  k_cpass_mfma<<<cgrid, dim3(64), 0, stream>>>(Bs, Cs, cosF, sinF, Ds, A, -1.f, SCL, nullptr, nullptr);                   // D,A = F2
  k_fc1_mfma<<<pgrid, dim3(256), 0, stream>>>(Ds, A, wAf1, fc1b, Bs, Cs);          // B,C = gated
  k_fc2_mfma<<<pgrid, dim3(256), 0, stream>>>(Bs, Cs, wAf2, fc2b, Ds, A);          // D = r, A = i
  k_meanhw<<<dim3(128), dim3(256), 0, stream>>>(Ds, rmv);
  k_meanhw<<<dim3(128), dim3(256), 0, stream>>>(A, imv);
  k_small_mv<<<dim3(1), dim3(128), 0, stream>>>(rmv, fscaw, fscab, sra, 1);
  k_small_mv<<<dim3(1), dim3(128), 0, stream>>>(imv, fscaw, fscab, sia, 1);
  // inverse FFT2 (MFMA) with per-plane (1+ra)/(1+ia) scaling fused into first pass
  k_cpass_mfma<<<cgrid, dim3(64), 0, stream>>>(Ds, A, cosF, sinF, Bs, Cs, 1.f, SCL, sra, sia);  // B,C
  k_cpass_final_mfma<<<cgrid, dim3(64), 0, stream>>>(Bs, Cs, cosF, sinF, 1.f, SCL, gamma, yb);  // d_out = y + |z|*gamma
}

// Round 12
// 576.334 us; speedup vs baseline: 3.4082x; 1.1208x over previous
//
#include <hip/hip_runtime.h>
#include <hip/hip_bf16.h>

typedef __hip_bfloat16 bf16;
typedef __attribute__((ext_vector_type(8))) short short8;
typedef __attribute__((ext_vector_type(4))) float f32x4;

#define Hh 160
#define Wd 160
#define HWp (Hh*Wd)       // 25600
#define Bn 2
#define Cc 64
#define NPIX (Bn*HWp)     // 51200
#define SCL 0.07905694150420949f   // 1/sqrt(160)
#define TWO_PI_160 0.039269908169872414f  // 2*pi/160

static __device__ __forceinline__ float b2f(bf16 x) { return __bfloat162float(x); }
static __device__ __forceinline__ bf16 f2b(float f) { return __float2bfloat16(f); }
static __device__ __forceinline__ unsigned short f2bu(float f) {
  union { bf16 h; unsigned short u; } z; z.h = __float2bfloat16(f); return z.u;
}
static __device__ __forceinline__ float ubf(unsigned short u) {
  union { unsigned int i; float f; } z; z.i = ((unsigned int)u) << 16; return z.f;
}

// ---------------- LayerNorm over channel dim (per pixel), fp32 in -> bf16 out ----------------
__global__ void k_ln(const float* __restrict__ in, const float* __restrict__ w,
                     const float* __restrict__ bb, bf16* __restrict__ out) {
  int idx = blockIdx.x * 256 + threadIdx.x;   // grid covers exactly NPIX
  int b = idx / HWp, p = idx - b * HWp;
  const float* src = in + (size_t)b * Cc * HWp + p;
  float s = 0.f, s2 = 0.f;
  for (int c = 0; c < Cc; c++) { float v = src[(size_t)c * HWp]; s += v; s2 += v * v; }
  float mu = s * (1.f / 64.f);
  float var = s2 * (1.f / 64.f) - mu * mu;
  float rs = rsqrtf(fmaxf(var, 0.f) + 1e-6f);
  bf16* dst = out + (size_t)b * Cc * HWp + p;
  for (int c = 0; c < Cc; c++) {
    float v = src[(size_t)c * HWp];
    dst[(size_t)c * HWp] = f2b((v - mu) * rs * w[c] + bb[c]);
  }
}

// ---------------- mean over HW per (b,c) plane (bf16 in) ----------------
__global__ void k_meanhw(const bf16* __restrict__ in, float* __restrict__ out) {
  int bc = blockIdx.x;
  const bf16* src = in + (size_t)bc * HWp;
  int t = threadIdx.x;
  float s = 0.f;
  for (int i = t; i < HWp; i += 256) s += b2f(src[i]);
  __shared__ float sm[256];
  sm[t] = s; __syncthreads();
  for (int off = 128; off; off >>= 1) { if (t < off) sm[t] += sm[t + off]; __syncthreads(); }
  if (t == 0) out[bc] = sm[0] * (1.f / HWp);
}

// ---------------- small matvec: out[b,o] = (addone) + W[o,:]·xin[b,:] + bias[o] ----------------
__global__ void k_small_mv(const float* __restrict__ xin, const float* __restrict__ w,
                           const float* __restrict__ bias, float* __restrict__ out, int addone) {
  int t = threadIdx.x;              // 128 threads
  int b = t >> 6, o = t & 63;
  float acc = bias[o];
  for (int k = 0; k < 64; k++) acc += w[o * 64 + k] * xin[b * 64 + k];
  out[t] = addone ? (1.f + acc) : acc;
}

// ---------------- c2a: grouped 3x3, 64->32, groups=32 (2 in-ch/group), pad 1 ----------------
__global__ void k_c2a(const bf16* __restrict__ in, const float* __restrict__ w,
                      const float* __restrict__ bias, bf16* __restrict__ out) {
  int p = blockIdx.x * 64 + threadIdx.x;
  int o = blockIdx.y * 4 + threadIdx.y;   // 0..31
  int b = blockIdx.z;
  int h = p / Wd, x = p - h * Wd;
  float acc = bias[o];
  for (int ci = 0; ci < 2; ci++) {
    const bf16* src = in + ((size_t)b * Cc + o * 2 + ci) * HWp;
    for (int ki = 0; ki < 3; ki++) {
      int hh = h + ki - 1; if ((unsigned)hh >= Hh) continue;
      for (int kj = 0; kj < 3; kj++) {
        int ww = x + kj - 1; if ((unsigned)ww >= Wd) continue;
        acc += w[((o * 2 + ci) * 3 + ki) * 3 + kj] * b2f(src[hh * Wd + ww]);
      }
    }
  }
  out[((size_t)b * 32 + o) * HWp + p] = f2b(acc);
}

// ---------------- depthwise 3x3, pad 1 ----------------
__global__ void k_c21dw(const bf16* __restrict__ in, const float* __restrict__ w,
                        const float* __restrict__ bias, bf16* __restrict__ out) {
  int p = blockIdx.x * 64 + threadIdx.x;
  int c = blockIdx.y * 4 + threadIdx.y;
  int b = blockIdx.z;
  int h = p / Wd, x = p - h * Wd;
  float acc = bias[c];
  const bf16* src = in + ((size_t)b * Cc + c) * HWp;
  for (int ki = 0; ki < 3; ki++) {
    int hh = h + ki - 1; if ((unsigned)hh >= Hh) continue;
    for (int kj = 0; kj < 3; kj++) {
      int ww = x + kj - 1; if ((unsigned)ww >= Wd) continue;
      acc += w[c * 9 + ki * 3 + kj] * b2f(src[hh * Wd + ww]);
    }
  }
  out[((size_t)b * Cc + c) * HWp + p] = f2b(acc);
}

// ---------------- fc weight prep: bf16 MFMA A-fragment order ----------------
__global__ void k_wprep(const float* __restrict__ fc1w, const float* __restrict__ fc2w,
                        short* __restrict__ wAf1, short* __restrict__ wAf2) {
  int i = blockIdx.x * 256 + threadIdx.x;   // 49152 total (192 blocks)
  if (i < 32768) {
    int j = i & 7, lane = (i >> 3) & 63, fk = i >> 9;
    int kc = fk & 3, mt = fk >> 2;          // mt 0..15
    int o = mt * 16 + (lane & 15);
    int k = kc * 32 + (lane >> 4) * 8 + j;
    wAf1[i] = (short)f2bu(fc1w[o * 128 + k]);
  } else {
    int i2 = i - 32768;
    int j = i2 & 7, lane = (i2 >> 3) & 63, fk = i2 >> 9;
    int kc = fk & 3, mt = fk >> 2;          // mt 0..7
    int o = mt * 16 + (lane & 15);
    int k = kc * 32 + (lane >> 4) * 8 + j;
    wAf2[i2] = (short)f2bu(fc2w[o * 128 + k]);
  }
}

// ---------------- 1x1-conv weight prep: A-frags for c11a/c1/c3 (64x64) + att (32x96) ----------------
__global__ void k_wprep1x1(const float* __restrict__ c11aw, const float* __restrict__ c1w,
                           const float* __restrict__ c3w, const float* __restrict__ c2cw,
                           const float* __restrict__ c211w, const float* __restrict__ attg,
                           short* __restrict__ wA_c11a, short* __restrict__ wA_c1,
                           short* __restrict__ wA_c3, short* __restrict__ wA_att) {
  int i = blockIdx.x * 256 + threadIdx.x;   // 15360 total (60 blocks)
  if (i < 12288) {
    int wi = i / 4096, r = i - wi * 4096;
    int j = r & 7, lane = (r >> 3) & 63, fk = r >> 9;  // fk = mt*2+kc
    int kc = fk & 1, mt = fk >> 1;
    int o = mt * 16 + (lane & 15);
    int k = kc * 32 + (lane >> 4) * 8 + j;
    const float* w = (wi == 0) ? c11aw : (wi == 1) ? c1w : c3w;
    short* dst = (wi == 0) ? wA_c11a : (wi == 1) ? wA_c1 : wA_c3;
    dst[r] = (short)f2bu(w[o * 64 + k]);
  } else {
    int r = i - 12288;                      // 3072: fk = mt*3+kc (2mt x 3kc)
    int j = r & 7, lane = (r >> 3) & 63, fk = r >> 9;
    int kc = fk % 3, mt = fk / 3;
    int s = mt * 16 + (lane & 15);
    int k = kc * 32 + (lane >> 4) * 8 + j;
    float v;
    if (k < 16) v = c2cw[s * 16 + k] * attg[s];
    else if (k < 32) v = 0.f;
    else v = c211w[s * 64 + (k - 32)];
    wA_att[r] = (short)f2bu(v);
  }
}

// ---------------- KBA weight prep: per-group A-frags, bias folded at k=36 ----------------
__global__ void k_kbwF(const float* __restrict__ kbw, const float* __restrict__ kbb,
                       short* __restrict__ kbwF) {
  int i = blockIdx.x * 256 + threadIdx.x;   // 131072 total (512 blocks)
  int j = i & 7, lane = (i >> 3) & 63, fk = (i >> 9) & 15, g = i >> 13;
  int mt = fk >> 1, kc = fk & 1;
  int m = mt * 16 + (lane & 15);
  int s = m >> 2, o = m & 3;
  int k = kc * 32 + (lane >> 4) * 8 + j;
  float v = 0.f;
  if (k < 36) v = kbw[s * 2304 + g * 144 + o * 36 + k];
  else if (k == 36) v = kbb[s * 64 + g * 4 + o];
  kbwF[i] = (short)f2bu(v);
}

// ---------------- c11b weight prep: block-diag A-frags (M=16 per gset, K=416) ----------------
// frag[(gset*13+kc)*64+lane][j]: m=lane&15, k=kc*32+(lane>>4)*8+j.
// k<400: gl=k/100,ci=(k%100)/25,dd=k%25 -> w[(o*4+ci)*25+dd] if (m>>2)==gl else 0.
// k==400: bias[o].  o = gset*16 + m.
__global__ void k_c11F(const float* __restrict__ w, const float* __restrict__ bias,
                       short* __restrict__ frag) {
  int i = blockIdx.x * 256 + threadIdx.x;   // 26624 total (104 blocks)
  if (i >= 26624) return;
  int j = i & 7, lane = (i >> 3) & 63, fk = i >> 9;   // fk = gset*13+kc
  int kc = fk % 13, gset = fk / 13;
  int m = lane & 15;
  int k = kc * 32 + (lane >> 4) * 8 + j;
  int o = gset * 16 + m;
  float v = 0.f;
  if (k < 400) {
    int gl = k / 100, rem = k - gl * 100;
    int ci = rem / 25, dd = rem - ci * 25;
    if ((m >> 2) == gl) v = w[(o * 4 + ci) * 25 + dd];
  } else if (k == 400) {
    v = bias[o];
  }
  frag[i] = (short)f2bu(v);
}

// ---------------- generic 1x1 conv 64->64 via MFMA ----------------
__global__ __launch_bounds__(256) void k_conv1x1_mfma(
    const bf16* __restrict__ in, const short* __restrict__ wA,
    const float* __restrict__ bias, bf16* __restrict__ out) {
  int b = blockIdx.z;
  int lane = threadIdx.x & 63, w = threadIdx.x >> 6;
  int px = blockIdx.x * 64 + w * 16 + (lane & 15);
  int q = lane >> 4;
  const unsigned short* src = (const unsigned short*)in + (size_t)b * Cc * HWp;
  const short8* wf = (const short8*)wA;
  f32x4 acc[4];
  #pragma unroll
  for (int mt = 0; mt < 4; mt++) acc[mt] = (f32x4){0.f, 0.f, 0.f, 0.f};
  #pragma unroll
  for (int kc = 0; kc < 2; kc++) {
    short8 bfv;
    #pragma unroll
    for (int j = 0; j < 8; j++) bfv[j] = (short)src[(size_t)(kc * 32 + q * 8 + j) * HWp + px];
    #pragma unroll
    for (int mt = 0; mt < 4; mt++) {
      short8 af = wf[(mt * 2 + kc) * 64 + lane];
      acc[mt] = __builtin_amdgcn_mfma_f32_16x16x32_bf16(af, bfv, acc[mt], 0, 0, 0);
    }
  }
  unsigned short* dst = (unsigned short*)out + (size_t)b * Cc * HWp;
  #pragma unroll
  for (int mt = 0; mt < 4; mt++)
    #pragma unroll
    for (int j = 0; j < 4; j++) {
      int o = mt * 16 + q * 4 + j;
      dst[(size_t)o * HWp + px] = f2bu(acc[mt][j] + bias[o]);
    }
}

// ---------------- c3 1x1 conv + residual via MFMA: y = inp + (conv)*beta (fp32 out) ----------------
__global__ __launch_bounds__(256) void k_c3y_mfma(
    const bf16* __restrict__ in, const short* __restrict__ wA,
    const float* __restrict__ bias, const float* __restrict__ beta,
    const float* __restrict__ inp, float* __restrict__ y) {
  int b = blockIdx.z;
  int lane = threadIdx.x & 63, w = threadIdx.x >> 6;
  int px = blockIdx.x * 64 + w * 16 + (lane & 15);
  int q = lane >> 4;
  const unsigned short* src = (const unsigned short*)in + (size_t)b * Cc * HWp;
  const short8* wf = (const short8*)wA;
  f32x4 acc[4];
  #pragma unroll
  for (int mt = 0; mt < 4; mt++) acc[mt] = (f32x4){0.f, 0.f, 0.f, 0.f};
  #pragma unroll
  for (int kc = 0; kc < 2; kc++) {
    short8 bfv;
    #pragma unroll
    for (int j = 0; j < 8; j++) bfv[j] = (short)src[(size_t)(kc * 32 + q * 8 + j) * HWp + px];
    #pragma unroll
    for (int mt = 0; mt < 4; mt++) {
      short8 af = wf[(mt * 2 + kc) * 64 + lane];
      acc[mt] = __builtin_amdgcn_mfma_f32_16x16x32_bf16(af, bfv, acc[mt], 0, 0, 0);
    }
  }
  #pragma unroll
  for (int mt = 0; mt < 4; mt++)
    #pragma unroll
    for (int j = 0; j < 4; j++) {
      int o = mt * 16 + q * 4 + j;
      size_t oi = ((size_t)b * Cc + o) * HWp + px;
      y[oi] = inp[oi] + (acc[mt][j] + bias[o]) * beta[o];
    }
}

// ---------------- att via MFMA: M=32, K = [gate16 | pad16 | x64] ----------------
__global__ __launch_bounds__(256) void k_att_mfma(
    const bf16* __restrict__ g, const bf16* __restrict__ x,
    const short* __restrict__ wA, const float* __restrict__ c2cb,
    const float* __restrict__ c211b, const float* __restrict__ attg,
    bf16* __restrict__ att) {
  int b = blockIdx.z;
  int lane = threadIdx.x & 63, w = threadIdx.x >> 6;
  int px = blockIdx.x * 64 + w * 16 + (lane & 15);
  int q = lane >> 4;
  const unsigned short* gs = (const unsigned short*)g + (size_t)b * 32 * HWp;
  const unsigned short* xs = (const unsigned short*)x + (size_t)b * Cc * HWp;
  const short8* wf = (const short8*)wA;
  f32x4 acc[2];
  acc[0] = (f32x4){0.f, 0.f, 0.f, 0.f};
  acc[1] = (f32x4){0.f, 0.f, 0.f, 0.f};
  {
    short8 bfv;
    #pragma unroll
    for (int j = 0; j < 8; j++) {
      int k = q * 8 + j;
      short v = 0;
      if (q < 2) {
        float gv = ubf(gs[(size_t)k * HWp + px]) * ubf(gs[(size_t)(16 + k) * HWp + px]);
        v = (short)f2bu(gv);
      }
      bfv[j] = v;
    }
    #pragma unroll
    for (int mt = 0; mt < 2; mt++) {
      short8 af = wf[(mt * 3 + 0) * 64 + lane];
      acc[mt] = __builtin_amdgcn_mfma_f32_16x16x32_bf16(af, bfv, acc[mt], 0, 0, 0);
    }
  }
  #pragma unroll
  for (int kc = 1; kc < 3; kc++) {
    short8 bfv;
    #pragma unroll
    for (int j = 0; j < 8; j++)
      bfv[j] = (short)xs[(size_t)((kc - 1) * 32 + q * 8 + j) * HWp + px];
    #pragma unroll
    for (int mt = 0; mt < 2; mt++) {
      short8 af = wf[(mt * 3 + kc) * 64 + lane];
      acc[mt] = __builtin_amdgcn_mfma_f32_16x16x32_bf16(af, bfv, acc[mt], 0, 0, 0);
    }
  }
  unsigned short* dst = (unsigned short*)att + (size_t)b * 32 * HWp;
  #pragma unroll
  for (int mt = 0; mt < 2; mt++)
    #pragma unroll
    for (int j = 0; j < 4; j++) {
      int s = mt * 16 + q * 4 + j;
      dst[(size_t)s * HWp + px] = f2bu(acc[mt][j] + c2cb[s] * attg[s] + c211b[s]);
    }
}

// ---------------- c11b via MFMA: grouped 5x5, block-diag A, bias row at k=400 ----------------
__global__ __launch_bounds__(256) void k_c11b_mfma(
    const bf16* __restrict__ t1, const short* __restrict__ wF,
    bf16* __restrict__ out) {
  __shared__ unsigned short patchL[64 * 5 * 68];   // 43520 B, [c][ki(5)][col(68)]
  int b = blockIdx.z, h = blockIdx.y;
  int w0 = blockIdx.x * 64;
  int width = min(64, Wd - w0);
  int t = threadIdx.x;
  const unsigned short* src = (const unsigned short*)t1 + (size_t)b * Cc * HWp;
  for (int i = t; i < 64 * 340; i += 256) {
    int c = i / 340, rem = i - c * 340;
    int r = rem / 68, col = rem - r * 68;
    int hh = h + r - 2, ww = w0 + col - 2;
    unsigned short v = 0;
    if ((unsigned)hh < Hh && (unsigned)ww < Wd)
      v = src[(size_t)c * HWp + hh * Wd + ww];
    patchL[i] = v;
  }
  __syncthreads();
  int lane = t & 63, w = t >> 6;
  int n = lane & 15, q = lane >> 4;
  int pxl = w * 16 + n;
  const short8* wf = (const short8*)wF;
  f32x4 acc[4];
  #pragma unroll
  for (int gs = 0; gs < 4; gs++) acc[gs] = (f32x4){0.f, 0.f, 0.f, 0.f};
  #pragma unroll
  for (int kc = 0; kc < 13; kc++) {
    int off[8];          // >=0: patchL offset (gset-local); -1: bias row (1.0); -2: zero
    #pragma unroll
    for (int j = 0; j < 8; j++) {
      int k = kc * 32 + q * 8 + j;
      if (k < 400) {
        int gl = k / 100, rem = k - gl * 100;
        int ci = rem / 25, dd = rem - ci * 25;
        int ki = dd / 5, kj = dd - ki * 5;
        off[j] = (gl * 4 + ci) * 340 + ki * 68 + pxl + kj;
      } else off[j] = (k == 400) ? -1 : -2;
    }
    #pragma unroll
    for (int gs = 0; gs < 4; gs++) {
      short8 bfv;
      #pragma unroll
      for (int j = 0; j < 8; j++) {
        int o = off[j];
        short v;
        if (o >= 0) v = (short)patchL[gs * 5440 + o];
        else v = (o == -1) ? (short)0x3F80 : (short)0;
        bfv[j] = v;
      }
      short8 af = wf[(gs * 13 + kc) * 64 + lane];
      acc[gs] = __builtin_amdgcn_mfma_f32_16x16x32_bf16(af, bfv, acc[gs], 0, 0, 0);
    }
  }
  if (pxl < width) {
    unsigned short* dst = (unsigned short*)out + (size_t)b * Cc * HWp + h * Wd + w0 + pxl;
    #pragma unroll
    for (int gs = 0; gs < 4; gs++)
      #pragma unroll
      for (int j = 0; j < 4; j++) {
        int o = gs * 16 + q * 4 + j;
        dst[(size_t)o * HWp] = f2bu(acc[gs][j]);
      }
  }
}

// ---------------- DFT twiddle tables in MFMA A-fragment order ----------------
__global__ void k_dftfrag(short* __restrict__ cosF, short* __restrict__ sinF) {
  int i = blockIdx.x * 256 + threadIdx.x;   // 25600 total (100 blocks)
  int j = i & 7, lane = (i >> 3) & 63, fk = i >> 9;   // fk = ct*5+kc, 0..49
  int kc = fk % 5, ct = fk / 5;
  int c = ct * 16 + (lane & 15);
  int b = kc * 32 + (lane >> 4) * 8 + j;
  int m = (b * c) % 160;
  float sv, cv;
  __sincosf((float)m * TWO_PI_160, &sv, &cv);
  cosF[i] = (short)f2bu(cv);
  sinF[i] = (short)f2bu(sv);
}

// ---------------- KBA via MFMA ----------------
__global__ __launch_bounds__(256) void k_kba_mfma(
    const bf16* __restrict__ uf, const bf16* __restrict__ att,
    const bf16* __restrict__ x1, const float* __restrict__ scaV,
    const short* __restrict__ kbwF, const float* __restrict__ ga1,
    bf16* __restrict__ out) {
  __shared__ unsigned short patchL[64 * 3 * 66];   // 25344 B, bf16 [c][ki][col]
  __shared__ float attL[64][33];                   // 8448 B
  int b = blockIdx.z, h = blockIdx.y;
  int w0 = blockIdx.x * 64;
  int width = min(64, Wd - w0);
  int t = threadIdx.x;
  const unsigned short* uf_u = (const unsigned short*)uf;
  for (int i = t; i < 64 * 3 * 66; i += 256) {
    int c = i / 198, rem = i - c * 198;
    int r = rem / 66, col = rem - r * 66;
    int hh = h + r - 1, ww = w0 + col - 1;
    unsigned short v = 0;
    if ((unsigned)hh < Hh && (unsigned)ww < Wd)
      v = uf_u[((size_t)b * Cc + c) * HWp + hh * Wd + ww];
    patchL[i] = v;
  }
  for (int i = t; i < 64 * 32; i += 256) {
    int px = i & 63, s = i >> 6;
    float v = 0.f;
    if (px < width) v = b2f(att[((size_t)b * 32 + s) * HWp + h * Wd + w0 + px]);
    attL[px][s] = v;
  }
  __syncthreads();
  int lane = t & 63, w = t >> 6;
  int n = lane & 15, q = lane >> 4;
  int pxl = w * 16 + n;
  float attR[8];
  #pragma unroll
  for (int mt = 0; mt < 8; mt++) attR[mt] = attL[pxl][4 * mt + q];
  int offA[8];
  #pragma unroll
  for (int j = 0; j < 8; j++) {
    int k = q * 8 + j;
    int ci = k / 9, r = k - ci * 9, ki = r / 3, kj = r - ki * 3;
    offA[j] = ci * 198 + ki * 66 + pxl + kj;
  }
  int offB[4];
  #pragma unroll
  for (int j = 0; j < 4; j++) {
    int k = 32 + j, r = k - 27, ki = r / 3, kj = r - ki * 3;
    offB[j] = 3 * 198 + ki * 66 + pxl + kj;
  }
  const short8* wf = (const short8*)kbwF;
  const unsigned short* x1u = (const unsigned short*)x1 + (size_t)b * Cc * HWp + h * Wd + w0;
  unsigned short* outu = (unsigned short*)out + (size_t)b * Cc * HWp + h * Wd + w0;
  for (int g = 0; g < 16; g++) {
    short8 b0, b1;
    #pragma unroll
    for (int j = 0; j < 8; j++) b0[j] = (short)patchL[g * 792 + offA[j]];
    #pragma unroll
    for (int j = 0; j < 8; j++) b1[j] = 0;
    if (q == 0) {
      #pragma unroll
      for (int j = 0; j < 4; j++) b1[j] = (short)patchL[g * 792 + offB[j]];
      b1[4] = (short)0x3F80;                 // B[36][*] = 1.0 (bias row)
    }
    f32x4 acc[8];
    #pragma unroll
    for (int mt = 0; mt < 8; mt++) acc[mt] = (f32x4){0.f, 0.f, 0.f, 0.f};
    #pragma unroll
    for (int mt = 0; mt < 8; mt++) {
      short8 a0 = wf[(g * 16 + mt * 2 + 0) * 64 + lane];
      acc[mt] = __builtin_amdgcn_mfma_f32_16x16x32_bf16(a0, b0, acc[mt], 0, 0, 0);
      short8 a1 = wf[(g * 16 + mt * 2 + 1) * 64 + lane];
      acc[mt] = __builtin_amdgcn_mfma_f32_16x16x32_bf16(a1, b1, acc[mt], 0, 0, 0);
    }
    #pragma unroll
    for (int o = 0; o < 4; o++) {
      float P = 0.f;
      #pragma unroll
      for (int mt = 0; mt < 8; mt++) P += attR[mt] * acc[mt][o];
      P += __shfl_xor(P, 16);
      P += __shfl_xor(P, 32);
      if (o == q && pxl < width) {
        int c = g * 4 + q;
        float ufc = ubf(patchL[c * 198 + 66 + pxl + 1]);   // center tap
        float xk = P * ga1[c] + ufc;
        float xv = xk * ubf(x1u[(size_t)c * HWp + pxl]) * scaV[b * 64 + c];
        outu[(size_t)c * HWp + pxl] = f2bu(xv);
      }
    }
  }
}

// ---------------- LayerNorm, fp32 in (y in d_out) -> bf16 ws out ----------------
__global__ void k_ln2(const float* __restrict__ in, const float* __restrict__ w,
                      const float* __restrict__ bb, bf16* __restrict__ out) {
  int idx = blockIdx.x * 256 + threadIdx.x;
  int b = idx / HWp, p = idx - b * HWp;
  const float* src = in + (size_t)b * Cc * HWp + p;
  float s = 0.f, s2 = 0.f;
  for (int c = 0; c < Cc; c++) { float v = src[(size_t)c * HWp]; s += v; s2 += v * v; }
  float mu = s * (1.f / 64.f);
  float var = s2 * (1.f / 64.f) - mu * mu;
  float rs = rsqrtf(fmaxf(var, 0.f) + 1e-6f);
  bf16* dst = out + (size_t)b * Cc * HWp + p;
  for (int c = 0; c < Cc; c++) {
    float v = src[(size_t)c * HWp];
    dst[(size_t)c * HWp] = f2b((v - mu) * rs * w[c] + bb[c]);
  }
}

// ---------------- DFT pass via MFMA ----------------
__global__ __launch_bounds__(64) void k_cpass_mfma(
    const bf16* __restrict__ inr, const bf16* __restrict__ ini,
    const short* __restrict__ cosF, const short* __restrict__ sinF,
    bf16* __restrict__ outr, bf16* __restrict__ outi,
    float sgn, float scale,
    const float* __restrict__ sclr, const float* __restrict__ scli) {
  int plane = blockIdx.z;
  int a0 = blockIdx.x * 16;
  int cth = blockIdx.y * 5;          // c-half: ct 0..4 or 5..9
  int lane = threadIdx.x;
  int n = lane & 15, q = lane >> 4;
  const unsigned short* pr = (const unsigned short*)inr + (size_t)plane * HWp;
  const unsigned short* pi = ini ? (const unsigned short*)ini + (size_t)plane * HWp : nullptr;
  float srm = sclr ? sclr[plane] : 1.f;
  float sim = scli ? scli[plane] : 1.f;
  short8 br[5], bi[5];
  #pragma unroll
  for (int kc = 0; kc < 5; kc++) {
    br[kc] = *(const short8*)(pr + (a0 + n) * 160 + kc * 32 + q * 8);
    if (pi) bi[kc] = *(const short8*)(pi + (a0 + n) * 160 + kc * 32 + q * 8);
  }
  const short8* cf = (const short8*)cosF;
  const short8* sf = (const short8*)sinF;
  unsigned short* qr = (unsigned short*)outr + (size_t)plane * HWp;
  unsigned short* qi = (unsigned short*)outi + (size_t)plane * HWp;
  for (int ctl = 0; ctl < 5; ctl++) {
    int ct = cth + ctl;
    f32x4 arr = (f32x4){0.f,0.f,0.f,0.f}, asr = (f32x4){0.f,0.f,0.f,0.f};
    f32x4 ari = (f32x4){0.f,0.f,0.f,0.f}, asi = (f32x4){0.f,0.f,0.f,0.f};
    #pragma unroll
    for (int kc = 0; kc < 5; kc++) {
      short8 ca = cf[(ct * 5 + kc) * 64 + lane];
      short8 sa = sf[(ct * 5 + kc) * 64 + lane];
      arr = __builtin_amdgcn_mfma_f32_16x16x32_bf16(ca, br[kc], arr, 0, 0, 0);
      asr = __builtin_amdgcn_mfma_f32_16x16x32_bf16(sa, br[kc], asr, 0, 0, 0);
      if (pi) {
        ari = __builtin_amdgcn_mfma_f32_16x16x32_bf16(ca, bi[kc], ari, 0, 0, 0);
        asi = __builtin_amdgcn_mfma_f32_16x16x32_bf16(sa, bi[kc], asi, 0, 0, 0);
      }
    }
    #pragma unroll
    for (int j = 0; j < 4; j++) {
      int c = ct * 16 + q * 4 + j;
      float xc = srm * arr[j], xs = srm * asr[j];
      float ic = pi ? sim * ari[j] : 0.f, is = pi ? sim * asi[j] : 0.f;
      float orv = (xc - sgn * is) * scale;
      float oiv = (sgn * xs + ic) * scale;
      qr[c * 160 + a0 + n] = f2bu(orv);
      qi[c * 160 + a0 + n] = f2bu(oiv);
    }
  }
}

// ---------------- final inverse DFT pass via MFMA, fused |.|, *gamma, += y (fp32 d_out) ----------------
__global__ __launch_bounds__(64) void k_cpass_final_mfma(
    const bf16* __restrict__ inr, const bf16* __restrict__ ini,
    const short* __restrict__ cosF, const short* __restrict__ sinF,
    float sgn, float scale,
    const float* __restrict__ gamma, float* __restrict__ dout) {
  int plane = blockIdx.z;
  int a0 = blockIdx.x * 16;
  int cth = blockIdx.y * 5;
  int lane = threadIdx.x;
  int n = lane & 15, q = lane >> 4;
  const unsigned short* pr = (const unsigned short*)inr + (size_t)plane * HWp;
  const unsigned short* pi = (const unsigned short*)ini + (size_t)plane * HWp;
  short8 br[5], bi[5];
  #pragma unroll
  for (int kc = 0; kc < 5; kc++) {
    br[kc] = *(const short8*)(pr + (a0 + n) * 160 + kc * 32 + q * 8);
    bi[kc] = *(const short8*)(pi + (a0 + n) * 160 + kc * 32 + q * 8);
  }
  const short8* cf = (const short8*)cosF;
  const short8* sf = (const short8*)sinF;
  float gm = gamma[plane & 63];
  float* dp = dout + (size_t)plane * HWp;
  for (int ctl = 0; ctl < 5; ctl++) {
    int ct = cth + ctl;
    f32x4 arr = (f32x4){0.f,0.f,0.f,0.f}, asr = (f32x4){0.f,0.f,0.f,0.f};
    f32x4 ari = (f32x4){0.f,0.f,0.f,0.f}, asi = (f32x4){0.f,0.f,0.f,0.f};
    #pragma unroll
    for (int kc = 0; kc < 5; kc++) {
      short8 ca = cf[(ct * 5 + kc) * 64 + lane];
      short8 sa = sf[(ct * 5 + kc) * 64 + lane];
      arr = __builtin_amdgcn_mfma_f32_16x16x32_bf16(ca, br[kc], arr, 0, 0, 0);
      asr = __builtin_amdgcn_mfma_f32_16x16x32_bf16(sa, br[kc], asr, 0, 0, 0);
      ari = __builtin_amdgcn_mfma_f32_16x16x32_bf16(ca, bi[kc], ari, 0, 0, 0);
      asi = __builtin_amdgcn_mfma_f32_16x16x32_bf16(sa, bi[kc], asi, 0, 0, 0);
    }
    #pragma unroll
    for (int j = 0; j < 4; j++) {
      int c = ct * 16 + q * 4 + j;
      float orv = (arr[j] - sgn * asi[j]) * scale;
      float oiv = (sgn * asr[j] + ari[j]) * scale;
      float z = sqrtf(orv * orv + oiv * oiv);
      dp[c * 160 + a0 + n] += z * gm;   // dout currently holds y
    }
  }
}

// ---------------- fc1 (128->256) + simple_gate, MFMA ----------------
__global__ __launch_bounds__(256) void k_fc1_mfma(
    const bf16* __restrict__ Fr, const bf16* __restrict__ Fi,
    const short* __restrict__ wA, const float* __restrict__ bias,
    bf16* __restrict__ G1, bf16* __restrict__ G2) {
  int b = blockIdx.z;
  int lane = threadIdx.x & 63, w = threadIdx.x >> 6;
  int px = blockIdx.x * 64 + w * 16 + (lane & 15);
  int q = lane >> 4;
  const unsigned short* fr = (const unsigned short*)Fr + (size_t)b * Cc * HWp;
  const unsigned short* fi = (const unsigned short*)Fi + (size_t)b * Cc * HWp;
  const short8* wf = (const short8*)wA;
  f32x4 acc[16];
  #pragma unroll
  for (int mt = 0; mt < 16; mt++) acc[mt] = (f32x4){0.f, 0.f, 0.f, 0.f};
  #pragma unroll
  for (int kc = 0; kc < 4; kc++) {
    const unsigned short* basep = (kc < 2) ? (fr + (size_t)(kc * 32) * HWp)
                                           : (fi + (size_t)((kc - 2) * 32) * HWp);
    short8 bfv;
    #pragma unroll
    for (int j = 0; j < 8; j++) bfv[j] = (short)basep[(size_t)(q * 8 + j) * HWp + px];
    #pragma unroll
    for (int mt = 0; mt < 16; mt++) {
      short8 af = wf[(mt * 4 + kc) * 64 + lane];
      acc[mt] = __builtin_amdgcn_mfma_f32_16x16x32_bf16(af, bfv, acc[mt], 0, 0, 0);
    }
  }
  unsigned short* g1 = (unsigned short*)G1 + (size_t)b * Cc * HWp;
  unsigned short* g2 = (unsigned short*)G2 + (size_t)b * Cc * HWp;
  #pragma unroll
  for (int mt = 0; mt < 8; mt++)
    #pragma unroll
    for (int j = 0; j < 4; j++) {
      int o = mt * 16 + q * 4 + j;
      float v1 = acc[mt][j] + bias[o];
      float v2 = acc[mt + 8][j] + bias[o + 128];
      unsigned short hv = f2bu(v1 * v2);
      if (o < 64) g1[(size_t)o * HWp + px] = hv;
      else        g2[(size_t)(o - 64) * HWp + px] = hv;
    }
}

// ---------------- fc2 (128->128) MFMA, split output into r / i planes ----------------
__global__ __launch_bounds__(256) void k_fc2_mfma(
    const bf16* __restrict__ G1, const bf16* __restrict__ G2,
    const short* __restrict__ wA, const float* __restrict__ bias,
    bf16* __restrict__ Or, bf16* __restrict__ Oi) {
  int b = blockIdx.z;
  int lane = threadIdx.x & 63, w = threadIdx.x >> 6;
  int px = blockIdx.x * 64 + w * 16 + (lane & 15);
  int q = lane >> 4;
  const unsigned short* g1 = (const unsigned short*)G1 + (size_t)b * Cc * HWp;
  const unsigned short* g2 = (const unsigned short*)G2 + (size_t)b * Cc * HWp;
  const short8* wf = (const short8*)wA;
  f32x4 acc[8];
  #pragma unroll
  for (int mt = 0; mt < 8; mt++) acc[mt] = (f32x4){0.f, 0.f, 0.f, 0.f};
  #pragma unroll
  for (int kc = 0; kc < 4; kc++) {
    const unsigned short* basep = (kc < 2) ? (g1 + (size_t)(kc * 32) * HWp)
                                           : (g2 + (size_t)((kc - 2) * 32) * HWp);
    short8 bfv;
    #pragma unroll
    for (int j = 0; j < 8; j++) bfv[j] = (short)basep[(size_t)(q * 8 + j) * HWp + px];
    #pragma unroll
    for (int mt = 0; mt < 8; mt++) {
      short8 af = wf[(mt * 4 + kc) * 64 + lane];
      acc[mt] = __builtin_amdgcn_mfma_f32_16x16x32_bf16(af, bfv, acc[mt], 0, 0, 0);
    }
  }
  unsigned short* orp = (unsigned short*)Or + (size_t)b * Cc * HWp;
  unsigned short* oip = (unsigned short*)Oi + (size_t)b * Cc * HWp;
  #pragma unroll
  for (int mt = 0; mt < 8; mt++)
    #pragma unroll
    for (int j = 0; j < 4; j++) {
      int o = mt * 16 + q * 4 + j;
      unsigned short hv = f2bu(acc[mt][j] + bias[o]);
      if (o < 64) orp[(size_t)o * HWp + px] = hv;
      else        oip[(size_t)(o - 64) * HWp + px] = hv;
    }
}

extern "C" void kernel_launch(void* const* d_in, const int* in_sizes, int n_in,
                              void* d_out, int out_size, void* d_ws, size_t ws_size,
                              hipStream_t stream) {
  const float* inp   = (const float*)d_in[0];
  const float* n1w   = (const float*)d_in[1];
  const float* n1b   = (const float*)d_in[2];
  const float* n2w   = (const float*)d_in[3];
  const float* n2b   = (const float*)d_in[4];
  const float* scaw  = (const float*)d_in[5];
  const float* scab  = (const float*)d_in[6];
  const float* c11aw = (const float*)d_in[7];
  const float* c11ab = (const float*)d_in[8];
  const float* c11bw = (const float*)d_in[9];
  const float* c11bb = (const float*)d_in[10];
  const float* c1w   = (const float*)d_in[11];
  const float* c1b   = (const float*)d_in[12];
  const float* c21w  = (const float*)d_in[13];
  const float* c21b  = (const float*)d_in[14];
  const float* c2aw  = (const float*)d_in[15];
  const float* c2ab  = (const float*)d_in[16];
  const float* c2cw  = (const float*)d_in[17];
  const float* c2cb  = (const float*)d_in[18];
  const float* c211w = (const float*)d_in[19];
  const float* c211b = (const float*)d_in[20];
  const float* c3w   = (const float*)d_in[21];
  const float* c3b   = (const float*)d_in[22];
  const float* kbw   = (const float*)d_in[23];
  const float* kbb   = (const float*)d_in[24];
  const float* ga1   = (const float*)d_in[25];
  const float* attg  = (const float*)d_in[26];
  const float* beta  = (const float*)d_in[27];
  const float* gamma = (const float*)d_in[28];
  const float* fc1w  = (const float*)d_in[29];
  const float* fc1b  = (const float*)d_in[30];
  const float* fc2w  = (const float*)d_in[31];
  const float* fc2b  = (const float*)d_in[32];
  const float* fscaw = (const float*)d_in[33];
  const float* fscab = (const float*)d_in[34];

  const size_t S = (size_t)Bn * Cc * HWp;   // 3,276,800 elements per slot
  bf16* A  = (bf16*)d_ws;                   // 4 bf16 slots = 26.2 MB total
  bf16* Bs = A + S;
  bf16* Cs = A + 2 * S;
  bf16* Ds = A + 3 * S;
  float* smalls = (float*)(A + 4 * S);      // fp32 smalls
  float* xm   = smalls;
  float* scaV = smalls + 128;
  float* rmv  = smalls + 256;
  float* imv  = smalls + 384;
  float* sra  = smalls + 512;
  float* sia  = smalls + 640;
  short* wS   = (short*)(smalls + 1024);    // bf16 frag tables (~545 KB total)
  short* wAf1 = wS;                         // 32768
  short* wAf2 = wAf1 + 32768;               // 16384
  short* cosF = wAf2 + 16384;               // 25600
  short* sinF = cosF + 25600;               // 25600
  short* wA_c11a = sinF + 25600;            // 4096
  short* wA_c1   = wA_c11a + 4096;          // 4096
  short* wA_c3   = wA_c1 + 4096;            // 4096
  short* wA_att  = wA_c3 + 4096;            // 3072
  short* kbwF    = wA_att + 3072;           // 131072 (256 KB)
  short* c11F    = kbwF + 131072;           // 26624 (53 KB)
  bf16* gbuf = Bs;            // [B,32,HW] (first half of Bs)
  bf16* attb = Bs + S / 2;    // [B,32,HW] (second half of Bs)
  float* yb  = (float*)d_out; // y lives in d_out (fp32)

  dim3 blk(64, 4, 1);
  dim3 cgrid(10, 2, Bn * Cc);
  dim3 pgrid(400, 1, Bn);
  dim3 rgrid(3, 160, Bn);

  k_kbwF<<<dim3(512), dim3(256), 0, stream>>>(kbw, kbb, kbwF);          // kba frags (independent)
  k_wprep<<<dim3(192), dim3(256), 0, stream>>>(fc1w, fc2w, wAf1, wAf2); // fc frags (independent)
  k_dftfrag<<<dim3(100), dim3(256), 0, stream>>>(cosF, sinF);           // DFT frags (independent)
  k_wprep1x1<<<dim3(60), dim3(256), 0, stream>>>(c11aw, c1w, c3w, c2cw, c211w, attg,
                                                 wA_c11a, wA_c1, wA_c3, wA_att);
  k_c11F<<<dim3(104), dim3(256), 0, stream>>>(c11bw, c11bb, c11F);      // c11b frags (independent)
  k_ln<<<dim3(200), dim3(256), 0, stream>>>(inp, n1w, n1b, A);          // A = x
  k_meanhw<<<dim3(128), dim3(256), 0, stream>>>(A, xm);
  k_small_mv<<<dim3(1), dim3(128), 0, stream>>>(xm, scaw, scab, scaV, 0);
  k_conv1x1_mfma<<<pgrid, dim3(256), 0, stream>>>(A, wA_c11a, c11ab, Bs);          // B = t1
  k_c11b_mfma<<<rgrid, dim3(256), 0, stream>>>(Bs, c11F, Cs);                      // C = x1 (B dead)
  k_c2a<<<dim3(400, 8, Bn), blk, 0, stream>>>(A, c2aw, c2ab, gbuf);                // B.lo = g
  k_att_mfma<<<pgrid, dim3(256), 0, stream>>>(gbuf, A, wA_att, c2cb, c211b, attg, attb); // B.hi = att
  k_conv1x1_mfma<<<pgrid, dim3(256), 0, stream>>>(A, wA_c1, c1b, Ds);              // D = t2 (A dead after)
  k_c21dw<<<dim3(400, 16, Bn), blk, 0, stream>>>(Ds, c21w, c21b, A);               // A = uf
  k_kba_mfma<<<rgrid, dim3(256), 0, stream>>>(A, attb, Cs, scaV, kbwF, ga1, Ds);   // D = xprod
  k_c3y_mfma<<<pgrid, dim3(256), 0, stream>>>(Ds, wA_c3, c3b, beta, inp, yb);      // d_out = y (fp32)
  k_ln2<<<dim3(200), dim3(256), 0, stream>>>(yb, n2w, n2b, A);                     // A = X
  // forward FFT2 (MFMA): pass over W ([h][w] -> [u][h]), then over H ([u][h] -> [v][u])
  k_cpass_mfma<<<cgrid, dim3(64), 0, stream>>>(A, (const bf16*)nullptr, cosF, sinF, Bs, Cs, -1.f, SCL, nullptr, nullptr); // B,C = F1
  k_cpass_mfma<<<cgrid, dim3(64), 0, stream>>>(Bs, Cs, cosF, sinF, Ds, A, -1.f, SCL, nullptr, nullptr);                   // D,A = F2
  k_fc1_mfma<<<pgrid, dim3(256), 0, stream>>>(Ds, A, wAf1, fc1b, Bs, Cs);          // B,C = gated
  k_fc2_mfma<<<pgrid, dim3(256), 0, stream>>>(Bs, Cs, wAf2, fc2b, Ds, A);          // D = r, A = i
  k_meanhw<<<dim3(128), dim3(256), 0, stream>>>(Ds, rmv);
  k_meanhw<<<dim3(128), dim3(256), 0, stream>>>(A, imv);
  k_small_mv<<<dim3(1), dim3(128), 0, stream>>>(rmv, fscaw, fscab, sra, 1);
  k_small_mv<<<dim3(1), dim3(128), 0, stream>>>(imv, fscaw, fscab, sia, 1);
  // inverse FFT2 (MFMA) with per-plane (1+ra)/(1+ia) scaling fused into first pass
  k_cpass_mfma<<<cgrid, dim3(64), 0, stream>>>(Ds, A, cosF, sinF, Bs, Cs, 1.f, SCL, sra, sia);  // B,C
  k_cpass_final_mfma<<<cgrid, dim3(64), 0, stream>>>(Bs, Cs, cosF, sinF, 1.f, SCL, gamma, yb);  // d_out = y + |z|*gamma
}